// Round 11
// baseline (2472.982 us; speedup 1.0000x reference)
//
#include <hip/hip_runtime.h>
#include <hip/hip_bf16.h>
#include <math.h>

// ---------------------------------------------------------------------------
// EEGMamba forward. Round 20: TLP is grid-capped (1920 waves, ~7.5/CU, all
// occupancy attempts failed), so trade TLP for ILP: pass 3 becomes dual-chain
// — one wave runs heads h and h+4 over the same (b,chunk). The chains share
// the B/C LDS panel (same tokens) but have independent state arrays, doubling
// the FMA window per prefetch and filling each chain's latency bubbles with
// the other's ready FMAs. dA=exp(dt*A) and u=dt*x hoisted to prefetch time.
// Pass 1 = ssd_state4 (R12), nchunk=15, rstd row-scale GEMM epilogue.
#define D_MODEL   200
#define N_LAYER   12
#define NHEADS    8
#define HEADDIM   50
#define D_STATE   64
#define D_INNER   400
#define CONV_DIM  528
#define D_IN_PROJ 936
#define D_CONV    4
#define EPS       1e-5f

#define BATCH 16
#define CH    19
#define LLEN  30
#define SEQ   570
#define NTOK  9120
#define NFREQ 101

typedef __attribute__((ext_vector_type(8))) short s8v;
typedef __attribute__((ext_vector_type(4))) float f32x4;

__device__ __forceinline__ short f2bf(float f) {
    unsigned u = __float_as_uint(f);
    u += 0x7FFFu + ((u >> 16) & 1u);      // RNE
    return (short)(u >> 16);
}

// ---------------------------------------------------------------------------
// bf16 MFMA GEMM: C[M,N] = rowscale[m] * (A[M,Kp] @ W[N,Kp]^T) (+bias) (+C)
__global__ __launch_bounds__(256) void gemm_bf16(
    const short* __restrict__ A, const short* __restrict__ W,
    const float* __restrict__ bias, const float* __restrict__ rowscale,
    float* __restrict__ C, int M, int N, int Kp, int accum)
{
    __shared__ __align__(16) short As[128][40];
    __shared__ __align__(16) short Ws[128][40];

    int bm = blockIdx.y * 128;
    int bn = blockIdx.x * 128;
    int tid = threadIdx.x;
    int lane = tid & 63;
    int wv = tid >> 6;
    int wm = wv & 1, wn = wv >> 1;
    int lm = lane & 15, lg = lane >> 4;

    int sr = tid >> 1;
    int sh_ = (tid & 1) * 16;

    f32x4 acc[4][4];
#pragma unroll
    for (int i = 0; i < 4; i++)
#pragma unroll
        for (int j = 0; j < 4; j++) acc[i][j] = (f32x4)0.f;

    for (int k0 = 0; k0 < Kp; k0 += 32) {
        {
            s8v v0 = (s8v)0, v1 = (s8v)0;
            if (bm + sr < M) {
                const short* ga = A + (size_t)(bm + sr) * Kp + k0 + sh_;
                v0 = *(const s8v*)ga;
                v1 = *(const s8v*)(ga + 8);
            }
            *(s8v*)&As[sr][sh_] = v0;
            *(s8v*)&As[sr][sh_ + 8] = v1;
        }
        {
            s8v v0 = (s8v)0, v1 = (s8v)0;
            if (bn + sr < N) {
                const short* gw = W + (size_t)(bn + sr) * Kp + k0 + sh_;
                v0 = *(const s8v*)gw;
                v1 = *(const s8v*)(gw + 8);
            }
            *(s8v*)&Ws[sr][sh_] = v0;
            *(s8v*)&Ws[sr][sh_ + 8] = v1;
        }
        __syncthreads();

        s8v af[4], bf[4];
#pragma unroll
        for (int i = 0; i < 4; i++)
            af[i] = *(const s8v*)&As[wm * 64 + i * 16 + lm][lg * 8];
#pragma unroll
        for (int j = 0; j < 4; j++)
            bf[j] = *(const s8v*)&Ws[wn * 64 + j * 16 + lm][lg * 8];
#pragma unroll
        for (int i = 0; i < 4; i++)
#pragma unroll
            for (int j = 0; j < 4; j++)
                acc[i][j] = __builtin_amdgcn_mfma_f32_16x16x32_bf16(
                    af[i], bf[j], acc[i][j], 0, 0, 0);
        __syncthreads();
    }

#pragma unroll
    for (int j = 0; j < 4; j++) {
        int n = bn + wn * 64 + j * 16 + lm;
        if (n >= N) continue;
        float bv = bias ? bias[n] : 0.f;
#pragma unroll
        for (int i = 0; i < 4; i++) {
            int mbase = bm + wm * 64 + i * 16 + lg * 4;
#pragma unroll
            for (int r = 0; r < 4; r++) {
                int m = mbase + r;
                if (m >= M) continue;
                size_t idx = (size_t)m * N + n;
                float v = acc[i][j][r];
                if (rowscale) v *= rowscale[m];
                v += bv;
                if (accum) v += C[idx];
                C[idx] = v;
            }
        }
    }
}

// ---------------------------------------------------------------------------
// fp32 GEMM (fallback path)
__global__ __launch_bounds__(256) void gemm_nt(
    const float* __restrict__ A, const float* __restrict__ W,
    const float* __restrict__ bias, float* __restrict__ C,
    int M, int N, int K, int accum)
{
    const int BM = 128, BK = 16;
    __shared__ float As[16][BM + 4];
    __shared__ float Ws[16][BM + 4];

    int bm = blockIdx.y * BM;
    int bn = blockIdx.x * BM;
    int tid = threadIdx.x;
    int lr = tid >> 1;
    int lc = (tid & 1) * 8;
    int tx = tid & 15;
    int ty = tid >> 4;

    float acc[8][8];
#pragma unroll
    for (int i = 0; i < 8; i++)
#pragma unroll
        for (int j = 0; j < 8; j++) acc[i][j] = 0.f;

    for (int k0 = 0; k0 < K; k0 += BK) {
#pragma unroll
        for (int i = 0; i < 8; i++) {
            int gr = bm + lr, gk = k0 + lc + i;
            As[lc + i][lr] = (gr < M && gk < K) ? A[(size_t)gr * K + gk] : 0.f;
        }
#pragma unroll
        for (int i = 0; i < 8; i++) {
            int gr = bn + lr, gk = k0 + lc + i;
            Ws[lc + i][lr] = (gr < N && gk < K) ? W[(size_t)gr * K + gk] : 0.f;
        }
        __syncthreads();
#pragma unroll
        for (int kk = 0; kk < BK; kk++) {
            float a[8], bv[8];
#pragma unroll
            for (int i = 0; i < 8; i++) a[i] = As[kk][ty * 8 + i];
#pragma unroll
            for (int j = 0; j < 8; j++) bv[j] = Ws[kk][tx * 8 + j];
#pragma unroll
            for (int i = 0; i < 8; i++)
#pragma unroll
                for (int j = 0; j < 8; j++)
                    acc[i][j] = fmaf(a[i], bv[j], acc[i][j]);
        }
        __syncthreads();
    }

#pragma unroll
    for (int i = 0; i < 8; i++) {
        int gm = bm + ty * 8 + i;
        if (gm >= M) continue;
#pragma unroll
        for (int j = 0; j < 8; j++) {
            int gn = bn + tx * 8 + j;
            if (gn >= N) continue;
            float v = acc[i][j];
            if (bias) v += bias[gn];
            if (accum) v += C[(size_t)gm * N + gn];
            C[(size_t)gm * N + gn] = v;
        }
    }
}

// ---------------------------------------------------------------------------
__global__ __launch_bounds__(256) void cast_pad_kernel(
    const float* __restrict__ src, short* __restrict__ dst,
    int R, int K, int Kp)
{
    int idx = blockIdx.x * 256 + threadIdx.x;
    if (idx >= R * Kp) return;
    int r = idx / Kp, k = idx - r * Kp;
    dst[idx] = (k < K) ? f2bf(src[(size_t)r * K + k]) : (short)0;
}

// ---------------------------------------------------------------------------
__global__ __launch_bounds__(256) void time_conv_kernel(
    const float* __restrict__ x, const float* __restrict__ pw,
    float* __restrict__ traw)
{
    int br = blockIdx.x;
    __shared__ float xr[200];
    if (threadIdx.x < 200) xr[threadIdx.x] = x[(size_t)br * 200 + threadIdx.x];
    __syncthreads();
    if (threadIdx.x < 200) {
        int oc = threadIdx.x >> 3, j = threadIdx.x & 7;
        int start = j * 25 - 24;
        float acc = 0.f;
#pragma unroll
        for (int k = 0; k < 49; k++) {
            int d = start + k;
            if (d >= 0 && d < 200) acc = fmaf(xr[d], pw[oc * 49 + k], acc);
        }
        int b = br / SEQ, row = br % SEQ;
        traw[(((size_t)b * 25 + oc) * SEQ + row) * 8 + j] = acc;
    }
}

__global__ __launch_bounds__(256) void gn_stats_kernel(
    const float* __restrict__ traw, float* __restrict__ stats)
{
    int bg = blockIdx.x;
    int b = bg / 5, g = bg % 5;
    const float* base = traw + ((size_t)b * 25 + g * 5) * SEQ * 8;
    float s = 0.f, q = 0.f;
    for (int i = threadIdx.x; i < 5 * SEQ * 8; i += 256) {
        float v = base[i];
        s += v; q = fmaf(v, v, q);
    }
    __shared__ float rs[4], rq[4];
    int lane = threadIdx.x & 63, w = threadIdx.x >> 6;
#pragma unroll
    for (int o = 32; o; o >>= 1) { s += __shfl_xor(s, o, 64); q += __shfl_xor(q, o, 64); }
    if (lane == 0) { rs[w] = s; rq[w] = q; }
    __syncthreads();
    if (threadIdx.x == 0) {
        float S = rs[0] + rs[1] + rs[2] + rs[3];
        float Q = rq[0] + rq[1] + rq[2] + rq[3];
        float inv = 1.f / (5.f * SEQ * 8.f);
        float mean = S * inv;
        float var = Q * inv - mean * mean;
        stats[bg * 2] = mean;
        stats[bg * 2 + 1] = rsqrtf(var + EPS);
    }
}

__global__ __launch_bounds__(256) void gn_gelu_kernel(
    const float* __restrict__ traw, const float* __restrict__ stats,
    const float* __restrict__ gn_g, const float* __restrict__ gn_b,
    float* __restrict__ patch)
{
    int idx = blockIdx.x * 256 + threadIdx.x;
    if (idx >= NTOK * 200) return;
    int d = idx % 200;
    int row = (idx / 200) % SEQ;
    int b = idx / (200 * SEQ);
    int oc = d >> 3, j = d & 7;
    float v = traw[(((size_t)b * 25 + oc) * SEQ + row) * 8 + j];
    int g = oc / 5;
    float mean = stats[(b * 5 + g) * 2];
    float rstd = stats[(b * 5 + g) * 2 + 1];
    v = (v - mean) * rstd * gn_g[oc] + gn_b[oc];
    float ge = 0.5f * v * (1.f + erff(v * 0.70710678118654752f));
    patch[idx] = ge;
}

__global__ __launch_bounds__(256) void dft_init_kernel(float* __restrict__ CS)
{
    int idx = blockIdx.x * 256 + threadIdx.x;
    if (idx >= 202 * 200) return;
    int f = idx / 200, d = idx % 200;
    int fr = (f < NFREQ) ? f : (f - NFREQ);
    int m = (fr * d) % 200;
    float ang = -6.283185307179586f * (float)m * (1.f / 200.f);
    CS[idx] = (f < NFREQ) ? cosf(ang) : sinf(ang);
}

__global__ __launch_bounds__(256) void dft_init_bf_kernel(short* __restrict__ CS)
{
    int idx = blockIdx.x * 256 + threadIdx.x;
    if (idx >= 202 * 224) return;
    int f = idx / 224, d = idx - f * 224;
    short out = 0;
    if (d < 200) {
        int fr = (f < NFREQ) ? f : (f - NFREQ);
        int m = (fr * d) % 200;
        float ang = -6.283185307179586f * (float)m * (1.f / 200.f);
        out = f2bf((f < NFREQ) ? cosf(ang) : sinf(ang));
    }
    CS[idx] = out;
}

__global__ __launch_bounds__(256) void mag_kernel(
    const float* __restrict__ cs_out, float* __restrict__ magv)
{
    int idx = blockIdx.x * 256 + threadIdx.x;
    if (idx >= NTOK * NFREQ) return;
    int m = idx / NFREQ, f = idx % NFREQ;
    float re = cs_out[(size_t)m * 202 + f];
    float im = cs_out[(size_t)m * 202 + NFREQ + f];
    magv[idx] = sqrtf(re * re + im * im) * 0.005f;
}

__global__ __launch_bounds__(256) void mag_bf_kernel(
    const float* __restrict__ cs_out, short* __restrict__ magv)
{
    int idx = blockIdx.x * 256 + threadIdx.x;
    if (idx >= NTOK * 128) return;
    int m = idx >> 7, f = idx & 127;
    short out = 0;
    if (f < NFREQ) {
        float re = cs_out[(size_t)m * 202 + f];
        float im = cs_out[(size_t)m * 202 + NFREQ + f];
        out = f2bf(sqrtf(re * re + im * im) * 0.005f);
    }
    magv[idx] = out;
}

// ---------------------------------------------------------------------------
// depthwise 7x7 pos conv + residual. block = (b, 16-d slice, 4-c tile+halo)
__global__ __launch_bounds__(256) void pe_conv3_kernel(
    const float* __restrict__ patch, const float* __restrict__ pw,
    float* __restrict__ hidden)
{
    int b = blockIdx.x, dc = blockIdx.y, ct = blockIdx.z;
    int d0 = dc * 16, c0 = ct * 4;
    __shared__ float pl[10 * 30 * 16];
    __shared__ float wl[49 * 16];
    int tid = threadIdx.x;
    int dd = tid & 15;
    int d = d0 + dd;

    for (int i = tid; i < 10 * 30 * 16; i += 256) {
        int ddl = i & 15, r = i >> 4;
        int l = r % 30, cr = r / 30;
        int cc = c0 + cr - 3, dl = d0 + ddl;
        pl[i] = (cc >= 0 && cc < CH && dl < 200)
                    ? patch[((size_t)(b * CH + cc) * LLEN + l) * 200 + dl] : 0.f;
    }
    for (int i = tid; i < 49 * 16; i += 256) {
        int k = i >> 4, dl = d0 + (i & 15);
        wl[i] = (dl < 200) ? pw[(size_t)dl * 49 + k] : 0.f;
    }
    __syncthreads();

    float wreg[49];
#pragma unroll
    for (int k = 0; k < 49; k++) wreg[k] = wl[k * 16 + dd];

    for (int o = tid; o < 4 * 30 * 16; o += 256) {
        int r2 = o >> 4;
        int l = r2 % 30, ci = r2 / 30;
        int c = c0 + ci;
        if (c >= CH) continue;
        float acc = pl[((ci + 3) * 30 + l) * 16 + dd];
#pragma unroll
        for (int i = 0; i < 7; i++) {
#pragma unroll
            for (int j = 0; j < 7; j++) {
                int ll = l + j - 3;
                if (ll < 0 || ll >= LLEN) continue;
                acc = fmaf(pl[((ci + i) * 30 + ll) * 16 + dd], wreg[i * 7 + j], acc);
            }
        }
        if (d < 200) hidden[((size_t)(b * CH + c) * LLEN + l) * 200 + d] = acc;
    }
}

// ---------------------------------------------------------------------------
__global__ __launch_bounds__(64) void add_rmsnorm_kernel(
    const float* __restrict__ hidden, float* __restrict__ residual,
    const float* __restrict__ wn, float* __restrict__ u,
    short* __restrict__ ubf, int first)
{
    int m = blockIdx.x;
    int lane = threadIdx.x;
    const float* hr = hidden + (size_t)m * 200;
    float* rr = residual + (size_t)m * 200;
    float v[4];
    float ss = 0.f;
#pragma unroll
    for (int i = 0; i < 4; i++) {
        int k = lane + i * 64;
        float xv = 0.f;
        if (k < 200) {
            xv = hr[k] + (first ? 0.f : rr[k]);
            rr[k] = xv;
        }
        v[i] = xv;
        ss = fmaf(xv, xv, ss);
    }
#pragma unroll
    for (int o = 32; o; o >>= 1) ss += __shfl_xor(ss, o, 64);
    float rstd = rsqrtf(ss * (1.f / 200.f) + EPS);
#pragma unroll
    for (int i = 0; i < 4; i++) {
        int k = lane + i * 64;
        float val = v[i] * rstd * ((k < 200) ? wn[k] : 0.f);
        if (k < 200 && u) u[(size_t)m * 200 + k] = val;
        if (ubf) {
            if (k < 200) ubf[(size_t)m * 224 + k] = f2bf(val);
            else if (k < 224) ubf[(size_t)m * 224 + k] = 0;
        }
    }
}

// ---------------------------------------------------------------------------
// Fused: residual += hidden; u = rmsnorm*wn -> ubf; dt GEMV fp32.
__global__ __launch_bounds__(256) void norm_dt_kernel(
    const float* __restrict__ hidden, float* __restrict__ residual,
    const float* __restrict__ wn, short* __restrict__ ubf,
    const float* __restrict__ Win, const float* __restrict__ dt_bias,
    float* __restrict__ dtb, int layer, int first)
{
    int m = blockIdx.x;
    int tid = threadIdx.x;
    __shared__ float su[200];
    __shared__ float rs[4];
    float xv = 0.f;
    if (tid < 200) {
        xv = hidden[(size_t)m * 200 + tid] + (first ? 0.f : residual[(size_t)m * 200 + tid]);
        residual[(size_t)m * 200 + tid] = xv;
    }
    float ss = xv * xv;
#pragma unroll
    for (int o = 32; o; o >>= 1) ss += __shfl_xor(ss, o, 64);
    int lane = tid & 63, w = tid >> 6;
    if (lane == 0) rs[w] = ss;
    __syncthreads();
    float rstd = rsqrtf((rs[0] + rs[1] + rs[2] + rs[3]) * (1.f / 200.f) + EPS);
    if (tid < 200) {
        float val = xv * rstd * wn[tid];
        su[tid] = val;
        ubf[(size_t)m * 224 + tid] = f2bf(val);
    } else if (tid < 224) {
        ubf[(size_t)m * 224 + tid] = 0;
    }
    __syncthreads();
    int h = tid >> 5, l = tid & 31;
    const float* wr = Win + (size_t)layer * D_IN_PROJ * 200 + (size_t)(928 + h) * 200;
    float s = 0.f;
    for (int k = l; k < 200; k += 32) s = fmaf(su[k], wr[k], s);
    s += __shfl_xor(s, 16, 32);
    s += __shfl_xor(s, 8, 32);
    s += __shfl_xor(s, 4, 32);
    s += __shfl_xor(s, 2, 32);
    s += __shfl_xor(s, 1, 32);
    if (l == 0) {
        float raw = s + dt_bias[layer * NHEADS + h];
        dtb[(size_t)m * NHEADS + h] = (raw > 20.f) ? raw : log1pf(expf(raw));
    }
}

// fp32 dt GEMV (fallback)
__global__ __launch_bounds__(256) void dt_gemv_kernel(
    const float* __restrict__ u, const float* __restrict__ Win,
    const float* __restrict__ dt_bias, float* __restrict__ dtb, int layer)
{
    int tid = threadIdx.x;
    int tok = blockIdx.x * 4 + (tid >> 6);
    int head = (tid >> 3) & 7;
    int l8 = tid & 7;
    const float* ur = u + (size_t)tok * 200;
    const float* wr = Win + (size_t)layer * D_IN_PROJ * 200 + (size_t)(928 + head) * 200;
    float s = 0.f;
    for (int k = l8; k < 200; k += 8) s = fmaf(ur[k], wr[k], s);
    s += __shfl_xor(s, 1, 64);
    s += __shfl_xor(s, 2, 64);
    s += __shfl_xor(s, 4, 64);
    if (l8 == 0) {
        float raw = s + dt_bias[layer * NHEADS + head];
        dtb[(size_t)tok * NHEADS + head] = (raw > 20.f) ? raw : log1pf(expf(raw));
    }
}

// ---------------------------------------------------------------------------
// xBC = silu(causal depthwise conv4), t-tiled
__global__ __launch_bounds__(256) void dtconv2_kernel(
    const float* __restrict__ zxbcdt, const float* __restrict__ cw,
    const float* __restrict__ cb, float* __restrict__ xBC, int layer)
{
    int b = blockIdx.x, tt = blockIdx.y;
    int t0 = tt * 8;
    __shared__ float zs[11][528];
    const float* cwl = cw + (size_t)layer * CONV_DIM * 4;
    const float* cbl = cb + (size_t)layer * CONV_DIM;
    for (int i = threadIdx.x; i < 11 * 528; i += 256) {
        int r = i / 528, ch = i - r * 528;
        int t = t0 - 3 + r;
        zs[r][ch] = (t >= 0 && t < SEQ)
                        ? zxbcdt[(size_t)(b * SEQ + t) * D_IN_PROJ + D_INNER + ch] : 0.f;
    }
    __syncthreads();
    for (int o = threadIdx.x; o < 8 * 528; o += 256) {
        int tr = o / 528, ch = o - tr * 528;
        int t = t0 + tr;
        if (t >= SEQ) continue;
        float acc = cbl[ch];
#pragma unroll
        for (int k = 0; k < 4; k++)
            acc = fmaf(zs[tr + k][ch], cwl[ch * 4 + k], acc);
        xBC[(size_t)(b * SEQ + t) * CONV_DIM + ch] = acc / (1.f + __expf(-acc));
    }
}

// ---------------------------------------------------------------------------
// SSD pass 1, 4 heads per 256-thr block: grid (b, chunk, half). Each block
// stages only its 4 heads' x slice (200 f) + B (64 f) + 4 dt. wave = head,
// lane = p. (R12's fastest pass-1 variant.)
__global__ __launch_bounds__(256) void ssd_state4_kernel(
    const float* __restrict__ xBC, const float* __restrict__ dtb,
    const float* __restrict__ A_log, float* __restrict__ Sbuf,
    float* __restrict__ Pd, int layer, int lchunk, int nchunk)
{
    int b = blockIdx.x, c = blockIdx.y, bz = blockIdx.z;
    int tid = threadIdx.x;
    int hl = tid >> 6, p = tid & 63;
    int h = bz * 4 + hl;
    float A = -expf(A_log[layer * NHEADS + h]);

    // per token: x slice [0,200), B [200,264), dt [264,268); pad to 272
    __shared__ __align__(16) float sh[2][2][272];
    int t0 = c * lchunk;
    int npairs = lchunk >> 1, rem = lchunk & 1;

    {
        if (tid < 132) {
            int tok = (tid >= 66) ? 1 : 0;
            int fidx = tid - tok * 66;
            int g = (fidx < 50) ? (50 * bz + fidx) : (fidx + 50);
            float4 v = ((const float4*)(xBC + (size_t)(b * SEQ + t0 + tok) * CONV_DIM))[g];
            *(float4*)&sh[0][tok][fidx * 4] = v;
        } else if (tid < 140) {
            int e = tid - 132, tok = e >> 2, hd = e & 3;
            sh[0][tok][264 + hd] = dtb[(size_t)(b * SEQ + t0 + tok) * NHEADS + bz * 4 + hd];
        }
    }
    __syncthreads();

    float s[64];
#pragma unroll
    for (int n = 0; n < 64; n++) s[n] = 0.f;
    float pacc = 1.f;

    for (int i = 0; i < npairs; i++) {
        int t = t0 + 2 * i;
        int buf = i & 1, nb = buf ^ 1;
        bool pf = (2 * i + 2 < lchunk);
        float4 rx;
        float rdt = 0.f;
        int tok = 0, fidx = 0;
        if (pf) {
            if (tid < 132) {
                tok = (tid >= 66) ? 1 : 0;
                fidx = tid - tok * 66;
                int tq = t + 2 + tok; if (tq > SEQ - 1) tq = SEQ - 1;
                int g = (fidx < 50) ? (50 * bz + fidx) : (fidx + 50);
                rx = ((const float4*)(xBC + (size_t)(b * SEQ + tq) * CONV_DIM))[g];
            } else if (tid < 140) {
                int e = tid - 132, tk = e >> 2, hd = e & 3;
                int tq = t + 2 + tk; if (tq > SEQ - 1) tq = SEQ - 1;
                rdt = dtb[(size_t)(b * SEQ + tq) * NHEADS + bz * 4 + hd];
            }
        }
#pragma unroll
        for (int k = 0; k < 2; k++) {
            float dtv = sh[buf][k][264 + hl];
            float xp  = (p < HEADDIM) ? sh[buf][k][hl * HEADDIM + p] : 0.f;
            float dA = __expf(dtv * A);
            float u  = dtv * xp;
            pacc *= dA;
            const float4* B4 = (const float4*)&sh[buf][k][200];
#pragma unroll
            for (int n4 = 0; n4 < 16; n4++) {
                float4 bq = B4[n4];
                s[4 * n4 + 0] = fmaf(s[4 * n4 + 0], dA, u * bq.x);
                s[4 * n4 + 1] = fmaf(s[4 * n4 + 1], dA, u * bq.y);
                s[4 * n4 + 2] = fmaf(s[4 * n4 + 2], dA, u * bq.z);
                s[4 * n4 + 3] = fmaf(s[4 * n4 + 3], dA, u * bq.w);
            }
        }
        if (pf) {
            if (tid < 132) *(float4*)&sh[nb][tok][fidx * 4] = rx;
            else if (tid < 140) { int e = tid - 132; sh[nb][e >> 2][264 + (e & 3)] = rdt; }
        }
        __syncthreads();
    }

    if (rem) {
        int buf = npairs & 1;
        float dtv = sh[buf][0][264 + hl];
        float xp  = (p < HEADDIM) ? sh[buf][0][hl * HEADDIM + p] : 0.f;
        float dA = __expf(dtv * A);
        float u  = dtv * xp;
        pacc *= dA;
        const float4* B4 = (const float4*)&sh[buf][0][200];
#pragma unroll
        for (int n4 = 0; n4 < 16; n4++) {
            float4 bq = B4[n4];
            s[4 * n4 + 0] = fmaf(s[4 * n4 + 0], dA, u * bq.x);
            s[4 * n4 + 1] = fmaf(s[4 * n4 + 1], dA, u * bq.y);
            s[4 * n4 + 2] = fmaf(s[4 * n4 + 2], dA, u * bq.z);
            s[4 * n4 + 3] = fmaf(s[4 * n4 + 3], dA, u * bq.w);
        }
    }

    if (p < HEADDIM) {
        float* Sb = Sbuf + ((size_t)((b * NHEADS + h) * nchunk + c)) * (HEADDIM * 64)
                    + p * 64;
#pragma unroll
        for (int n4 = 0; n4 < 16; n4++)
            ((float4*)Sb)[n4] = make_float4(s[4 * n4], s[4 * n4 + 1],
                                            s[4 * n4 + 2], s[4 * n4 + 3]);
    }
    if (p == 0) Pd[(b * NHEADS + h) * nchunk + c] = pacc;
}

// single-step pass 1 (fallback)
__global__ __launch_bounds__(512) void ssd_state_kernel(
    const float* __restrict__ xBC, const float* __restrict__ dtb,
    const float* __restrict__ A_log, float* __restrict__ Sbuf,
    float* __restrict__ Pd, int layer, int lchunk, int nchunk)
{
    int b = blockIdx.x, c = blockIdx.y;
    int tid = threadIdx.x;
    int h = tid >> 6, p = tid & 63;
    float A = -expf(A_log[layer * NHEADS + h]);

    __shared__ float sh[2][544];
    int t0 = c * lchunk, tend = t0 + lchunk;

    {
        const float* base = xBC + (size_t)(b * SEQ + t0) * CONV_DIM;
        sh[0][tid] = base[tid];
        if (tid < 24) {
            int e2 = 512 + tid;
            sh[0][e2] = (e2 < 528) ? base[e2]
                                   : dtb[(size_t)(b * SEQ + t0) * NHEADS + (e2 - 528)];
        }
    }
    __syncthreads();

    float s[64];
#pragma unroll
    for (int n = 0; n < 64; n++) s[n] = 0.f;
    float pacc = 1.f;

    for (int t = t0; t < tend; t++) {
        int cur = (t - t0) & 1, nxt = cur ^ 1;
        float pf0 = 0.f, pf1 = 0.f;
        if (t + 1 < tend) {
            const float* base = xBC + (size_t)(b * SEQ + t + 1) * CONV_DIM;
            pf0 = base[tid];
            if (tid < 24) {
                int e2 = 512 + tid;
                pf1 = (e2 < 528) ? base[e2]
                                 : dtb[(size_t)(b * SEQ + t + 1) * NHEADS + (e2 - 528)];
            }
        }
        float dtv = sh[cur][528 + h];
        float xp  = (p < HEADDIM) ? sh[cur][h * HEADDIM + p] : 0.f;
        float dA = __expf(dtv * A);
        float u  = dtv * xp;
        pacc *= dA;
        const float4* B4 = (const float4*)&sh[cur][D_INNER];
#pragma unroll
        for (int n4 = 0; n4 < 16; n4++) {
            float4 bq = B4[n4];
            s[4 * n4 + 0] = fmaf(s[4 * n4 + 0], dA, u * bq.x);
            s[4 * n4 + 1] = fmaf(s[4 * n4 + 1], dA, u * bq.y);
            s[4 * n4 + 2] = fmaf(s[4 * n4 + 2], dA, u * bq.z);
            s[4 * n4 + 3] = fmaf(s[4 * n4 + 3], dA, u * bq.w);
        }
        if (t + 1 < tend) {
            sh[nxt][tid] = pf0;
            if (tid < 24) sh[nxt][512 + tid] = pf1;
        }
        __syncthreads();
    }

    if (p < HEADDIM) {
        float* Sb = Sbuf + ((size_t)((b * NHEADS + h) * nchunk + c)) * (HEADDIM * 64)
                    + p * 64;
#pragma unroll
        for (int n4 = 0; n4 < 16; n4++)
            ((float4*)Sb)[n4] = make_float4(s[4 * n4], s[4 * n4 + 1],
                                            s[4 * n4 + 2], s[4 * n4 + 3]);
    }
    if (p == 0) Pd[(b * NHEADS + h) * nchunk + c] = pacc;
}

// ---------------------------------------------------------------------------
// Pass 2, parallel over element tiles: grid (128 bh, 13), 256 thr.
__global__ __launch_bounds__(256) void ssd_scan2b_kernel(
    float* __restrict__ Sbuf, const float* __restrict__ Pd, int nchunk)
{
    int bh = blockIdx.x;
    int e = blockIdx.y * 256 + threadIdx.x;
    if (e >= HEADDIM * 64) return;
    float* base = Sbuf + (size_t)bh * nchunk * (HEADDIM * 64) + e;
    const float* pd = Pd + bh * nchunk;
    float cur = 0.f;
    for (int c = 0; c < nchunk; c++) {
        float l = base[(size_t)c * (HEADDIM * 64)];
        base[(size_t)c * (HEADDIM * 64)] = cur;
        cur = fmaf(pd[c], cur, l);
    }
}

// ---------------------------------------------------------------------------
// SSD fused pass 3, DUAL-CHAIN: grid (b, chunk), 256 thr = 4 waves; wave w
// runs TWO independent recurrences (heads w and w+4) over the same tokens.
// Chains share the B/C LDS panel (same tokens -> shared staging + shared LDS
// reads); states s0/s1 independent -> 2x FMA window per prefetch, chain A's
// bubbles filled by chain B. dA=exp(dt*A), u=dt*x hoisted to prefetch time.
// Writes ybf = bf16(g*gw) un-normalized + per-(token,head) ssq.
// Requires even lchunk.
__global__ __launch_bounds__(256) void ssd_out11_kernel(
    const float* __restrict__ xBC, const float* __restrict__ dtb,
    const float* __restrict__ zxbcdt, const float* __restrict__ A_log,
    const float* __restrict__ Dv, const float* __restrict__ Sbuf,
    const float* __restrict__ gw, short* __restrict__ ybf,
    float* __restrict__ ssq, int layer, int lchunk, int nchunk)
{
    int b = blockIdx.x, c = blockIdx.y;
    int tid = threadIdx.x;
    int w = tid >> 6, p = tid & 63;
    int h0 = w, h1 = w + 4;
    float A0 = -expf(A_log[layer * NHEADS + h0]);
    float A1 = -expf(A_log[layer * NHEADS + h1]);
    float Dh0 = Dv[layer * NHEADS + h0];
    float Dh1 = Dv[layer * NHEADS + h1];
    float gw0 = (p < HEADDIM) ? gw[(size_t)layer * D_INNER + h0 * HEADDIM + p] : 0.f;
    float gw1 = (p < HEADDIM) ? gw[(size_t)layer * D_INNER + h1 * HEADDIM + p] : 0.f;

    __shared__ __align__(16) float sBC[4][2][256];
    int t0 = c * lchunk;
    int npairs = lchunk >> 1;                 // lchunk even (fast path)

    const float* xb  = xBC + (size_t)(b * SEQ + t0) * CONV_DIM;
    const float* zb  = zxbcdt + (size_t)(b * SEQ + t0) * D_IN_PROJ;
    const float* dtp = dtb + (size_t)(b * SEQ + t0) * NHEADS;

    int ldtok = p >> 5;                       // token in pair
    int ldf4  = 100 + (p & 31);               // B+C = float4 idx 100..131
    int ldoff = ldtok * 128 + ((p & 31) << 2);

    float4 gvv;
    gvv = ((const float4*)(xb + (size_t)ldtok * CONV_DIM))[ldf4];
    *(float4*)&sBC[w][0][ldoff] = gvv;

    // prefetch pair 0: x (for D term), z, dt -> hoisted dA and u, both chains
    float nxA0, nxA1, nxB0, nxB1, nzA0, nzA1, nzB0, nzB1;
    float nuA0, nuA1, nuB0, nuB1, ndA_A0, ndA_A1, ndA_B0, ndA_B1;
    {
        nxA0 = (p < HEADDIM) ? xb[h0 * HEADDIM + p] : 0.f;
        nxA1 = (p < HEADDIM) ? xb[CONV_DIM + h0 * HEADDIM + p] : 0.f;
        nxB0 = (p < HEADDIM) ? xb[h1 * HEADDIM + p] : 0.f;
        nxB1 = (p < HEADDIM) ? xb[CONV_DIM + h1 * HEADDIM + p] : 0.f;
        nzA0 = (p < HEADDIM) ? zb[h0 * HEADDIM + p] : 0.f;
        nzA1 = (p < HEADDIM) ? zb[D_IN_PROJ + h0 * HEADDIM + p] : 0.f;
        nzB0 = (p < HEADDIM) ? zb[h1 * HEADDIM + p] : 0.f;
        nzB1 = (p < HEADDIM) ? zb[D_IN_PROJ + h1 * HEADDIM + p] : 0.f;
        float dA0 = dtp[h0], dA1 = dtp[NHEADS + h0];
        float dB0 = dtp[h1], dB1 = dtp[NHEADS + h1];
        ndA_A0 = __expf(dA0 * A0); nuA0 = dA0 * nxA0;
        ndA_A1 = __expf(dA1 * A0); nuA1 = dA1 * nxA1;
        ndA_B0 = __expf(dB0 * A1); nuB0 = dB0 * nxB0;
        ndA_B1 = __expf(dB1 * A1); nuB1 = dB1 * nxB1;
    }
    if (npairs > 1)
        gvv = ((const float4*)(xb + (size_t)(2 + ldtok) * CONV_DIM))[ldf4];

    float s0[64], s1[64];
    if (p < HEADDIM) {
        const float* Sb0 = Sbuf + ((size_t)((b * NHEADS + h0) * nchunk + c)) * (HEADDIM * 64)
                           + p * 64;
        const float* Sb1 = Sbuf + ((size_t)((b * NHEADS + h1) * nchunk + c)) * (HEADDIM * 64)
                           + p * 64;
#pragma unroll
        for (int n4 = 0; n4 < 16; n4++) {
            float4 v0 = ((const float4*)Sb0)[n4];
            float4 v1 = ((const float4*)Sb1)[n4];
            s0[4 * n4] = v0.x; s0[4 * n4 + 1] = v0.y; s0[4 * n4 + 2] = v0.z; s0[4 * n4 + 3] = v0.w;
            s1[4 * n4] = v1.x; s1[4 * n4 + 1] = v1.y; s1[4 * n4 + 2] = v1.z; s1[4 * n4 + 3] = v1.w;
        }
    } else {
#pragma unroll
        for (int n = 0; n < 64; n++) { s0[n] = 0.f; s1[n] = 0.f; }
    }

    for (int i = 0; i < npairs; i++) {
        int buf = i & 1;
        int t = t0 + 2 * i;
        float xA0 = nxA0, xA1 = nxA1, xB0 = nxB0, xB1 = nxB1;
        float zA0 = nzA0, zA1 = nzA1, zB0 = nzB0, zB1 = nzB1;
        float uA0 = nuA0, uA1 = nuA1, uB0 = nuB0, uB1 = nuB1;
        float dAA0 = ndA_A0, dAA1 = ndA_A1, dAB0 = ndA_B0, dAB1 = ndA_B1;
        if (i + 1 < npairs) {
            *(float4*)&sBC[w][buf ^ 1][ldoff] = gvv;              // commit pair i+1
            const float* xn = xb + (size_t)(2 * (i + 1)) * CONV_DIM;
            const float* zn = zb + (size_t)(2 * (i + 1)) * D_IN_PROJ;
            nxA0 = (p < HEADDIM) ? xn[h0 * HEADDIM + p] : 0.f;
            nxA1 = (p < HEADDIM) ? xn[CONV_DIM + h0 * HEADDIM + p] : 0.f;
            nxB0 = (p < HEADDIM) ? xn[h1 * HEADDIM + p] : 0.f;
            nxB1 = (p < HEADDIM) ? xn[CONV_DIM + h1 * HEADDIM + p] : 0.f;
            nzA0 = (p < HEADDIM) ? zn[h0 * HEADDIM + p] : 0.f;
            nzA1 = (p < HEADDIM) ? zn[D_IN_PROJ + h0 * HEADDIM + p] : 0.f;
            nzB0 = (p < HEADDIM) ? zn[h1 * HEADDIM + p] : 0.f;
            nzB1 = (p < HEADDIM) ? zn[D_IN_PROJ + h1 * HEADDIM + p] : 0.f;
            const float* dn = dtp + (size_t)(2 * (i + 1)) * NHEADS;
            float dA0 = dn[h0], dA1 = dn[NHEADS + h0];
            float dB0 = dn[h1], dB1 = dn[NHEADS + h1];
            ndA_A0 = __expf(dA0 * A0); nuA0 = dA0 * nxA0;
            ndA_A1 = __expf(dA1 * A0); nuA1 = dA1 * nxA1;
            ndA_B0 = __expf(dB0 * A1); nuB0 = dB0 * nxB0;
            ndA_B1 = __expf(dB1 * A1); nuB1 = dB1 * nxB1;
            if (i + 2 < npairs)                                    // issue pair i+2
                gvv = ((const float4*)(xb + (size_t)(2 * (i + 2) + ldtok) * CONV_DIM))[ldf4];
        }
#pragma unroll
        for (int k = 0; k < 2; k++) {
            float dA_a = k ? dAA1 : dAA0, u_a = k ? uA1 : uA0;
            float dA_b = k ? dAB1 : dAB0, u_b = k ? uB1 : uB0;
            float xp_a = k ? xA1 : xA0,  zv_a = k ? zA1 : zA0;
            float xp_b = k ? xB1 : xB0,  zv_b = k ? zB1 : zB0;
            const float4* B4 = (const float4*)&sBC[w][buf][k * 128];
            const float4* C4 = (const float4*)&sBC[w][buf][k * 128 + 64];
            float ya0 = 0.f, ya1 = 0.f, ya2 = 0.f, ya3 = 0.f;
            float yb0 = 0.f, yb1 = 0.f, yb2 = 0.f, yb3 = 0.f;
#pragma unroll
            for (int n4 = 0; n4 < 16; n4++) {
                float4 bq = B4[n4];
                float4 cq = C4[n4];
                float a0 = fmaf(s0[4 * n4 + 0], dA_a, u_a * bq.x);
                float a1 = fmaf(s0[4 * n4 + 1], dA_a, u_a * bq.y);
                float a2 = fmaf(s0[4 * n4 + 2], dA_a, u_a * bq.z);
                float a3 = fmaf(s0[4 * n4 + 3], dA_a, u_a * bq.w);
                float b0 = fmaf(s1[4 * n4 + 0], dA_b, u_b * bq.x);
                float b1 = fmaf(s1[4 * n4 + 1], dA_b, u_b * bq.y);
                float b2 = fmaf(s1[4 * n4 + 2], dA_b, u_b * bq.z);
                float b3 = fmaf(s1[4 * n4 + 3], dA_b, u_b * bq.w);
                s0[4 * n4 + 0] = a0; s0[4 * n4 + 1] = a1;
                s0[4 * n4 + 2] = a2; s0[4 * n4 + 3] = a3;
                s1[4 * n4 + 0] = b0; s1[4 * n4 + 1] = b1;
                s1[4 * n4 + 2] = b2; s1[4 * n4 + 3] = b3;
                ya0 = fmaf(a0, cq.x, ya0);
                ya1 = fmaf(a1, cq.y, ya1);
                ya2 = fmaf(a2, cq.z, ya2);
                ya3 = fmaf(a3, cq.w, ya3);
                yb0 = fmaf(b0, cq.x, yb0);
                yb1 = fmaf(b1, cq.y, yb1);
                yb2 = fmaf(b2, cq.z, yb2);
                yb3 = fmaf(b3, cq.w, yb3);
            }
            float g0 = 0.f, g1 = 0.f;
            if (p < HEADDIM) {
                float yva = fmaf(xp_a, Dh0, (ya0 + ya1) + (ya2 + ya3));
                float yvb = fmaf(xp_b, Dh1, (yb0 + yb1) + (yb2 + yb3));
                g0 = yva * (zv_a / (1.f + __expf(-zv_a)));
                g1 = yvb * (zv_b / (1.f + __expf(-zv_b)));
            }
            size_t row0 = (size_t)(b * SEQ + t + k) * 416;
            if (p < HEADDIM) {
                ybf[row0 + h0 * HEADDIM + p] = f2bf(g0 * gw0);
                ybf[row0 + h1 * HEADDIM + p] = f2bf(g1 * gw1);
            } else {
                int widx = h0 * 14 + (p - HEADDIM);
                if (widx < 16) ybf[row0 + 400 + widx] = 0;
            }
            float gs0 = g0 * g0, gs1 = g1 * g1;
#pragma unroll
            for (int o = 32; o; o >>= 1) {
                gs0 += __shfl_xor(gs0, o, 64);
                gs1 += __shfl_xor(gs1, o, 64);
            }
            if (p == 0) {
                ssq[(size_t)(b * SEQ + t + k) * NHEADS + h0] = gs0;
                ssq[(size_t)(b * SEQ + t + k) * NHEADS + h1] = gs1;
            }
        }
    }
}

// combine per-head sums -> per-token rstd for the GEMM row-scale
__global__ __launch_bounds__(256) void rstd_kernel(
    const float* __restrict__ ssq, float* __restrict__ rstdb)
{
    int m = blockIdx.x * 256 + threadIdx.x;
    if (m >= NTOK) return;
    const float4* q = (const float4*)(ssq + (size_t)m * NHEADS);
    float4 a = q[0], bq = q[1];
    float tot = ((a.x + a.y) + (a.z + a.w)) + ((bq.x + bq.y) + (bq.z + bq.w));
    rstdb[m] = rsqrtf(tot * (1.f / D_INNER) + EPS);
}

// Pass 3 (fallback, fp32 y out, single-step)
__global__ __launch_bounds__(512) void ssd_out_kernel(
    const float* __restrict__ xBC, const float* __restrict__ dtb,
    const float* __restrict__ A_log, const float* __restrict__ Dv,
    const float* __restrict__ Sbuf, float* __restrict__ y,
    int layer, int lchunk, int nchunk)
{
    int b = blockIdx.x, c = blockIdx.y;
    int tid = threadIdx.x;
    int h = tid >> 6, p = tid & 63;
    float A = -expf(A_log[layer * NHEADS + h]);
    float Dh = Dv[layer * NHEADS + h];

    __shared__ float sh[2][544];
    int t0 = c * lchunk, tend = t0 + lchunk;

    {
        const float* base = xBC + (size_t)(b * SEQ + t0) * CONV_DIM;
        sh[0][tid] = base[tid];
        if (tid < 24) {
            int e2 = 512 + tid;
            sh[0][e2] = (e2 < 528) ? base[e2]
                                   : dtb[(size_t)(b * SEQ + t0) * NHEADS + (e2 - 528)];
        }
    }

    float s[64];
    if (p < HEADDIM) {
        const float* Sb = Sbuf + ((size_t)((b * NHEADS + h) * nchunk + c)) * (HEADDIM * 64)
                          + p * 64;
#pragma unroll
        for (int n4 = 0; n4 < 16; n4++) {
            float4 v = ((const float4*)Sb)[n4];
            s[4 * n4] = v.x; s[4 * n4 + 1] = v.y; s[4 * n4 + 2] = v.z; s[4 * n4 + 3] = v.w;
        }
    } else {
#pragma unroll
        for (int n = 0; n < 64; n++) s[n] = 0.f;
    }
    __syncthreads();

    for (int t = t0; t < tend; t++) {
        int cur = (t - t0) & 1, nxt = cur ^ 1;
        float pf0 = 0.f, pf1 = 0.f;
        if (t + 1 < tend) {
            const float* base = xBC + (size_t)(b * SEQ + t + 1) * CONV_DIM;
            pf0 = base[tid];
            if (tid < 24) {
                int e2 = 512 + tid;
                pf1 = (e2 < 528) ? base[e2]
                                 : dtb[(size_t)(b * SEQ + t + 1) * NHEADS + (e2 - 528)];
            }
        }
        float dtv = sh[cur][528 + h];
        float xp  = (p < HEADDIM) ? sh[cur][h * HEADDIM + p] : 0.f;
        float dA = __expf(dtv * A);
        float u  = dtv * xp;
        const float4* B4 = (const float4*)&sh[cur][D_INNER];
        const float4* C4 = (const float4*)&sh[cur][D_INNER + D_STATE];
        float y0 = 0.f, y1 = 0.f, y2 = 0.f, y3 = 0.f;
#pragma unroll
        for (int n4 = 0; n4 < 16; n4++) {
            float4 bq = B4[n4];
            float4 cq = C4[n4];
            float t0v = fmaf(s[4 * n4 + 0], dA, u * bq.x);
            float t1v = fmaf(s[4 * n4 + 1], dA, u * bq.y);
            float t2v = fmaf(s[4 * n4 + 2], dA, u * bq.z);
            float t3v = fmaf(s[4 * n4 + 3], dA, u * bq.w);
            s[4 * n4 + 0] = t0v; s[4 * n4 + 1] = t1v;
            s[4 * n4 + 2] = t2v; s[4 * n4 + 3] = t3v;
            y0 = fmaf(t0v, cq.x, y0);
            y1 = fmaf(t1v, cq.y, y1);
            y2 = fmaf(t2v, cq.z, y2);
            y3 = fmaf(t3v, cq.w, y3);
        }
        if (p < HEADDIM) {
            float yv = (y0 + y1) + (y2 + y3);
            y[(size_t)(b * SEQ + t) * D_INNER + h * HEADDIM + p] = fmaf(xp, Dh, yv);
        }
        if (t + 1 < tend) {
            sh[nxt][tid] = pf0;
            if (tid < 24) sh[nxt][512 + tid] = pf1;
        }
        __syncthreads();
    }
}

// ---------------------------------------------------------------------------
// fallback gate+norm
__global__ __launch_bounds__(256) void gate_norm_kernel(
    float* __restrict__ y, const float* __restrict__ zxbcdt,
    const float* __restrict__ gw, short* __restrict__ ybf, int layer)
{
    int m = blockIdx.x;
    __shared__ float buf[D_INNER];
    __shared__ float red[4];
    const float* z = zxbcdt + (size_t)m * D_IN_PROJ;
    float* yr = y + (size_t)m * D_INNER;
    const float* gwl = gw + (size_t)layer * D_INNER;
    float ss = 0.f;
    for (int k = threadIdx.x; k < D_INNER; k += 256) {
        float zv = z[k];
        float sz = zv / (1.f + expf(-zv));
        float g = yr[k] * sz;
        buf[k] = g;
        ss = fmaf(g, g, ss);
    }
    int lane = threadIdx.x & 63, w = threadIdx.x >> 6;
#pragma unroll
    for (int o = 32; o; o >>= 1) ss += __shfl_xor(ss, o, 64);
    if (lane == 0) red[w] = ss;
    __syncthreads();
    float tot = red[0] + red[1] + red[2] + red[3];
    float rstd = rsqrtf(tot * (1.f / D_INNER) + EPS);
    for (int k = threadIdx.x; k < 416; k += 256) {
        if (k < D_INNER) {
            float v = buf[k] * rstd * gwl[k];
            yr[k] = v;
            if (ybf) ybf[(size_t)m * 416 + k] = f2bf(v);
        } else if (ybf) {
            ybf[(size_t)m * 416 + k] = 0;
        }
    }
}

// ---------------------------------------------------------------------------
extern "C" void kernel_launch(void* const* d_in, const int* in_sizes, int n_in,
                              void* d_out, int out_size, void* d_ws, size_t ws_size,
                              hipStream_t stream)
{
    const float* x         = (const float*)d_in[0];
    const float* pe_conv_w = (const float*)d_in[1];
    const float* proj_in_w = (const float*)d_in[2];
    const float* gn_g      = (const float*)d_in[3];
    const float* gn_b      = (const float*)d_in[4];
    const float* spec_w    = (const float*)d_in[5];
    const float* norm_w    = (const float*)d_in[6];
    const float* in_proj_w = (const float*)d_in[7];
    const float* conv_w    = (const float*)d_in[8];
    const float* conv_b    = (const float*)d_in[9];
    const float* dt_bias   = (const float*)d_in[10];
    const float* A_log     = (const float*)d_in[11];
    const float* Dv        = (const float*)d_in[12];
    const float* gnorm_w   = (const float*)d_in[13];
    const float* out_proj_w= (const float*)d_in[14];
    const float* norm_f_w  = (const float*)d_in[15];
    const float* head_w    = (const float*)d_in[16];
    const float* head_b    = (const float*)d_in[17];
    float* out = (float*)d_out;
    float* ws  = (float*)d_ws;

    // fast gate: 28,011,424 floats = 112.05 MB (prior rounds ran fast at
    // gates up to 136.4 MB on this harness).
    const size_t needA = 28011424ull * sizeof(float);
    int fast = (ws_size >= needA) ? 1 : 0;

    int nchunk, lchunk;
    float *residual = ws, *hidden = ws + 1824000;
    float *zxbcdt, *xBC, *dtb, *Sbuf, *Pd;
    float *ubuf = nullptr, *ybuf = nullptr, *ssq = nullptr, *rstdb = nullptr;
    short *w_in_bf = nullptr, *w_out_bf = nullptr, *w_head_bf = nullptr,
          *w_spec_bf = nullptr, *csmat_bf = nullptr, *x_bf = nullptr,
          *ubuf_bf = nullptr, *ybuf_bf = nullptr, *magb_bf = nullptr;

    if (fast) {
        nchunk = 15; lchunk = 38;               // 15*38 = 570 (even lchunk)
        zxbcdt = ws + 3648000;                  // 8,536,320
        xBC    = ws + 12184320;                 // 4,815,360
        dtb    = ws + 16999680;                 // 72,960
        Sbuf   = ws + 17072640;                 // 15*128*3200 = 6,144,000
        Pd     = ws + 23216640;                 // 1,920
        short* pool = (short*)(ws + 23218560);
        w_in_bf   = pool;                       // 2,515,968
        w_out_bf  = pool + 2515968;             //   998,400
        w_head_bf = pool + 3514368;             //    44,800
        w_spec_bf = pool + 3559168;             //    25,600
        ubuf_bf   = pool + 3584768;             // 2,042,880
        ybuf_bf   = pool + 5627648;             // 3,793,920 -> 9,421,568 shorts
        ssq       = ws + 27929344;              // 72,960 (NTOK*8)
        rstdb     = ws + 28002304;              // 9,120 -> end 28,011,424
        // preamble-only temporaries in the (then-dead) Sbuf region
        csmat_bf  = (short*)(Sbuf + 4000000);   //    45,248 shorts
        x_bf      = (short*)(Sbuf + 4100000);   // 2,042,880 shorts
        magb_bf   = (short*)(Sbuf + 5200000);   // 1,167,360 shorts (fits 6.14M)
    } else {
        nchunk = 6; lchunk = 95;
        ubuf   = ws + 3648000;
        zxbcdt = ws + 5472000;
        xBC    = ws + 14008320;
        dtb    = ws + 18823680;
        ybuf   = ws + 18896640;
        Sbuf   = ws + 1824000;
        Pd     = ws + 5470000;
    }

    // preamble aliases (dead layer buffers / dead Sbuf)
    float* traw  = fast ? Sbuf : ybuf;
    float* patch = zxbcdt;
    float* csout = fast ? (Sbuf + 2000000) : (xBC + 50000);
    float* csmat = xBC;                         // fallback fp32 DFT matrix
    float* magb  = fast ? nullptr : (xBC + 2000000);
    float* stats = dtb;

    // ---- weight / input casts (fast) ----
    if (fast) {
        cast_pad_kernel<<<(12 * 936 * 224 + 255) / 256, 256, 0, stream>>>(
            in_proj_w, w_in_bf, 12 * 936, 200, 224);
        cast_pad_kernel<<<(12 * 200 * 416 + 255) / 256, 256, 0, stream>>>(
            out_proj_w, w_out_bf, 12 * 200, 400, 416);
        cast_pad_kernel<<<(200 * 224 + 255) / 256, 256, 0, stream>>>(
            head_w, w_head_bf, 200, 200, 224);
        cast_pad_kernel<<<(200 * 128 + 255) / 256, 256, 0, stream>>>(
            spec_w, w_spec_bf, 200, 101, 128);
        cast_pad_kernel<<<(9120 * 224 + 255) / 256, 256, 0, stream>>>(
            x, x_bf, 9120, 200, 224);
        dft_init_bf_kernel<<<(202 * 224 + 255) / 256, 256, 0, stream>>>(csmat_bf);
    } else {
        dft_init_kernel<<<(202 * 200 + 255) / 256, 256, 0, stream>>>(csmat);
    }

    // ---- patch embed ----
    time_conv_kernel<<<NTOK, 256, 0, stream>>>(x, proj_in_w, traw);
    gn_stats_kernel<<<80, 256, 0, stream>>>(traw, stats);
    gn_gelu_kernel<<<(NTOK * 200 + 255) / 256, 256, 0, stream>>>(traw, stats, gn_g, gn_b, patch);
    if (fast) {
        gemm_bf16<<<dim3(2, 72), 256, 0, stream>>>(x_bf, csmat_bf, nullptr, nullptr, csout,
                                                   NTOK, 202, 224, 0);
        mag_bf_kernel<<<(NTOK * 128 + 255) / 256, 256, 0, stream>>>(csout, magb_bf);
        gemm_bf16<<<dim3(2, 72), 256, 0, stream>>>(magb_bf, w_spec_bf, nullptr, nullptr, patch,
                                                   NTOK, 200, 128, 1);
    } else {
        gemm_nt<<<dim3(2, 72), 256, 0, stream>>>(x, csmat, nullptr, csout, NTOK, 202, 200, 0);
        mag_kernel<<<(NTOK * NFREQ + 255) / 256, 256, 0, stream>>>(csout, magb);
        gemm_nt<<<dim3(2, 72), 256, 0, stream>>>(magb, spec_w, nullptr, patch,
                                                 NTOK, 200, NFREQ, 1);
    }
    pe_conv3_kernel<<<dim3(16, 13, 5), 256, 0, stream>>>(patch, pe_conv_w, hidden);

    // ---- layers ----
    for (int i = 0; i < N_LAYER; i++) {
        if (fast) {
            norm_dt_kernel<<<NTOK, 256, 0, stream>>>(hidden, residual, norm_w + i * 200,
                                                     ubuf_bf, in_proj_w, dt_bias, dtb,
                                                     i, (i == 0) ? 1 : 0);
            gemm_bf16<<<dim3(8, 72), 256, 0, stream>>>(
                ubuf_bf, w_in_bf + (size_t)i * 936 * 224, nullptr, nullptr, zxbcdt,
                NTOK, D_IN_PROJ, 224, 0);
        } else {
            add_rmsnorm_kernel<<<NTOK, 64, 0, stream>>>(hidden, residual, norm_w + i * 200,
                                                        ubuf, nullptr, (i == 0) ? 1 : 0);
            dt_gemv_kernel<<<NTOK / 4, 256, 0, stream>>>(ubuf, in_proj_w, dt_bias, dtb, i);
            gemm_nt<<<dim3(8, 72), 256, 0, stream>>>(
                ubuf, in_proj_w + (size_t)i * D_IN_PROJ * 200, nullptr, zxbcdt,
                NTOK, D_IN_PROJ, 200, 0);
        }
        dtconv2_kernel<<<dim3(16, 72), 256, 0, stream>>>(zxbcdt, conv_w, conv_b, xBC, i);
        {
            dim3 g(BATCH, nchunk);
            if (fast) {
                ssd_state4_kernel<<<dim3(BATCH, nchunk, 2), 256, 0, stream>>>(
                    xBC, dtb, A_log, Sbuf, Pd, i, lchunk, nchunk);
                ssd_scan2b_kernel<<<dim3(BATCH * NHEADS, 13), 256, 0, stream>>>(Sbuf, Pd, nchunk);
                ssd_out11_kernel<<<dim3(BATCH, nchunk), 256, 0, stream>>>(
                    xBC, dtb, zxbcdt, A_log, Dv, Sbuf, gnorm_w, ybuf_bf, ssq,
                    i, lchunk, nchunk);
                rstd_kernel<<<(NTOK + 255) / 256, 256, 0, stream>>>(ssq, rstdb);
                gemm_bf16<<<dim3(2, 72), 256, 0, stream>>>(
                    ybuf_bf, w_out_bf + (size_t)i * 200 * 416, nullptr, rstdb, hidden,
                    NTOK, 200, 416, 0);
            } else {
                ssd_state_kernel<<<g, 512, 0, stream>>>(xBC, dtb, A_log, Sbuf, Pd,
                                                        i, lchunk, nchunk);
                ssd_scan2b_kernel<<<dim3(BATCH * NHEADS, 13), 256, 0, stream>>>(Sbuf, Pd, nchunk);
                ssd_out_kernel<<<g, 512, 0, stream>>>(xBC, dtb, A_log, Dv, Sbuf, ybuf,
                                                      i, lchunk, nchunk);
                gate_norm_kernel<<<NTOK, 256, 0, stream>>>(ybuf, zxbcdt, gnorm_w, nullptr, i);
                gemm_nt<<<dim3(2, 72), 256, 0, stream>>>(
                    ybuf, out_proj_w + (size_t)i * 200 * D_INNER, nullptr, hidden,
                    NTOK, 200, D_INNER, 0);
            }
        }
    }

    // ---- final norm + head ----
    add_rmsnorm_kernel<<<NTOK, 64, 0, stream>>>(hidden, residual, norm_f_w,
                                                fast ? nullptr : ubuf,
                                                fast ? ubuf_bf : nullptr, 0);
    if (fast) {
        gemm_bf16<<<dim3(2, 72), 256, 0, stream>>>(ubuf_bf, w_head_bf, head_b, nullptr, out,
                                                   NTOK, 200, 224, 0);
    } else {
        gemm_nt<<<dim3(2, 72), 256, 0, stream>>>(ubuf, head_w, head_b, out,
                                                 NTOK, 200, 200, 0);
    }
}

// Round 12
// 2426.334 us; speedup vs baseline: 1.0192x; 1.0192x over previous
//
#include <hip/hip_runtime.h>
#include <hip/hip_bf16.h>
#include <math.h>

// ---------------------------------------------------------------------------
// EEGMamba forward. Round 21: consolidation — revert to the measured-best
// configuration (R12/R18, 2432 us twice-reproduced): pass 1 = ssd_state4
// (barrier-staged 4-head blocks), pass 3 = ssd_out7 (per-wave autonomous
// 2-deep prefetch), nchunk=15, rstd row-scale in out-proj GEMM epilogue.
// R20's dual-chain was a null (ILP/TLP trade canceled exactly: occ 17.8->9.5,
// VALUBusy 46->29.5, dur unchanged). Nine pass-3 structures converge at
// 60±6 us — latency-bound plateau at this algorithm shape.
#define D_MODEL   200
#define N_LAYER   12
#define NHEADS    8
#define HEADDIM   50
#define D_STATE   64
#define D_INNER   400
#define CONV_DIM  528
#define D_IN_PROJ 936
#define D_CONV    4
#define EPS       1e-5f

#define BATCH 16
#define CH    19
#define LLEN  30
#define SEQ   570
#define NTOK  9120
#define NFREQ 101

typedef __attribute__((ext_vector_type(8))) short s8v;
typedef __attribute__((ext_vector_type(4))) float f32x4;

__device__ __forceinline__ short f2bf(float f) {
    unsigned u = __float_as_uint(f);
    u += 0x7FFFu + ((u >> 16) & 1u);      // RNE
    return (short)(u >> 16);
}

// ---------------------------------------------------------------------------
// bf16 MFMA GEMM: C[M,N] = rowscale[m] * (A[M,Kp] @ W[N,Kp]^T) (+bias) (+C)
__global__ __launch_bounds__(256) void gemm_bf16(
    const short* __restrict__ A, const short* __restrict__ W,
    const float* __restrict__ bias, const float* __restrict__ rowscale,
    float* __restrict__ C, int M, int N, int Kp, int accum)
{
    __shared__ __align__(16) short As[128][40];
    __shared__ __align__(16) short Ws[128][40];

    int bm = blockIdx.y * 128;
    int bn = blockIdx.x * 128;
    int tid = threadIdx.x;
    int lane = tid & 63;
    int wv = tid >> 6;
    int wm = wv & 1, wn = wv >> 1;
    int lm = lane & 15, lg = lane >> 4;

    int sr = tid >> 1;
    int sh_ = (tid & 1) * 16;

    f32x4 acc[4][4];
#pragma unroll
    for (int i = 0; i < 4; i++)
#pragma unroll
        for (int j = 0; j < 4; j++) acc[i][j] = (f32x4)0.f;

    for (int k0 = 0; k0 < Kp; k0 += 32) {
        {
            s8v v0 = (s8v)0, v1 = (s8v)0;
            if (bm + sr < M) {
                const short* ga = A + (size_t)(bm + sr) * Kp + k0 + sh_;
                v0 = *(const s8v*)ga;
                v1 = *(const s8v*)(ga + 8);
            }
            *(s8v*)&As[sr][sh_] = v0;
            *(s8v*)&As[sr][sh_ + 8] = v1;
        }
        {
            s8v v0 = (s8v)0, v1 = (s8v)0;
            if (bn + sr < N) {
                const short* gw = W + (size_t)(bn + sr) * Kp + k0 + sh_;
                v0 = *(const s8v*)gw;
                v1 = *(const s8v*)(gw + 8);
            }
            *(s8v*)&Ws[sr][sh_] = v0;
            *(s8v*)&Ws[sr][sh_ + 8] = v1;
        }
        __syncthreads();

        s8v af[4], bf[4];
#pragma unroll
        for (int i = 0; i < 4; i++)
            af[i] = *(const s8v*)&As[wm * 64 + i * 16 + lm][lg * 8];
#pragma unroll
        for (int j = 0; j < 4; j++)
            bf[j] = *(const s8v*)&Ws[wn * 64 + j * 16 + lm][lg * 8];
#pragma unroll
        for (int i = 0; i < 4; i++)
#pragma unroll
            for (int j = 0; j < 4; j++)
                acc[i][j] = __builtin_amdgcn_mfma_f32_16x16x32_bf16(
                    af[i], bf[j], acc[i][j], 0, 0, 0);
        __syncthreads();
    }

#pragma unroll
    for (int j = 0; j < 4; j++) {
        int n = bn + wn * 64 + j * 16 + lm;
        if (n >= N) continue;
        float bv = bias ? bias[n] : 0.f;
#pragma unroll
        for (int i = 0; i < 4; i++) {
            int mbase = bm + wm * 64 + i * 16 + lg * 4;
#pragma unroll
            for (int r = 0; r < 4; r++) {
                int m = mbase + r;
                if (m >= M) continue;
                size_t idx = (size_t)m * N + n;
                float v = acc[i][j][r];
                if (rowscale) v *= rowscale[m];
                v += bv;
                if (accum) v += C[idx];
                C[idx] = v;
            }
        }
    }
}

// ---------------------------------------------------------------------------
// fp32 GEMM (fallback path)
__global__ __launch_bounds__(256) void gemm_nt(
    const float* __restrict__ A, const float* __restrict__ W,
    const float* __restrict__ bias, float* __restrict__ C,
    int M, int N, int K, int accum)
{
    const int BM = 128, BK = 16;
    __shared__ float As[16][BM + 4];
    __shared__ float Ws[16][BM + 4];

    int bm = blockIdx.y * BM;
    int bn = blockIdx.x * BM;
    int tid = threadIdx.x;
    int lr = tid >> 1;
    int lc = (tid & 1) * 8;
    int tx = tid & 15;
    int ty = tid >> 4;

    float acc[8][8];
#pragma unroll
    for (int i = 0; i < 8; i++)
#pragma unroll
        for (int j = 0; j < 8; j++) acc[i][j] = 0.f;

    for (int k0 = 0; k0 < K; k0 += BK) {
#pragma unroll
        for (int i = 0; i < 8; i++) {
            int gr = bm + lr, gk = k0 + lc + i;
            As[lc + i][lr] = (gr < M && gk < K) ? A[(size_t)gr * K + gk] : 0.f;
        }
#pragma unroll
        for (int i = 0; i < 8; i++) {
            int gr = bn + lr, gk = k0 + lc + i;
            Ws[lc + i][lr] = (gr < N && gk < K) ? W[(size_t)gr * K + gk] : 0.f;
        }
        __syncthreads();
#pragma unroll
        for (int kk = 0; kk < BK; kk++) {
            float a[8], bv[8];
#pragma unroll
            for (int i = 0; i < 8; i++) a[i] = As[kk][ty * 8 + i];
#pragma unroll
            for (int j = 0; j < 8; j++) bv[j] = Ws[kk][tx * 8 + j];
#pragma unroll
            for (int i = 0; i < 8; i++)
#pragma unroll
                for (int j = 0; j < 8; j++)
                    acc[i][j] = fmaf(a[i], bv[j], acc[i][j]);
        }
        __syncthreads();
    }

#pragma unroll
    for (int i = 0; i < 8; i++) {
        int gm = bm + ty * 8 + i;
        if (gm >= M) continue;
#pragma unroll
        for (int j = 0; j < 8; j++) {
            int gn = bn + tx * 8 + j;
            if (gn >= N) continue;
            float v = acc[i][j];
            if (bias) v += bias[gn];
            if (accum) v += C[(size_t)gm * N + gn];
            C[(size_t)gm * N + gn] = v;
        }
    }
}

// ---------------------------------------------------------------------------
__global__ __launch_bounds__(256) void cast_pad_kernel(
    const float* __restrict__ src, short* __restrict__ dst,
    int R, int K, int Kp)
{
    int idx = blockIdx.x * 256 + threadIdx.x;
    if (idx >= R * Kp) return;
    int r = idx / Kp, k = idx - r * Kp;
    dst[idx] = (k < K) ? f2bf(src[(size_t)r * K + k]) : (short)0;
}

// ---------------------------------------------------------------------------
__global__ __launch_bounds__(256) void time_conv_kernel(
    const float* __restrict__ x, const float* __restrict__ pw,
    float* __restrict__ traw)
{
    int br = blockIdx.x;
    __shared__ float xr[200];
    if (threadIdx.x < 200) xr[threadIdx.x] = x[(size_t)br * 200 + threadIdx.x];
    __syncthreads();
    if (threadIdx.x < 200) {
        int oc = threadIdx.x >> 3, j = threadIdx.x & 7;
        int start = j * 25 - 24;
        float acc = 0.f;
#pragma unroll
        for (int k = 0; k < 49; k++) {
            int d = start + k;
            if (d >= 0 && d < 200) acc = fmaf(xr[d], pw[oc * 49 + k], acc);
        }
        int b = br / SEQ, row = br % SEQ;
        traw[(((size_t)b * 25 + oc) * SEQ + row) * 8 + j] = acc;
    }
}

__global__ __launch_bounds__(256) void gn_stats_kernel(
    const float* __restrict__ traw, float* __restrict__ stats)
{
    int bg = blockIdx.x;
    int b = bg / 5, g = bg % 5;
    const float* base = traw + ((size_t)b * 25 + g * 5) * SEQ * 8;
    float s = 0.f, q = 0.f;
    for (int i = threadIdx.x; i < 5 * SEQ * 8; i += 256) {
        float v = base[i];
        s += v; q = fmaf(v, v, q);
    }
    __shared__ float rs[4], rq[4];
    int lane = threadIdx.x & 63, w = threadIdx.x >> 6;
#pragma unroll
    for (int o = 32; o; o >>= 1) { s += __shfl_xor(s, o, 64); q += __shfl_xor(q, o, 64); }
    if (lane == 0) { rs[w] = s; rq[w] = q; }
    __syncthreads();
    if (threadIdx.x == 0) {
        float S = rs[0] + rs[1] + rs[2] + rs[3];
        float Q = rq[0] + rq[1] + rq[2] + rq[3];
        float inv = 1.f / (5.f * SEQ * 8.f);
        float mean = S * inv;
        float var = Q * inv - mean * mean;
        stats[bg * 2] = mean;
        stats[bg * 2 + 1] = rsqrtf(var + EPS);
    }
}

__global__ __launch_bounds__(256) void gn_gelu_kernel(
    const float* __restrict__ traw, const float* __restrict__ stats,
    const float* __restrict__ gn_g, const float* __restrict__ gn_b,
    float* __restrict__ patch)
{
    int idx = blockIdx.x * 256 + threadIdx.x;
    if (idx >= NTOK * 200) return;
    int d = idx % 200;
    int row = (idx / 200) % SEQ;
    int b = idx / (200 * SEQ);
    int oc = d >> 3, j = d & 7;
    float v = traw[(((size_t)b * 25 + oc) * SEQ + row) * 8 + j];
    int g = oc / 5;
    float mean = stats[(b * 5 + g) * 2];
    float rstd = stats[(b * 5 + g) * 2 + 1];
    v = (v - mean) * rstd * gn_g[oc] + gn_b[oc];
    float ge = 0.5f * v * (1.f + erff(v * 0.70710678118654752f));
    patch[idx] = ge;
}

__global__ __launch_bounds__(256) void dft_init_kernel(float* __restrict__ CS)
{
    int idx = blockIdx.x * 256 + threadIdx.x;
    if (idx >= 202 * 200) return;
    int f = idx / 200, d = idx % 200;
    int fr = (f < NFREQ) ? f : (f - NFREQ);
    int m = (fr * d) % 200;
    float ang = -6.283185307179586f * (float)m * (1.f / 200.f);
    CS[idx] = (f < NFREQ) ? cosf(ang) : sinf(ang);
}

__global__ __launch_bounds__(256) void dft_init_bf_kernel(short* __restrict__ CS)
{
    int idx = blockIdx.x * 256 + threadIdx.x;
    if (idx >= 202 * 224) return;
    int f = idx / 224, d = idx - f * 224;
    short out = 0;
    if (d < 200) {
        int fr = (f < NFREQ) ? f : (f - NFREQ);
        int m = (fr * d) % 200;
        float ang = -6.283185307179586f * (float)m * (1.f / 200.f);
        out = f2bf((f < NFREQ) ? cosf(ang) : sinf(ang));
    }
    CS[idx] = out;
}

__global__ __launch_bounds__(256) void mag_kernel(
    const float* __restrict__ cs_out, float* __restrict__ magv)
{
    int idx = blockIdx.x * 256 + threadIdx.x;
    if (idx >= NTOK * NFREQ) return;
    int m = idx / NFREQ, f = idx % NFREQ;
    float re = cs_out[(size_t)m * 202 + f];
    float im = cs_out[(size_t)m * 202 + NFREQ + f];
    magv[idx] = sqrtf(re * re + im * im) * 0.005f;
}

__global__ __launch_bounds__(256) void mag_bf_kernel(
    const float* __restrict__ cs_out, short* __restrict__ magv)
{
    int idx = blockIdx.x * 256 + threadIdx.x;
    if (idx >= NTOK * 128) return;
    int m = idx >> 7, f = idx & 127;
    short out = 0;
    if (f < NFREQ) {
        float re = cs_out[(size_t)m * 202 + f];
        float im = cs_out[(size_t)m * 202 + NFREQ + f];
        out = f2bf(sqrtf(re * re + im * im) * 0.005f);
    }
    magv[idx] = out;
}

// ---------------------------------------------------------------------------
// depthwise 7x7 pos conv + residual. block = (b, 16-d slice, 4-c tile+halo)
__global__ __launch_bounds__(256) void pe_conv3_kernel(
    const float* __restrict__ patch, const float* __restrict__ pw,
    float* __restrict__ hidden)
{
    int b = blockIdx.x, dc = blockIdx.y, ct = blockIdx.z;
    int d0 = dc * 16, c0 = ct * 4;
    __shared__ float pl[10 * 30 * 16];
    __shared__ float wl[49 * 16];
    int tid = threadIdx.x;
    int dd = tid & 15;
    int d = d0 + dd;

    for (int i = tid; i < 10 * 30 * 16; i += 256) {
        int ddl = i & 15, r = i >> 4;
        int l = r % 30, cr = r / 30;
        int cc = c0 + cr - 3, dl = d0 + ddl;
        pl[i] = (cc >= 0 && cc < CH && dl < 200)
                    ? patch[((size_t)(b * CH + cc) * LLEN + l) * 200 + dl] : 0.f;
    }
    for (int i = tid; i < 49 * 16; i += 256) {
        int k = i >> 4, dl = d0 + (i & 15);
        wl[i] = (dl < 200) ? pw[(size_t)dl * 49 + k] : 0.f;
    }
    __syncthreads();

    float wreg[49];
#pragma unroll
    for (int k = 0; k < 49; k++) wreg[k] = wl[k * 16 + dd];

    for (int o = tid; o < 4 * 30 * 16; o += 256) {
        int r2 = o >> 4;
        int l = r2 % 30, ci = r2 / 30;
        int c = c0 + ci;
        if (c >= CH) continue;
        float acc = pl[((ci + 3) * 30 + l) * 16 + dd];
#pragma unroll
        for (int i = 0; i < 7; i++) {
#pragma unroll
            for (int j = 0; j < 7; j++) {
                int ll = l + j - 3;
                if (ll < 0 || ll >= LLEN) continue;
                acc = fmaf(pl[((ci + i) * 30 + ll) * 16 + dd], wreg[i * 7 + j], acc);
            }
        }
        if (d < 200) hidden[((size_t)(b * CH + c) * LLEN + l) * 200 + d] = acc;
    }
}

// ---------------------------------------------------------------------------
__global__ __launch_bounds__(64) void add_rmsnorm_kernel(
    const float* __restrict__ hidden, float* __restrict__ residual,
    const float* __restrict__ wn, float* __restrict__ u,
    short* __restrict__ ubf, int first)
{
    int m = blockIdx.x;
    int lane = threadIdx.x;
    const float* hr = hidden + (size_t)m * 200;
    float* rr = residual + (size_t)m * 200;
    float v[4];
    float ss = 0.f;
#pragma unroll
    for (int i = 0; i < 4; i++) {
        int k = lane + i * 64;
        float xv = 0.f;
        if (k < 200) {
            xv = hr[k] + (first ? 0.f : rr[k]);
            rr[k] = xv;
        }
        v[i] = xv;
        ss = fmaf(xv, xv, ss);
    }
#pragma unroll
    for (int o = 32; o; o >>= 1) ss += __shfl_xor(ss, o, 64);
    float rstd = rsqrtf(ss * (1.f / 200.f) + EPS);
#pragma unroll
    for (int i = 0; i < 4; i++) {
        int k = lane + i * 64;
        float val = v[i] * rstd * ((k < 200) ? wn[k] : 0.f);
        if (k < 200 && u) u[(size_t)m * 200 + k] = val;
        if (ubf) {
            if (k < 200) ubf[(size_t)m * 224 + k] = f2bf(val);
            else if (k < 224) ubf[(size_t)m * 224 + k] = 0;
        }
    }
}

// ---------------------------------------------------------------------------
// Fused: residual += hidden; u = rmsnorm*wn -> ubf; dt GEMV fp32.
__global__ __launch_bounds__(256) void norm_dt_kernel(
    const float* __restrict__ hidden, float* __restrict__ residual,
    const float* __restrict__ wn, short* __restrict__ ubf,
    const float* __restrict__ Win, const float* __restrict__ dt_bias,
    float* __restrict__ dtb, int layer, int first)
{
    int m = blockIdx.x;
    int tid = threadIdx.x;
    __shared__ float su[200];
    __shared__ float rs[4];
    float xv = 0.f;
    if (tid < 200) {
        xv = hidden[(size_t)m * 200 + tid] + (first ? 0.f : residual[(size_t)m * 200 + tid]);
        residual[(size_t)m * 200 + tid] = xv;
    }
    float ss = xv * xv;
#pragma unroll
    for (int o = 32; o; o >>= 1) ss += __shfl_xor(ss, o, 64);
    int lane = tid & 63, w = tid >> 6;
    if (lane == 0) rs[w] = ss;
    __syncthreads();
    float rstd = rsqrtf((rs[0] + rs[1] + rs[2] + rs[3]) * (1.f / 200.f) + EPS);
    if (tid < 200) {
        float val = xv * rstd * wn[tid];
        su[tid] = val;
        ubf[(size_t)m * 224 + tid] = f2bf(val);
    } else if (tid < 224) {
        ubf[(size_t)m * 224 + tid] = 0;
    }
    __syncthreads();
    int h = tid >> 5, l = tid & 31;
    const float* wr = Win + (size_t)layer * D_IN_PROJ * 200 + (size_t)(928 + h) * 200;
    float s = 0.f;
    for (int k = l; k < 200; k += 32) s = fmaf(su[k], wr[k], s);
    s += __shfl_xor(s, 16, 32);
    s += __shfl_xor(s, 8, 32);
    s += __shfl_xor(s, 4, 32);
    s += __shfl_xor(s, 2, 32);
    s += __shfl_xor(s, 1, 32);
    if (l == 0) {
        float raw = s + dt_bias[layer * NHEADS + h];
        dtb[(size_t)m * NHEADS + h] = (raw > 20.f) ? raw : log1pf(expf(raw));
    }
}

// fp32 dt GEMV (fallback)
__global__ __launch_bounds__(256) void dt_gemv_kernel(
    const float* __restrict__ u, const float* __restrict__ Win,
    const float* __restrict__ dt_bias, float* __restrict__ dtb, int layer)
{
    int tid = threadIdx.x;
    int tok = blockIdx.x * 4 + (tid >> 6);
    int head = (tid >> 3) & 7;
    int l8 = tid & 7;
    const float* ur = u + (size_t)tok * 200;
    const float* wr = Win + (size_t)layer * D_IN_PROJ * 200 + (size_t)(928 + head) * 200;
    float s = 0.f;
    for (int k = l8; k < 200; k += 8) s = fmaf(ur[k], wr[k], s);
    s += __shfl_xor(s, 1, 64);
    s += __shfl_xor(s, 2, 64);
    s += __shfl_xor(s, 4, 64);
    if (l8 == 0) {
        float raw = s + dt_bias[layer * NHEADS + head];
        dtb[(size_t)tok * NHEADS + head] = (raw > 20.f) ? raw : log1pf(expf(raw));
    }
}

// ---------------------------------------------------------------------------
// xBC = silu(causal depthwise conv4), t-tiled
__global__ __launch_bounds__(256) void dtconv2_kernel(
    const float* __restrict__ zxbcdt, const float* __restrict__ cw,
    const float* __restrict__ cb, float* __restrict__ xBC, int layer)
{
    int b = blockIdx.x, tt = blockIdx.y;
    int t0 = tt * 8;
    __shared__ float zs[11][528];
    const float* cwl = cw + (size_t)layer * CONV_DIM * 4;
    const float* cbl = cb + (size_t)layer * CONV_DIM;
    for (int i = threadIdx.x; i < 11 * 528; i += 256) {
        int r = i / 528, ch = i - r * 528;
        int t = t0 - 3 + r;
        zs[r][ch] = (t >= 0 && t < SEQ)
                        ? zxbcdt[(size_t)(b * SEQ + t) * D_IN_PROJ + D_INNER + ch] : 0.f;
    }
    __syncthreads();
    for (int o = threadIdx.x; o < 8 * 528; o += 256) {
        int tr = o / 528, ch = o - tr * 528;
        int t = t0 + tr;
        if (t >= SEQ) continue;
        float acc = cbl[ch];
#pragma unroll
        for (int k = 0; k < 4; k++)
            acc = fmaf(zs[tr + k][ch], cwl[ch * 4 + k], acc);
        xBC[(size_t)(b * SEQ + t) * CONV_DIM + ch] = acc / (1.f + __expf(-acc));
    }
}

// ---------------------------------------------------------------------------
// SSD pass 1, 4 heads per 256-thr block: grid (b, chunk, half). Each block
// stages only its 4 heads' x slice (200 f) + B (64 f) + 4 dt. wave = head,
// lane = p. (R12's fastest pass-1 variant.)
__global__ __launch_bounds__(256) void ssd_state4_kernel(
    const float* __restrict__ xBC, const float* __restrict__ dtb,
    const float* __restrict__ A_log, float* __restrict__ Sbuf,
    float* __restrict__ Pd, int layer, int lchunk, int nchunk)
{
    int b = blockIdx.x, c = blockIdx.y, bz = blockIdx.z;
    int tid = threadIdx.x;
    int hl = tid >> 6, p = tid & 63;
    int h = bz * 4 + hl;
    float A = -expf(A_log[layer * NHEADS + h]);

    // per token: x slice [0,200), B [200,264), dt [264,268); pad to 272
    __shared__ __align__(16) float sh[2][2][272];
    int t0 = c * lchunk;
    int npairs = lchunk >> 1, rem = lchunk & 1;

    {
        if (tid < 132) {
            int tok = (tid >= 66) ? 1 : 0;
            int fidx = tid - tok * 66;
            int g = (fidx < 50) ? (50 * bz + fidx) : (fidx + 50);
            float4 v = ((const float4*)(xBC + (size_t)(b * SEQ + t0 + tok) * CONV_DIM))[g];
            *(float4*)&sh[0][tok][fidx * 4] = v;
        } else if (tid < 140) {
            int e = tid - 132, tok = e >> 2, hd = e & 3;
            sh[0][tok][264 + hd] = dtb[(size_t)(b * SEQ + t0 + tok) * NHEADS + bz * 4 + hd];
        }
    }
    __syncthreads();

    float s[64];
#pragma unroll
    for (int n = 0; n < 64; n++) s[n] = 0.f;
    float pacc = 1.f;

    for (int i = 0; i < npairs; i++) {
        int t = t0 + 2 * i;
        int buf = i & 1, nb = buf ^ 1;
        bool pf = (2 * i + 2 < lchunk);
        float4 rx;
        float rdt = 0.f;
        int tok = 0, fidx = 0;
        if (pf) {
            if (tid < 132) {
                tok = (tid >= 66) ? 1 : 0;
                fidx = tid - tok * 66;
                int tq = t + 2 + tok; if (tq > SEQ - 1) tq = SEQ - 1;
                int g = (fidx < 50) ? (50 * bz + fidx) : (fidx + 50);
                rx = ((const float4*)(xBC + (size_t)(b * SEQ + tq) * CONV_DIM))[g];
            } else if (tid < 140) {
                int e = tid - 132, tk = e >> 2, hd = e & 3;
                int tq = t + 2 + tk; if (tq > SEQ - 1) tq = SEQ - 1;
                rdt = dtb[(size_t)(b * SEQ + tq) * NHEADS + bz * 4 + hd];
            }
        }
#pragma unroll
        for (int k = 0; k < 2; k++) {
            float dtv = sh[buf][k][264 + hl];
            float xp  = (p < HEADDIM) ? sh[buf][k][hl * HEADDIM + p] : 0.f;
            float dA = __expf(dtv * A);
            float u  = dtv * xp;
            pacc *= dA;
            const float4* B4 = (const float4*)&sh[buf][k][200];
#pragma unroll
            for (int n4 = 0; n4 < 16; n4++) {
                float4 bq = B4[n4];
                s[4 * n4 + 0] = fmaf(s[4 * n4 + 0], dA, u * bq.x);
                s[4 * n4 + 1] = fmaf(s[4 * n4 + 1], dA, u * bq.y);
                s[4 * n4 + 2] = fmaf(s[4 * n4 + 2], dA, u * bq.z);
                s[4 * n4 + 3] = fmaf(s[4 * n4 + 3], dA, u * bq.w);
            }
        }
        if (pf) {
            if (tid < 132) *(float4*)&sh[nb][tok][fidx * 4] = rx;
            else if (tid < 140) { int e = tid - 132; sh[nb][e >> 2][264 + (e & 3)] = rdt; }
        }
        __syncthreads();
    }

    if (rem) {
        int buf = npairs & 1;
        float dtv = sh[buf][0][264 + hl];
        float xp  = (p < HEADDIM) ? sh[buf][0][hl * HEADDIM + p] : 0.f;
        float dA = __expf(dtv * A);
        float u  = dtv * xp;
        pacc *= dA;
        const float4* B4 = (const float4*)&sh[buf][0][200];
#pragma unroll
        for (int n4 = 0; n4 < 16; n4++) {
            float4 bq = B4[n4];
            s[4 * n4 + 0] = fmaf(s[4 * n4 + 0], dA, u * bq.x);
            s[4 * n4 + 1] = fmaf(s[4 * n4 + 1], dA, u * bq.y);
            s[4 * n4 + 2] = fmaf(s[4 * n4 + 2], dA, u * bq.z);
            s[4 * n4 + 3] = fmaf(s[4 * n4 + 3], dA, u * bq.w);
        }
    }

    if (p < HEADDIM) {
        float* Sb = Sbuf + ((size_t)((b * NHEADS + h) * nchunk + c)) * (HEADDIM * 64)
                    + p * 64;
#pragma unroll
        for (int n4 = 0; n4 < 16; n4++)
            ((float4*)Sb)[n4] = make_float4(s[4 * n4], s[4 * n4 + 1],
                                            s[4 * n4 + 2], s[4 * n4 + 3]);
    }
    if (p == 0) Pd[(b * NHEADS + h) * nchunk + c] = pacc;
}

// single-step pass 1 (fallback)
__global__ __launch_bounds__(512) void ssd_state_kernel(
    const float* __restrict__ xBC, const float* __restrict__ dtb,
    const float* __restrict__ A_log, float* __restrict__ Sbuf,
    float* __restrict__ Pd, int layer, int lchunk, int nchunk)
{
    int b = blockIdx.x, c = blockIdx.y;
    int tid = threadIdx.x;
    int h = tid >> 6, p = tid & 63;
    float A = -expf(A_log[layer * NHEADS + h]);

    __shared__ float sh[2][544];
    int t0 = c * lchunk, tend = t0 + lchunk;

    {
        const float* base = xBC + (size_t)(b * SEQ + t0) * CONV_DIM;
        sh[0][tid] = base[tid];
        if (tid < 24) {
            int e2 = 512 + tid;
            sh[0][e2] = (e2 < 528) ? base[e2]
                                   : dtb[(size_t)(b * SEQ + t0) * NHEADS + (e2 - 528)];
        }
    }
    __syncthreads();

    float s[64];
#pragma unroll
    for (int n = 0; n < 64; n++) s[n] = 0.f;
    float pacc = 1.f;

    for (int t = t0; t < tend; t++) {
        int cur = (t - t0) & 1, nxt = cur ^ 1;
        float pf0 = 0.f, pf1 = 0.f;
        if (t + 1 < tend) {
            const float* base = xBC + (size_t)(b * SEQ + t + 1) * CONV_DIM;
            pf0 = base[tid];
            if (tid < 24) {
                int e2 = 512 + tid;
                pf1 = (e2 < 528) ? base[e2]
                                 : dtb[(size_t)(b * SEQ + t + 1) * NHEADS + (e2 - 528)];
            }
        }
        float dtv = sh[cur][528 + h];
        float xp  = (p < HEADDIM) ? sh[cur][h * HEADDIM + p] : 0.f;
        float dA = __expf(dtv * A);
        float u  = dtv * xp;
        pacc *= dA;
        const float4* B4 = (const float4*)&sh[cur][D_INNER];
#pragma unroll
        for (int n4 = 0; n4 < 16; n4++) {
            float4 bq = B4[n4];
            s[4 * n4 + 0] = fmaf(s[4 * n4 + 0], dA, u * bq.x);
            s[4 * n4 + 1] = fmaf(s[4 * n4 + 1], dA, u * bq.y);
            s[4 * n4 + 2] = fmaf(s[4 * n4 + 2], dA, u * bq.z);
            s[4 * n4 + 3] = fmaf(s[4 * n4 + 3], dA, u * bq.w);
        }
        if (t + 1 < tend) {
            sh[nxt][tid] = pf0;
            if (tid < 24) sh[nxt][512 + tid] = pf1;
        }
        __syncthreads();
    }

    if (p < HEADDIM) {
        float* Sb = Sbuf + ((size_t)((b * NHEADS + h) * nchunk + c)) * (HEADDIM * 64)
                    + p * 64;
#pragma unroll
        for (int n4 = 0; n4 < 16; n4++)
            ((float4*)Sb)[n4] = make_float4(s[4 * n4], s[4 * n4 + 1],
                                            s[4 * n4 + 2], s[4 * n4 + 3]);
    }
    if (p == 0) Pd[(b * NHEADS + h) * nchunk + c] = pacc;
}

// ---------------------------------------------------------------------------
// Pass 2, parallel over element tiles: grid (128 bh, 13), 256 thr.
__global__ __launch_bounds__(256) void ssd_scan2b_kernel(
    float* __restrict__ Sbuf, const float* __restrict__ Pd, int nchunk)
{
    int bh = blockIdx.x;
    int e = blockIdx.y * 256 + threadIdx.x;
    if (e >= HEADDIM * 64) return;
    float* base = Sbuf + (size_t)bh * nchunk * (HEADDIM * 64) + e;
    const float* pd = Pd + bh * nchunk;
    float cur = 0.f;
    for (int c = 0; c < nchunk; c++) {
        float l = base[(size_t)c * (HEADDIM * 64)];
        base[(size_t)c * (HEADDIM * 64)] = cur;
        cur = fmaf(pd[c], cur, l);
    }
}

// ---------------------------------------------------------------------------
// SSD fused pass 3, per-wave autonomous with 2-deep prefetch. grid
// (b, chunk, half), 4 independent waves, wave = head, no barriers.
// B+C pair = exactly 1 float4 per lane (64 lanes x 16B = 2 tokens x 128 f).
// Writes ybf = bf16(g*gw) un-normalized + per-(token,head) ssq.
// Requires even lchunk. (R15's fastest pass-3 variant.)
__global__ __launch_bounds__(256) void ssd_out7_kernel(
    const float* __restrict__ xBC, const float* __restrict__ dtb,
    const float* __restrict__ zxbcdt, const float* __restrict__ A_log,
    const float* __restrict__ Dv, const float* __restrict__ Sbuf,
    const float* __restrict__ gw, short* __restrict__ ybf,
    float* __restrict__ ssq, int layer, int lchunk, int nchunk)
{
    int b = blockIdx.x, c = blockIdx.y, bz = blockIdx.z;
    int tid = threadIdx.x;
    int hl = tid >> 6, p = tid & 63;
    int h = bz * 4 + hl;
    float A = -expf(A_log[layer * NHEADS + h]);
    float Dh = Dv[layer * NHEADS + h];
    float gval = (p < HEADDIM) ? gw[(size_t)layer * D_INNER + h * HEADDIM + p] : 0.f;

    __shared__ __align__(16) float sBC[4][2][256];
    int t0 = c * lchunk;
    int npairs = lchunk >> 1;                 // lchunk even (fast path)

    const float* xb  = xBC + (size_t)(b * SEQ + t0) * CONV_DIM;
    const float* zb  = zxbcdt + (size_t)(b * SEQ + t0) * D_IN_PROJ;
    const float* dtp = dtb + (size_t)(b * SEQ + t0) * NHEADS + h;

    int ldtok = p >> 5;                       // token in pair
    int ldf4  = 100 + (p & 31);               // B+C = float4 idx 100..131
    int ldoff = ldtok * 128 + ((p & 31) << 2);

    float4 gv;
    gv = ((const float4*)(xb + (size_t)ldtok * CONV_DIM))[ldf4];
    *(float4*)&sBC[hl][0][ldoff] = gv;
    float nx0 = (p < HEADDIM) ? xb[h * HEADDIM + p] : 0.f;
    float nx1 = (p < HEADDIM) ? xb[CONV_DIM + h * HEADDIM + p] : 0.f;
    float nz0 = (p < HEADDIM) ? zb[h * HEADDIM + p] : 0.f;
    float nz1 = (p < HEADDIM) ? zb[D_IN_PROJ + h * HEADDIM + p] : 0.f;
    float ndt0 = dtp[0];
    float ndt1 = dtp[NHEADS];
    if (npairs > 1)
        gv = ((const float4*)(xb + (size_t)(2 + ldtok) * CONV_DIM))[ldf4];

    float s[64];
    if (p < HEADDIM) {
        const float* Sb = Sbuf + ((size_t)((b * NHEADS + h) * nchunk + c)) * (HEADDIM * 64)
                          + p * 64;
#pragma unroll
        for (int n4 = 0; n4 < 16; n4++) {
            float4 v = ((const float4*)Sb)[n4];
            s[4 * n4] = v.x; s[4 * n4 + 1] = v.y; s[4 * n4 + 2] = v.z; s[4 * n4 + 3] = v.w;
        }
    } else {
#pragma unroll
        for (int n = 0; n < 64; n++) s[n] = 0.f;
    }

    for (int i = 0; i < npairs; i++) {
        int buf = i & 1;
        int t = t0 + 2 * i;
        float x0 = nx0, x1 = nx1, z0 = nz0, z1 = nz1, dt0 = ndt0, dt1 = ndt1;
        if (i + 1 < npairs) {
            *(float4*)&sBC[hl][buf ^ 1][ldoff] = gv;              // commit pair i+1
            const float* xn = xb + (size_t)(2 * (i + 1)) * CONV_DIM;
            const float* zn = zb + (size_t)(2 * (i + 1)) * D_IN_PROJ;
            nx0 = (p < HEADDIM) ? xn[h * HEADDIM + p] : 0.f;
            nx1 = (p < HEADDIM) ? xn[CONV_DIM + h * HEADDIM + p] : 0.f;
            nz0 = (p < HEADDIM) ? zn[h * HEADDIM + p] : 0.f;
            nz1 = (p < HEADDIM) ? zn[D_IN_PROJ + h * HEADDIM + p] : 0.f;
            ndt0 = dtp[(size_t)(2 * (i + 1)) * NHEADS];
            ndt1 = dtp[(size_t)(2 * (i + 1) + 1) * NHEADS];
            if (i + 2 < npairs)                                    // issue pair i+2
                gv = ((const float4*)(xb + (size_t)(2 * (i + 2) + ldtok) * CONV_DIM))[ldf4];
        }
#pragma unroll
        for (int k = 0; k < 2; k++) {
            float dtv = k ? dt1 : dt0;
            float xp  = k ? x1 : x0;
            float zv  = k ? z1 : z0;
            float dA = __expf(dtv * A);
            float u  = dtv * xp;
            const float4* B4 = (const float4*)&sBC[hl][buf][k * 128];
            const float4* C4 = (const float4*)&sBC[hl][buf][k * 128 + 64];
            float y0 = 0.f, y1 = 0.f, y2 = 0.f, y3 = 0.f;
#pragma unroll
            for (int n4 = 0; n4 < 16; n4++) {
                float4 bq = B4[n4];
                float4 cq = C4[n4];
                float t0v = fmaf(s[4 * n4 + 0], dA, u * bq.x);
                float t1v = fmaf(s[4 * n4 + 1], dA, u * bq.y);
                float t2v = fmaf(s[4 * n4 + 2], dA, u * bq.z);
                float t3v = fmaf(s[4 * n4 + 3], dA, u * bq.w);
                s[4 * n4 + 0] = t0v; s[4 * n4 + 1] = t1v;
                s[4 * n4 + 2] = t2v; s[4 * n4 + 3] = t3v;
                y0 = fmaf(t0v, cq.x, y0);
                y1 = fmaf(t1v, cq.y, y1);
                y2 = fmaf(t2v, cq.z, y2);
                y3 = fmaf(t3v, cq.w, y3);
            }
            float g0 = 0.f;
            if (p < HEADDIM) {
                float yv = fmaf(xp, Dh, (y0 + y1) + (y2 + y3));
                g0 = yv * (zv / (1.f + __expf(-zv)));
            }
            size_t row0 = (size_t)(b * SEQ + t + k) * 416;
            if (p < HEADDIM) {
                ybf[row0 + h * HEADDIM + p] = f2bf(g0 * gval);
            } else {
                int widx = h * 14 + (p - HEADDIM);
                if (widx < 16) ybf[row0 + 400 + widx] = 0;
            }
            float gs0 = g0 * g0;
#pragma unroll
            for (int o = 32; o; o >>= 1) gs0 += __shfl_xor(gs0, o, 64);
            if (p == 0) ssq[(size_t)(b * SEQ + t + k) * NHEADS + h] = gs0;
        }
    }
}

// combine per-head sums -> per-token rstd for the GEMM row-scale
__global__ __launch_bounds__(256) void rstd_kernel(
    const float* __restrict__ ssq, float* __restrict__ rstdb)
{
    int m = blockIdx.x * 256 + threadIdx.x;
    if (m >= NTOK) return;
    const float4* q = (const float4*)(ssq + (size_t)m * NHEADS);
    float4 a = q[0], bq = q[1];
    float tot = ((a.x + a.y) + (a.z + a.w)) + ((bq.x + bq.y) + (bq.z + bq.w));
    rstdb[m] = rsqrtf(tot * (1.f / D_INNER) + EPS);
}

// Pass 3 (fallback, fp32 y out, single-step)
__global__ __launch_bounds__(512) void ssd_out_kernel(
    const float* __restrict__ xBC, const float* __restrict__ dtb,
    const float* __restrict__ A_log, const float* __restrict__ Dv,
    const float* __restrict__ Sbuf, float* __restrict__ y,
    int layer, int lchunk, int nchunk)
{
    int b = blockIdx.x, c = blockIdx.y;
    int tid = threadIdx.x;
    int h = tid >> 6, p = tid & 63;
    float A = -expf(A_log[layer * NHEADS + h]);
    float Dh = Dv[layer * NHEADS + h];

    __shared__ float sh[2][544];
    int t0 = c * lchunk, tend = t0 + lchunk;

    {
        const float* base = xBC + (size_t)(b * SEQ + t0) * CONV_DIM;
        sh[0][tid] = base[tid];
        if (tid < 24) {
            int e2 = 512 + tid;
            sh[0][e2] = (e2 < 528) ? base[e2]
                                   : dtb[(size_t)(b * SEQ + t0) * NHEADS + (e2 - 528)];
        }
    }

    float s[64];
    if (p < HEADDIM) {
        const float* Sb = Sbuf + ((size_t)((b * NHEADS + h) * nchunk + c)) * (HEADDIM * 64)
                          + p * 64;
#pragma unroll
        for (int n4 = 0; n4 < 16; n4++) {
            float4 v = ((const float4*)Sb)[n4];
            s[4 * n4] = v.x; s[4 * n4 + 1] = v.y; s[4 * n4 + 2] = v.z; s[4 * n4 + 3] = v.w;
        }
    } else {
#pragma unroll
        for (int n = 0; n < 64; n++) s[n] = 0.f;
    }
    __syncthreads();

    for (int t = t0; t < tend; t++) {
        int cur = (t - t0) & 1, nxt = cur ^ 1;
        float pf0 = 0.f, pf1 = 0.f;
        if (t + 1 < tend) {
            const float* base = xBC + (size_t)(b * SEQ + t + 1) * CONV_DIM;
            pf0 = base[tid];
            if (tid < 24) {
                int e2 = 512 + tid;
                pf1 = (e2 < 528) ? base[e2]
                                 : dtb[(size_t)(b * SEQ + t + 1) * NHEADS + (e2 - 528)];
            }
        }
        float dtv = sh[cur][528 + h];
        float xp  = (p < HEADDIM) ? sh[cur][h * HEADDIM + p] : 0.f;
        float dA = __expf(dtv * A);
        float u  = dtv * xp;
        const float4* B4 = (const float4*)&sh[cur][D_INNER];
        const float4* C4 = (const float4*)&sh[cur][D_INNER + D_STATE];
        float y0 = 0.f, y1 = 0.f, y2 = 0.f, y3 = 0.f;
#pragma unroll
        for (int n4 = 0; n4 < 16; n4++) {
            float4 bq = B4[n4];
            float4 cq = C4[n4];
            float t0v = fmaf(s[4 * n4 + 0], dA, u * bq.x);
            float t1v = fmaf(s[4 * n4 + 1], dA, u * bq.y);
            float t2v = fmaf(s[4 * n4 + 2], dA, u * bq.z);
            float t3v = fmaf(s[4 * n4 + 3], dA, u * bq.w);
            s[4 * n4 + 0] = t0v; s[4 * n4 + 1] = t1v;
            s[4 * n4 + 2] = t2v; s[4 * n4 + 3] = t3v;
            y0 = fmaf(t0v, cq.x, y0);
            y1 = fmaf(t1v, cq.y, y1);
            y2 = fmaf(t2v, cq.z, y2);
            y3 = fmaf(t3v, cq.w, y3);
        }
        if (p < HEADDIM) {
            float yv = (y0 + y1) + (y2 + y3);
            y[(size_t)(b * SEQ + t) * D_INNER + h * HEADDIM + p] = fmaf(xp, Dh, yv);
        }
        if (t + 1 < tend) {
            sh[nxt][tid] = pf0;
            if (tid < 24) sh[nxt][512 + tid] = pf1;
        }
        __syncthreads();
    }
}

// ---------------------------------------------------------------------------
// fallback gate+norm
__global__ __launch_bounds__(256) void gate_norm_kernel(
    float* __restrict__ y, const float* __restrict__ zxbcdt,
    const float* __restrict__ gw, short* __restrict__ ybf, int layer)
{
    int m = blockIdx.x;
    __shared__ float buf[D_INNER];
    __shared__ float red[4];
    const float* z = zxbcdt + (size_t)m * D_IN_PROJ;
    float* yr = y + (size_t)m * D_INNER;
    const float* gwl = gw + (size_t)layer * D_INNER;
    float ss = 0.f;
    for (int k = threadIdx.x; k < D_INNER; k += 256) {
        float zv = z[k];
        float sz = zv / (1.f + expf(-zv));
        float g = yr[k] * sz;
        buf[k] = g;
        ss = fmaf(g, g, ss);
    }
    int lane = threadIdx.x & 63, w = threadIdx.x >> 6;
#pragma unroll
    for (int o = 32; o; o >>= 1) ss += __shfl_xor(ss, o, 64);
    if (lane == 0) red[w] = ss;
    __syncthreads();
    float tot = red[0] + red[1] + red[2] + red[3];
    float rstd = rsqrtf(tot * (1.f / D_INNER) + EPS);
    for (int k = threadIdx.x; k < 416; k += 256) {
        if (k < D_INNER) {
            float v = buf[k] * rstd * gwl[k];
            yr[k] = v;
            if (ybf) ybf[(size_t)m * 416 + k] = f2bf(v);
        } else if (ybf) {
            ybf[(size_t)m * 416 + k] = 0;
        }
    }
}

// ---------------------------------------------------------------------------
extern "C" void kernel_launch(void* const* d_in, const int* in_sizes, int n_in,
                              void* d_out, int out_size, void* d_ws, size_t ws_size,
                              hipStream_t stream)
{
    const float* x         = (const float*)d_in[0];
    const float* pe_conv_w = (const float*)d_in[1];
    const float* proj_in_w = (const float*)d_in[2];
    const float* gn_g      = (const float*)d_in[3];
    const float* gn_b      = (const float*)d_in[4];
    const float* spec_w    = (const float*)d_in[5];
    const float* norm_w    = (const float*)d_in[6];
    const float* in_proj_w = (const float*)d_in[7];
    const float* conv_w    = (const float*)d_in[8];
    const float* conv_b    = (const float*)d_in[9];
    const float* dt_bias   = (const float*)d_in[10];
    const float* A_log     = (const float*)d_in[11];
    const float* Dv        = (const float*)d_in[12];
    const float* gnorm_w   = (const float*)d_in[13];
    const float* out_proj_w= (const float*)d_in[14];
    const float* norm_f_w  = (const float*)d_in[15];
    const float* head_w    = (const float*)d_in[16];
    const float* head_b    = (const float*)d_in[17];
    float* out = (float*)d_out;
    float* ws  = (float*)d_ws;

    // fast gate: 28,011,424 floats = 112.05 MB (prior rounds ran fast at
    // gates up to 136.4 MB on this harness).
    const size_t needA = 28011424ull * sizeof(float);
    int fast = (ws_size >= needA) ? 1 : 0;

    int nchunk, lchunk;
    float *residual = ws, *hidden = ws + 1824000;
    float *zxbcdt, *xBC, *dtb, *Sbuf, *Pd;
    float *ubuf = nullptr, *ybuf = nullptr, *ssq = nullptr, *rstdb = nullptr;
    short *w_in_bf = nullptr, *w_out_bf = nullptr, *w_head_bf = nullptr,
          *w_spec_bf = nullptr, *csmat_bf = nullptr, *x_bf = nullptr,
          *ubuf_bf = nullptr, *ybuf_bf = nullptr, *magb_bf = nullptr;

    if (fast) {
        nchunk = 15; lchunk = 38;               // 15*38 = 570 (even lchunk)
        zxbcdt = ws + 3648000;                  // 8,536,320
        xBC    = ws + 12184320;                 // 4,815,360
        dtb    = ws + 16999680;                 // 72,960
        Sbuf   = ws + 17072640;                 // 15*128*3200 = 6,144,000
        Pd     = ws + 23216640;                 // 1,920
        short* pool = (short*)(ws + 23218560);
        w_in_bf   = pool;                       // 2,515,968
        w_out_bf  = pool + 2515968;             //   998,400
        w_head_bf = pool + 3514368;             //    44,800
        w_spec_bf = pool + 3559168;             //    25,600
        ubuf_bf   = pool + 3584768;             // 2,042,880
        ybuf_bf   = pool + 5627648;             // 3,793,920 -> 9,421,568 shorts
        ssq       = ws + 27929344;              // 72,960 (NTOK*8)
        rstdb     = ws + 28002304;              // 9,120 -> end 28,011,424
        // preamble-only temporaries in the (then-dead) Sbuf region
        csmat_bf  = (short*)(Sbuf + 4000000);   //    45,248 shorts
        x_bf      = (short*)(Sbuf + 4100000);   // 2,042,880 shorts
        magb_bf   = (short*)(Sbuf + 5200000);   // 1,167,360 shorts (fits 6.14M)
    } else {
        nchunk = 6; lchunk = 95;
        ubuf   = ws + 3648000;
        zxbcdt = ws + 5472000;
        xBC    = ws + 14008320;
        dtb    = ws + 18823680;
        ybuf   = ws + 18896640;
        Sbuf   = ws + 1824000;
        Pd     = ws + 5470000;
    }

    // preamble aliases (dead layer buffers / dead Sbuf)
    float* traw  = fast ? Sbuf : ybuf;
    float* patch = zxbcdt;
    float* csout = fast ? (Sbuf + 2000000) : (xBC + 50000);
    float* csmat = xBC;                         // fallback fp32 DFT matrix
    float* magb  = fast ? nullptr : (xBC + 2000000);
    float* stats = dtb;

    // ---- weight / input casts (fast) ----
    if (fast) {
        cast_pad_kernel<<<(12 * 936 * 224 + 255) / 256, 256, 0, stream>>>(
            in_proj_w, w_in_bf, 12 * 936, 200, 224);
        cast_pad_kernel<<<(12 * 200 * 416 + 255) / 256, 256, 0, stream>>>(
            out_proj_w, w_out_bf, 12 * 200, 400, 416);
        cast_pad_kernel<<<(200 * 224 + 255) / 256, 256, 0, stream>>>(
            head_w, w_head_bf, 200, 200, 224);
        cast_pad_kernel<<<(200 * 128 + 255) / 256, 256, 0, stream>>>(
            spec_w, w_spec_bf, 200, 101, 128);
        cast_pad_kernel<<<(9120 * 224 + 255) / 256, 256, 0, stream>>>(
            x, x_bf, 9120, 200, 224);
        dft_init_bf_kernel<<<(202 * 224 + 255) / 256, 256, 0, stream>>>(csmat_bf);
    } else {
        dft_init_kernel<<<(202 * 200 + 255) / 256, 256, 0, stream>>>(csmat);
    }

    // ---- patch embed ----
    time_conv_kernel<<<NTOK, 256, 0, stream>>>(x, proj_in_w, traw);
    gn_stats_kernel<<<80, 256, 0, stream>>>(traw, stats);
    gn_gelu_kernel<<<(NTOK * 200 + 255) / 256, 256, 0, stream>>>(traw, stats, gn_g, gn_b, patch);
    if (fast) {
        gemm_bf16<<<dim3(2, 72), 256, 0, stream>>>(x_bf, csmat_bf, nullptr, nullptr, csout,
                                                   NTOK, 202, 224, 0);
        mag_bf_kernel<<<(NTOK * 128 + 255) / 256, 256, 0, stream>>>(csout, magb_bf);
        gemm_bf16<<<dim3(2, 72), 256, 0, stream>>>(magb_bf, w_spec_bf, nullptr, nullptr, patch,
                                                   NTOK, 200, 128, 1);
    } else {
        gemm_nt<<<dim3(2, 72), 256, 0, stream>>>(x, csmat, nullptr, csout, NTOK, 202, 200, 0);
        mag_kernel<<<(NTOK * NFREQ + 255) / 256, 256, 0, stream>>>(csout, magb);
        gemm_nt<<<dim3(2, 72), 256, 0, stream>>>(magb, spec_w, nullptr, patch,
                                                 NTOK, 200, NFREQ, 1);
    }
    pe_conv3_kernel<<<dim3(16, 13, 5), 256, 0, stream>>>(patch, pe_conv_w, hidden);

    // ---- layers ----
    for (int i = 0; i < N_LAYER; i++) {
        if (fast) {
            norm_dt_kernel<<<NTOK, 256, 0, stream>>>(hidden, residual, norm_w + i * 200,
                                                     ubuf_bf, in_proj_w, dt_bias, dtb,
                                                     i, (i == 0) ? 1 : 0);
            gemm_bf16<<<dim3(8, 72), 256, 0, stream>>>(
                ubuf_bf, w_in_bf + (size_t)i * 936 * 224, nullptr, nullptr, zxbcdt,
                NTOK, D_IN_PROJ, 224, 0);
        } else {
            add_rmsnorm_kernel<<<NTOK, 64, 0, stream>>>(hidden, residual, norm_w + i * 200,
                                                        ubuf, nullptr, (i == 0) ? 1 : 0);
            dt_gemv_kernel<<<NTOK / 4, 256, 0, stream>>>(ubuf, in_proj_w, dt_bias, dtb, i);
            gemm_nt<<<dim3(8, 72), 256, 0, stream>>>(
                ubuf, in_proj_w + (size_t)i * D_IN_PROJ * 200, nullptr, zxbcdt,
                NTOK, D_IN_PROJ, 200, 0);
        }
        dtconv2_kernel<<<dim3(16, 72), 256, 0, stream>>>(zxbcdt, conv_w, conv_b, xBC, i);
        {
            dim3 g(BATCH, nchunk);
            if (fast) {
                ssd_state4_kernel<<<dim3(BATCH, nchunk, 2), 256, 0, stream>>>(
                    xBC, dtb, A_log, Sbuf, Pd, i, lchunk, nchunk);
                ssd_scan2b_kernel<<<dim3(BATCH * NHEADS, 13), 256, 0, stream>>>(Sbuf, Pd, nchunk);
                ssd_out7_kernel<<<dim3(BATCH, nchunk, 2), 256, 0, stream>>>(
                    xBC, dtb, zxbcdt, A_log, Dv, Sbuf, gnorm_w, ybuf_bf, ssq,
                    i, lchunk, nchunk);
                rstd_kernel<<<(NTOK + 255) / 256, 256, 0, stream>>>(ssq, rstdb);
                gemm_bf16<<<dim3(2, 72), 256, 0, stream>>>(
                    ybuf_bf, w_out_bf + (size_t)i * 200 * 416, nullptr, rstdb, hidden,
                    NTOK, 200, 416, 0);
            } else {
                ssd_state_kernel<<<g, 512, 0, stream>>>(xBC, dtb, A_log, Sbuf, Pd,
                                                        i, lchunk, nchunk);
                ssd_scan2b_kernel<<<dim3(BATCH * NHEADS, 13), 256, 0, stream>>>(Sbuf, Pd, nchunk);
                ssd_out_kernel<<<g, 512, 0, stream>>>(xBC, dtb, A_log, Dv, Sbuf, ybuf,
                                                      i, lchunk, nchunk);
                gate_norm_kernel<<<NTOK, 256, 0, stream>>>(ybuf, zxbcdt, gnorm_w, nullptr, i);
                gemm_nt<<<dim3(2, 72), 256, 0, stream>>>(
                    ybuf, out_proj_w + (size_t)i * 200 * D_INNER, nullptr, hidden,
                    NTOK, 200, D_INNER, 0);
            }
        }
    }

    // ---- final norm + head ----
    add_rmsnorm_kernel<<<NTOK, 64, 0, stream>>>(hidden, residual, norm_f_w,
                                                fast ? nullptr : ubuf,
                                                fast ? ubuf_bf : nullptr, 0);
    if (fast) {
        gemm_bf16<<<dim3(2, 72), 256, 0, stream>>>(ubuf_bf, w_head_bf, head_b, nullptr, out,
                                                   NTOK, 200, 224, 0);
    } else {
        gemm_nt<<<dim3(2, 72), 256, 0, stream>>>(ubuf, head_w, head_b, out,
                                                 NTOK, 200, 200, 0);
    }
}

// Round 13
// 2300.996 us; speedup vs baseline: 1.0747x; 1.0545x over previous
//
#include <hip/hip_runtime.h>
#include <hip/hip_bf16.h>
#include <math.h>

// ---------------------------------------------------------------------------
// EEGMamba forward. Round 22: pass 1 as ONE MFMA GEMM. With log-decay prefix
// lc[t] = sum dt*A, chunk-final state S[p][n] = sum_s exp(lcTot-lc[s])*dt_s*
// x_s[p]*B_s[n] = Xw @ B^T (64x64x38, bf16 MFMA, fp32 accum) — no recurrence.
// Serial part = 64-lane shfl prefix over 38 scalars. Fragment layout mirrors
// the long-verified in-file gemm_bf16. Pass 2/3 (scan2b, out7) unchanged;
// base config = R21 (2426 us reproduced).
#define D_MODEL   200
#define N_LAYER   12
#define NHEADS    8
#define HEADDIM   50
#define D_STATE   64
#define D_INNER   400
#define CONV_DIM  528
#define D_IN_PROJ 936
#define D_CONV    4
#define EPS       1e-5f

#define BATCH 16
#define CH    19
#define LLEN  30
#define SEQ   570
#define NTOK  9120
#define NFREQ 101

typedef __attribute__((ext_vector_type(8))) short s8v;
typedef __attribute__((ext_vector_type(4))) float f32x4;

__device__ __forceinline__ short f2bf(float f) {
    unsigned u = __float_as_uint(f);
    u += 0x7FFFu + ((u >> 16) & 1u);      // RNE
    return (short)(u >> 16);
}

// ---------------------------------------------------------------------------
// bf16 MFMA GEMM: C[M,N] = rowscale[m] * (A[M,Kp] @ W[N,Kp]^T) (+bias) (+C)
__global__ __launch_bounds__(256) void gemm_bf16(
    const short* __restrict__ A, const short* __restrict__ W,
    const float* __restrict__ bias, const float* __restrict__ rowscale,
    float* __restrict__ C, int M, int N, int Kp, int accum)
{
    __shared__ __align__(16) short As[128][40];
    __shared__ __align__(16) short Ws[128][40];

    int bm = blockIdx.y * 128;
    int bn = blockIdx.x * 128;
    int tid = threadIdx.x;
    int lane = tid & 63;
    int wv = tid >> 6;
    int wm = wv & 1, wn = wv >> 1;
    int lm = lane & 15, lg = lane >> 4;

    int sr = tid >> 1;
    int sh_ = (tid & 1) * 16;

    f32x4 acc[4][4];
#pragma unroll
    for (int i = 0; i < 4; i++)
#pragma unroll
        for (int j = 0; j < 4; j++) acc[i][j] = (f32x4)0.f;

    for (int k0 = 0; k0 < Kp; k0 += 32) {
        {
            s8v v0 = (s8v)0, v1 = (s8v)0;
            if (bm + sr < M) {
                const short* ga = A + (size_t)(bm + sr) * Kp + k0 + sh_;
                v0 = *(const s8v*)ga;
                v1 = *(const s8v*)(ga + 8);
            }
            *(s8v*)&As[sr][sh_] = v0;
            *(s8v*)&As[sr][sh_ + 8] = v1;
        }
        {
            s8v v0 = (s8v)0, v1 = (s8v)0;
            if (bn + sr < N) {
                const short* gw = W + (size_t)(bn + sr) * Kp + k0 + sh_;
                v0 = *(const s8v*)gw;
                v1 = *(const s8v*)(gw + 8);
            }
            *(s8v*)&Ws[sr][sh_] = v0;
            *(s8v*)&Ws[sr][sh_ + 8] = v1;
        }
        __syncthreads();

        s8v af[4], bf[4];
#pragma unroll
        for (int i = 0; i < 4; i++)
            af[i] = *(const s8v*)&As[wm * 64 + i * 16 + lm][lg * 8];
#pragma unroll
        for (int j = 0; j < 4; j++)
            bf[j] = *(const s8v*)&Ws[wn * 64 + j * 16 + lm][lg * 8];
#pragma unroll
        for (int i = 0; i < 4; i++)
#pragma unroll
            for (int j = 0; j < 4; j++)
                acc[i][j] = __builtin_amdgcn_mfma_f32_16x16x32_bf16(
                    af[i], bf[j], acc[i][j], 0, 0, 0);
        __syncthreads();
    }

#pragma unroll
    for (int j = 0; j < 4; j++) {
        int n = bn + wn * 64 + j * 16 + lm;
        if (n >= N) continue;
        float bv = bias ? bias[n] : 0.f;
#pragma unroll
        for (int i = 0; i < 4; i++) {
            int mbase = bm + wm * 64 + i * 16 + lg * 4;
#pragma unroll
            for (int r = 0; r < 4; r++) {
                int m = mbase + r;
                if (m >= M) continue;
                size_t idx = (size_t)m * N + n;
                float v = acc[i][j][r];
                if (rowscale) v *= rowscale[m];
                v += bv;
                if (accum) v += C[idx];
                C[idx] = v;
            }
        }
    }
}

// ---------------------------------------------------------------------------
// fp32 GEMM (fallback path)
__global__ __launch_bounds__(256) void gemm_nt(
    const float* __restrict__ A, const float* __restrict__ W,
    const float* __restrict__ bias, float* __restrict__ C,
    int M, int N, int K, int accum)
{
    const int BM = 128, BK = 16;
    __shared__ float As[16][BM + 4];
    __shared__ float Ws[16][BM + 4];

    int bm = blockIdx.y * BM;
    int bn = blockIdx.x * BM;
    int tid = threadIdx.x;
    int lr = tid >> 1;
    int lc = (tid & 1) * 8;
    int tx = tid & 15;
    int ty = tid >> 4;

    float acc[8][8];
#pragma unroll
    for (int i = 0; i < 8; i++)
#pragma unroll
        for (int j = 0; j < 8; j++) acc[i][j] = 0.f;

    for (int k0 = 0; k0 < K; k0 += BK) {
#pragma unroll
        for (int i = 0; i < 8; i++) {
            int gr = bm + lr, gk = k0 + lc + i;
            As[lc + i][lr] = (gr < M && gk < K) ? A[(size_t)gr * K + gk] : 0.f;
        }
#pragma unroll
        for (int i = 0; i < 8; i++) {
            int gr = bn + lr, gk = k0 + lc + i;
            Ws[lc + i][lr] = (gr < N && gk < K) ? W[(size_t)gr * K + gk] : 0.f;
        }
        __syncthreads();
#pragma unroll
        for (int kk = 0; kk < BK; kk++) {
            float a[8], bv[8];
#pragma unroll
            for (int i = 0; i < 8; i++) a[i] = As[kk][ty * 8 + i];
#pragma unroll
            for (int j = 0; j < 8; j++) bv[j] = Ws[kk][tx * 8 + j];
#pragma unroll
            for (int i = 0; i < 8; i++)
#pragma unroll
                for (int j = 0; j < 8; j++)
                    acc[i][j] = fmaf(a[i], bv[j], acc[i][j]);
        }
        __syncthreads();
    }

#pragma unroll
    for (int i = 0; i < 8; i++) {
        int gm = bm + ty * 8 + i;
        if (gm >= M) continue;
#pragma unroll
        for (int j = 0; j < 8; j++) {
            int gn = bn + tx * 8 + j;
            if (gn >= N) continue;
            float v = acc[i][j];
            if (bias) v += bias[gn];
            if (accum) v += C[(size_t)gm * N + gn];
            C[(size_t)gm * N + gn] = v;
        }
    }
}

// ---------------------------------------------------------------------------
__global__ __launch_bounds__(256) void cast_pad_kernel(
    const float* __restrict__ src, short* __restrict__ dst,
    int R, int K, int Kp)
{
    int idx = blockIdx.x * 256 + threadIdx.x;
    if (idx >= R * Kp) return;
    int r = idx / Kp, k = idx - r * Kp;
    dst[idx] = (k < K) ? f2bf(src[(size_t)r * K + k]) : (short)0;
}

// ---------------------------------------------------------------------------
__global__ __launch_bounds__(256) void time_conv_kernel(
    const float* __restrict__ x, const float* __restrict__ pw,
    float* __restrict__ traw)
{
    int br = blockIdx.x;
    __shared__ float xr[200];
    if (threadIdx.x < 200) xr[threadIdx.x] = x[(size_t)br * 200 + threadIdx.x];
    __syncthreads();
    if (threadIdx.x < 200) {
        int oc = threadIdx.x >> 3, j = threadIdx.x & 7;
        int start = j * 25 - 24;
        float acc = 0.f;
#pragma unroll
        for (int k = 0; k < 49; k++) {
            int d = start + k;
            if (d >= 0 && d < 200) acc = fmaf(xr[d], pw[oc * 49 + k], acc);
        }
        int b = br / SEQ, row = br % SEQ;
        traw[(((size_t)b * 25 + oc) * SEQ + row) * 8 + j] = acc;
    }
}

__global__ __launch_bounds__(256) void gn_stats_kernel(
    const float* __restrict__ traw, float* __restrict__ stats)
{
    int bg = blockIdx.x;
    int b = bg / 5, g = bg % 5;
    const float* base = traw + ((size_t)b * 25 + g * 5) * SEQ * 8;
    float s = 0.f, q = 0.f;
    for (int i = threadIdx.x; i < 5 * SEQ * 8; i += 256) {
        float v = base[i];
        s += v; q = fmaf(v, v, q);
    }
    __shared__ float rs[4], rq[4];
    int lane = threadIdx.x & 63, w = threadIdx.x >> 6;
#pragma unroll
    for (int o = 32; o; o >>= 1) { s += __shfl_xor(s, o, 64); q += __shfl_xor(q, o, 64); }
    if (lane == 0) { rs[w] = s; rq[w] = q; }
    __syncthreads();
    if (threadIdx.x == 0) {
        float S = rs[0] + rs[1] + rs[2] + rs[3];
        float Q = rq[0] + rq[1] + rq[2] + rq[3];
        float inv = 1.f / (5.f * SEQ * 8.f);
        float mean = S * inv;
        float var = Q * inv - mean * mean;
        stats[bg * 2] = mean;
        stats[bg * 2 + 1] = rsqrtf(var + EPS);
    }
}

__global__ __launch_bounds__(256) void gn_gelu_kernel(
    const float* __restrict__ traw, const float* __restrict__ stats,
    const float* __restrict__ gn_g, const float* __restrict__ gn_b,
    float* __restrict__ patch)
{
    int idx = blockIdx.x * 256 + threadIdx.x;
    if (idx >= NTOK * 200) return;
    int d = idx % 200;
    int row = (idx / 200) % SEQ;
    int b = idx / (200 * SEQ);
    int oc = d >> 3, j = d & 7;
    float v = traw[(((size_t)b * 25 + oc) * SEQ + row) * 8 + j];
    int g = oc / 5;
    float mean = stats[(b * 5 + g) * 2];
    float rstd = stats[(b * 5 + g) * 2 + 1];
    v = (v - mean) * rstd * gn_g[oc] + gn_b[oc];
    float ge = 0.5f * v * (1.f + erff(v * 0.70710678118654752f));
    patch[idx] = ge;
}

__global__ __launch_bounds__(256) void dft_init_kernel(float* __restrict__ CS)
{
    int idx = blockIdx.x * 256 + threadIdx.x;
    if (idx >= 202 * 200) return;
    int f = idx / 200, d = idx % 200;
    int fr = (f < NFREQ) ? f : (f - NFREQ);
    int m = (fr * d) % 200;
    float ang = -6.283185307179586f * (float)m * (1.f / 200.f);
    CS[idx] = (f < NFREQ) ? cosf(ang) : sinf(ang);
}

__global__ __launch_bounds__(256) void dft_init_bf_kernel(short* __restrict__ CS)
{
    int idx = blockIdx.x * 256 + threadIdx.x;
    if (idx >= 202 * 224) return;
    int f = idx / 224, d = idx - f * 224;
    short out = 0;
    if (d < 200) {
        int fr = (f < NFREQ) ? f : (f - NFREQ);
        int m = (fr * d) % 200;
        float ang = -6.283185307179586f * (float)m * (1.f / 200.f);
        out = f2bf((f < NFREQ) ? cosf(ang) : sinf(ang));
    }
    CS[idx] = out;
}

__global__ __launch_bounds__(256) void mag_kernel(
    const float* __restrict__ cs_out, float* __restrict__ magv)
{
    int idx = blockIdx.x * 256 + threadIdx.x;
    if (idx >= NTOK * NFREQ) return;
    int m = idx / NFREQ, f = idx % NFREQ;
    float re = cs_out[(size_t)m * 202 + f];
    float im = cs_out[(size_t)m * 202 + NFREQ + f];
    magv[idx] = sqrtf(re * re + im * im) * 0.005f;
}

__global__ __launch_bounds__(256) void mag_bf_kernel(
    const float* __restrict__ cs_out, short* __restrict__ magv)
{
    int idx = blockIdx.x * 256 + threadIdx.x;
    if (idx >= NTOK * 128) return;
    int m = idx >> 7, f = idx & 127;
    short out = 0;
    if (f < NFREQ) {
        float re = cs_out[(size_t)m * 202 + f];
        float im = cs_out[(size_t)m * 202 + NFREQ + f];
        out = f2bf(sqrtf(re * re + im * im) * 0.005f);
    }
    magv[idx] = out;
}

// ---------------------------------------------------------------------------
// depthwise 7x7 pos conv + residual. block = (b, 16-d slice, 4-c tile+halo)
__global__ __launch_bounds__(256) void pe_conv3_kernel(
    const float* __restrict__ patch, const float* __restrict__ pw,
    float* __restrict__ hidden)
{
    int b = blockIdx.x, dc = blockIdx.y, ct = blockIdx.z;
    int d0 = dc * 16, c0 = ct * 4;
    __shared__ float pl[10 * 30 * 16];
    __shared__ float wl[49 * 16];
    int tid = threadIdx.x;
    int dd = tid & 15;
    int d = d0 + dd;

    for (int i = tid; i < 10 * 30 * 16; i += 256) {
        int ddl = i & 15, r = i >> 4;
        int l = r % 30, cr = r / 30;
        int cc = c0 + cr - 3, dl = d0 + ddl;
        pl[i] = (cc >= 0 && cc < CH && dl < 200)
                    ? patch[((size_t)(b * CH + cc) * LLEN + l) * 200 + dl] : 0.f;
    }
    for (int i = tid; i < 49 * 16; i += 256) {
        int k = i >> 4, dl = d0 + (i & 15);
        wl[i] = (dl < 200) ? pw[(size_t)dl * 49 + k] : 0.f;
    }
    __syncthreads();

    float wreg[49];
#pragma unroll
    for (int k = 0; k < 49; k++) wreg[k] = wl[k * 16 + dd];

    for (int o = tid; o < 4 * 30 * 16; o += 256) {
        int r2 = o >> 4;
        int l = r2 % 30, ci = r2 / 30;
        int c = c0 + ci;
        if (c >= CH) continue;
        float acc = pl[((ci + 3) * 30 + l) * 16 + dd];
#pragma unroll
        for (int i = 0; i < 7; i++) {
#pragma unroll
            for (int j = 0; j < 7; j++) {
                int ll = l + j - 3;
                if (ll < 0 || ll >= LLEN) continue;
                acc = fmaf(pl[((ci + i) * 30 + ll) * 16 + dd], wreg[i * 7 + j], acc);
            }
        }
        if (d < 200) hidden[((size_t)(b * CH + c) * LLEN + l) * 200 + d] = acc;
    }
}

// ---------------------------------------------------------------------------
__global__ __launch_bounds__(64) void add_rmsnorm_kernel(
    const float* __restrict__ hidden, float* __restrict__ residual,
    const float* __restrict__ wn, float* __restrict__ u,
    short* __restrict__ ubf, int first)
{
    int m = blockIdx.x;
    int lane = threadIdx.x;
    const float* hr = hidden + (size_t)m * 200;
    float* rr = residual + (size_t)m * 200;
    float v[4];
    float ss = 0.f;
#pragma unroll
    for (int i = 0; i < 4; i++) {
        int k = lane + i * 64;
        float xv = 0.f;
        if (k < 200) {
            xv = hr[k] + (first ? 0.f : rr[k]);
            rr[k] = xv;
        }
        v[i] = xv;
        ss = fmaf(xv, xv, ss);
    }
#pragma unroll
    for (int o = 32; o; o >>= 1) ss += __shfl_xor(ss, o, 64);
    float rstd = rsqrtf(ss * (1.f / 200.f) + EPS);
#pragma unroll
    for (int i = 0; i < 4; i++) {
        int k = lane + i * 64;
        float val = v[i] * rstd * ((k < 200) ? wn[k] : 0.f);
        if (k < 200 && u) u[(size_t)m * 200 + k] = val;
        if (ubf) {
            if (k < 200) ubf[(size_t)m * 224 + k] = f2bf(val);
            else if (k < 224) ubf[(size_t)m * 224 + k] = 0;
        }
    }
}

// ---------------------------------------------------------------------------
// Fused: residual += hidden; u = rmsnorm*wn -> ubf; dt GEMV fp32.
__global__ __launch_bounds__(256) void norm_dt_kernel(
    const float* __restrict__ hidden, float* __restrict__ residual,
    const float* __restrict__ wn, short* __restrict__ ubf,
    const float* __restrict__ Win, const float* __restrict__ dt_bias,
    float* __restrict__ dtb, int layer, int first)
{
    int m = blockIdx.x;
    int tid = threadIdx.x;
    __shared__ float su[200];
    __shared__ float rs[4];
    float xv = 0.f;
    if (tid < 200) {
        xv = hidden[(size_t)m * 200 + tid] + (first ? 0.f : residual[(size_t)m * 200 + tid]);
        residual[(size_t)m * 200 + tid] = xv;
    }
    float ss = xv * xv;
#pragma unroll
    for (int o = 32; o; o >>= 1) ss += __shfl_xor(ss, o, 64);
    int lane = tid & 63, w = tid >> 6;
    if (lane == 0) rs[w] = ss;
    __syncthreads();
    float rstd = rsqrtf((rs[0] + rs[1] + rs[2] + rs[3]) * (1.f / 200.f) + EPS);
    if (tid < 200) {
        float val = xv * rstd * wn[tid];
        su[tid] = val;
        ubf[(size_t)m * 224 + tid] = f2bf(val);
    } else if (tid < 224) {
        ubf[(size_t)m * 224 + tid] = 0;
    }
    __syncthreads();
    int h = tid >> 5, l = tid & 31;
    const float* wr = Win + (size_t)layer * D_IN_PROJ * 200 + (size_t)(928 + h) * 200;
    float s = 0.f;
    for (int k = l; k < 200; k += 32) s = fmaf(su[k], wr[k], s);
    s += __shfl_xor(s, 16, 32);
    s += __shfl_xor(s, 8, 32);
    s += __shfl_xor(s, 4, 32);
    s += __shfl_xor(s, 2, 32);
    s += __shfl_xor(s, 1, 32);
    if (l == 0) {
        float raw = s + dt_bias[layer * NHEADS + h];
        dtb[(size_t)m * NHEADS + h] = (raw > 20.f) ? raw : log1pf(expf(raw));
    }
}

// fp32 dt GEMV (fallback)
__global__ __launch_bounds__(256) void dt_gemv_kernel(
    const float* __restrict__ u, const float* __restrict__ Win,
    const float* __restrict__ dt_bias, float* __restrict__ dtb, int layer)
{
    int tid = threadIdx.x;
    int tok = blockIdx.x * 4 + (tid >> 6);
    int head = (tid >> 3) & 7;
    int l8 = tid & 7;
    const float* ur = u + (size_t)tok * 200;
    const float* wr = Win + (size_t)layer * D_IN_PROJ * 200 + (size_t)(928 + head) * 200;
    float s = 0.f;
    for (int k = l8; k < 200; k += 8) s = fmaf(ur[k], wr[k], s);
    s += __shfl_xor(s, 1, 64);
    s += __shfl_xor(s, 2, 64);
    s += __shfl_xor(s, 4, 64);
    if (l8 == 0) {
        float raw = s + dt_bias[layer * NHEADS + head];
        dtb[(size_t)tok * NHEADS + head] = (raw > 20.f) ? raw : log1pf(expf(raw));
    }
}

// ---------------------------------------------------------------------------
// xBC = silu(causal depthwise conv4), t-tiled
__global__ __launch_bounds__(256) void dtconv2_kernel(
    const float* __restrict__ zxbcdt, const float* __restrict__ cw,
    const float* __restrict__ cb, float* __restrict__ xBC, int layer)
{
    int b = blockIdx.x, tt = blockIdx.y;
    int t0 = tt * 8;
    __shared__ float zs[11][528];
    const float* cwl = cw + (size_t)layer * CONV_DIM * 4;
    const float* cbl = cb + (size_t)layer * CONV_DIM;
    for (int i = threadIdx.x; i < 11 * 528; i += 256) {
        int r = i / 528, ch = i - r * 528;
        int t = t0 - 3 + r;
        zs[r][ch] = (t >= 0 && t < SEQ)
                        ? zxbcdt[(size_t)(b * SEQ + t) * D_IN_PROJ + D_INNER + ch] : 0.f;
    }
    __syncthreads();
    for (int o = threadIdx.x; o < 8 * 528; o += 256) {
        int tr = o / 528, ch = o - tr * 528;
        int t = t0 + tr;
        if (t >= SEQ) continue;
        float acc = cbl[ch];
#pragma unroll
        for (int k = 0; k < 4; k++)
            acc = fmaf(zs[tr + k][ch], cwl[ch * 4 + k], acc);
        xBC[(size_t)(b * SEQ + t) * CONV_DIM + ch] = acc / (1.f + __expf(-acc));
    }
}

// ---------------------------------------------------------------------------
// SSD pass 1 as ONE MFMA GEMM per (b,h,chunk):
//   S[p][n] = sum_s exp(lcTot - lc[s]) * dt_s * x_s[p] * B_s[n]
//           = Xw[p][s] @ Bt[n][s]^T   (K = s, bf16 inputs, fp32 accum)
// grid (b, chunk, 2), 256 thr = 4 waves, wave = head. Bt shared across the
// block's 4 heads; Xw per-wave. lc via 64-lane shfl prefix. Pd = exp(lcTot).
// Requires lchunk <= 48 (fast path uses 38).
__global__ __launch_bounds__(256) void ssd_state12_kernel(
    const float* __restrict__ xBC, const float* __restrict__ dtb,
    const float* __restrict__ A_log, float* __restrict__ Sbuf,
    float* __restrict__ Pd, int layer, int lchunk, int nchunk)
{
    int b = blockIdx.x, c = blockIdx.y, bz = blockIdx.z;
    int tid = threadIdx.x;
    int w = tid >> 6, lane = tid & 63;
    int h = bz * 4 + w;
    int t0 = c * lchunk;
    float A = -expf(A_log[layer * NHEADS + h]);

    __shared__ __align__(16) short Bt[64 * 64];      // [n][s], block-shared
    __shared__ __align__(16) short Xw[4][64 * 64];   // [p][s], per wave

    // zero both tiles (covers K/M padding)
    for (int i = tid; i < 512; i += 256) ((s8v*)Bt)[i] = (s8v)0;
#pragma unroll
    for (int ww = 0; ww < 4; ww++)
        for (int i = tid; i < 512; i += 256) ((s8v*)Xw[ww])[i] = (s8v)0;
    __syncthreads();

    // per-wave: dt in lane s -> inclusive prefix lc -> weights w_s
    float dtv = 0.f;
    if (lane < lchunk) dtv = dtb[(size_t)(b * SEQ + t0 + lane) * NHEADS + h];
    float lc = dtv * A;
#pragma unroll
    for (int o = 1; o < 64; o <<= 1) {
        float v = __shfl_up(lc, o, 64);
        if (lane >= o) lc += v;
    }
    float lcTot = __shfl(lc, lchunk - 1, 64);
    float wdec = __expf(lcTot - lc) * dtv;            // lanes >= lchunk: 0

    // fill Bt (block): B[s][n] -> Bt[n][s]
    for (int idx = tid; idx < lchunk * 64; idx += 256) {
        int s = idx >> 6, n = idx & 63;
        float v = xBC[(size_t)(b * SEQ + t0 + s) * CONV_DIM + D_INNER + n];
        Bt[n * 64 + s] = f2bf(v);
    }
    // fill Xw (wave): X[s][p] * w_s -> Xw[w][p][s]
    for (int idx = lane; idx < lchunk * HEADDIM; idx += 64) {
        int s = idx / HEADDIM, p = idx - s * HEADDIM;
        float ws = __shfl(wdec, s, 64);
        float v = xBC[(size_t)(b * SEQ + t0 + s) * CONV_DIM + h * HEADDIM + p] * ws;
        Xw[w][p * 64 + s] = f2bf(v);
    }
    __syncthreads();

    int lm = lane & 15, lg = lane >> 4;
    f32x4 acc[4][4];
#pragma unroll
    for (int i = 0; i < 4; i++)
#pragma unroll
        for (int j = 0; j < 4; j++) acc[i][j] = (f32x4)0.f;

#pragma unroll
    for (int k0 = 0; k0 < 64; k0 += 32) {
        s8v af[4], bf[4];
#pragma unroll
        for (int i = 0; i < 4; i++)
            af[i] = *(const s8v*)&Xw[w][(i * 16 + lm) * 64 + k0 + lg * 8];
#pragma unroll
        for (int j = 0; j < 4; j++)
            bf[j] = *(const s8v*)&Bt[(j * 16 + lm) * 64 + k0 + lg * 8];
#pragma unroll
        for (int i = 0; i < 4; i++)
#pragma unroll
            for (int j = 0; j < 4; j++)
                acc[i][j] = __builtin_amdgcn_mfma_f32_16x16x32_bf16(
                    af[i], bf[j], acc[i][j], 0, 0, 0);
    }

    float* Sb = Sbuf + ((size_t)((b * NHEADS + h) * nchunk + c)) * (HEADDIM * 64);
#pragma unroll
    for (int i = 0; i < 4; i++) {
        int pbase = i * 16 + lg * 4;
#pragma unroll
        for (int r = 0; r < 4; r++) {
            int p = pbase + r;
            if (p >= HEADDIM) continue;
#pragma unroll
            for (int j = 0; j < 4; j++) {
                int n = j * 16 + lm;
                Sb[(size_t)p * 64 + n] = acc[i][j][r];
            }
        }
    }
    if (lane == 0) Pd[(b * NHEADS + h) * nchunk + c] = __expf(lcTot);
}

// single-step pass 1 (fallback)
__global__ __launch_bounds__(512) void ssd_state_kernel(
    const float* __restrict__ xBC, const float* __restrict__ dtb,
    const float* __restrict__ A_log, float* __restrict__ Sbuf,
    float* __restrict__ Pd, int layer, int lchunk, int nchunk)
{
    int b = blockIdx.x, c = blockIdx.y;
    int tid = threadIdx.x;
    int h = tid >> 6, p = tid & 63;
    float A = -expf(A_log[layer * NHEADS + h]);

    __shared__ float sh[2][544];
    int t0 = c * lchunk, tend = t0 + lchunk;

    {
        const float* base = xBC + (size_t)(b * SEQ + t0) * CONV_DIM;
        sh[0][tid] = base[tid];
        if (tid < 24) {
            int e2 = 512 + tid;
            sh[0][e2] = (e2 < 528) ? base[e2]
                                   : dtb[(size_t)(b * SEQ + t0) * NHEADS + (e2 - 528)];
        }
    }
    __syncthreads();

    float s[64];
#pragma unroll
    for (int n = 0; n < 64; n++) s[n] = 0.f;
    float pacc = 1.f;

    for (int t = t0; t < tend; t++) {
        int cur = (t - t0) & 1, nxt = cur ^ 1;
        float pf0 = 0.f, pf1 = 0.f;
        if (t + 1 < tend) {
            const float* base = xBC + (size_t)(b * SEQ + t + 1) * CONV_DIM;
            pf0 = base[tid];
            if (tid < 24) {
                int e2 = 512 + tid;
                pf1 = (e2 < 528) ? base[e2]
                                 : dtb[(size_t)(b * SEQ + t + 1) * NHEADS + (e2 - 528)];
            }
        }
        float dtv = sh[cur][528 + h];
        float xp  = (p < HEADDIM) ? sh[cur][h * HEADDIM + p] : 0.f;
        float dA = __expf(dtv * A);
        float u  = dtv * xp;
        pacc *= dA;
        const float4* B4 = (const float4*)&sh[cur][D_INNER];
#pragma unroll
        for (int n4 = 0; n4 < 16; n4++) {
            float4 bq = B4[n4];
            s[4 * n4 + 0] = fmaf(s[4 * n4 + 0], dA, u * bq.x);
            s[4 * n4 + 1] = fmaf(s[4 * n4 + 1], dA, u * bq.y);
            s[4 * n4 + 2] = fmaf(s[4 * n4 + 2], dA, u * bq.z);
            s[4 * n4 + 3] = fmaf(s[4 * n4 + 3], dA, u * bq.w);
        }
        if (t + 1 < tend) {
            sh[nxt][tid] = pf0;
            if (tid < 24) sh[nxt][512 + tid] = pf1;
        }
        __syncthreads();
    }

    if (p < HEADDIM) {
        float* Sb = Sbuf + ((size_t)((b * NHEADS + h) * nchunk + c)) * (HEADDIM * 64)
                    + p * 64;
#pragma unroll
        for (int n4 = 0; n4 < 16; n4++)
            ((float4*)Sb)[n4] = make_float4(s[4 * n4], s[4 * n4 + 1],
                                            s[4 * n4 + 2], s[4 * n4 + 3]);
    }
    if (p == 0) Pd[(b * NHEADS + h) * nchunk + c] = pacc;
}

// ---------------------------------------------------------------------------
// Pass 2, parallel over element tiles: grid (128 bh, 13), 256 thr.
__global__ __launch_bounds__(256) void ssd_scan2b_kernel(
    float* __restrict__ Sbuf, const float* __restrict__ Pd, int nchunk)
{
    int bh = blockIdx.x;
    int e = blockIdx.y * 256 + threadIdx.x;
    if (e >= HEADDIM * 64) return;
    float* base = Sbuf + (size_t)bh * nchunk * (HEADDIM * 64) + e;
    const float* pd = Pd + bh * nchunk;
    float cur = 0.f;
    for (int c = 0; c < nchunk; c++) {
        float l = base[(size_t)c * (HEADDIM * 64)];
        base[(size_t)c * (HEADDIM * 64)] = cur;
        cur = fmaf(pd[c], cur, l);
    }
}

// ---------------------------------------------------------------------------
// SSD fused pass 3, per-wave autonomous with 2-deep prefetch. grid
// (b, chunk, half), 4 independent waves, wave = head, no barriers.
// B+C pair = exactly 1 float4 per lane (64 lanes x 16B = 2 tokens x 128 f).
// Writes ybf = bf16(g*gw) un-normalized + per-(token,head) ssq.
// Requires even lchunk. (R15's fastest pass-3 variant.)
__global__ __launch_bounds__(256) void ssd_out7_kernel(
    const float* __restrict__ xBC, const float* __restrict__ dtb,
    const float* __restrict__ zxbcdt, const float* __restrict__ A_log,
    const float* __restrict__ Dv, const float* __restrict__ Sbuf,
    const float* __restrict__ gw, short* __restrict__ ybf,
    float* __restrict__ ssq, int layer, int lchunk, int nchunk)
{
    int b = blockIdx.x, c = blockIdx.y, bz = blockIdx.z;
    int tid = threadIdx.x;
    int hl = tid >> 6, p = tid & 63;
    int h = bz * 4 + hl;
    float A = -expf(A_log[layer * NHEADS + h]);
    float Dh = Dv[layer * NHEADS + h];
    float gval = (p < HEADDIM) ? gw[(size_t)layer * D_INNER + h * HEADDIM + p] : 0.f;

    __shared__ __align__(16) float sBC[4][2][256];
    int t0 = c * lchunk;
    int npairs = lchunk >> 1;                 // lchunk even (fast path)

    const float* xb  = xBC + (size_t)(b * SEQ + t0) * CONV_DIM;
    const float* zb  = zxbcdt + (size_t)(b * SEQ + t0) * D_IN_PROJ;
    const float* dtp = dtb + (size_t)(b * SEQ + t0) * NHEADS + h;

    int ldtok = p >> 5;                       // token in pair
    int ldf4  = 100 + (p & 31);               // B+C = float4 idx 100..131
    int ldoff = ldtok * 128 + ((p & 31) << 2);

    float4 gv;
    gv = ((const float4*)(xb + (size_t)ldtok * CONV_DIM))[ldf4];
    *(float4*)&sBC[hl][0][ldoff] = gv;
    float nx0 = (p < HEADDIM) ? xb[h * HEADDIM + p] : 0.f;
    float nx1 = (p < HEADDIM) ? xb[CONV_DIM + h * HEADDIM + p] : 0.f;
    float nz0 = (p < HEADDIM) ? zb[h * HEADDIM + p] : 0.f;
    float nz1 = (p < HEADDIM) ? zb[D_IN_PROJ + h * HEADDIM + p] : 0.f;
    float ndt0 = dtp[0];
    float ndt1 = dtp[NHEADS];
    if (npairs > 1)
        gv = ((const float4*)(xb + (size_t)(2 + ldtok) * CONV_DIM))[ldf4];

    float s[64];
    if (p < HEADDIM) {
        const float* Sb = Sbuf + ((size_t)((b * NHEADS + h) * nchunk + c)) * (HEADDIM * 64)
                          + p * 64;
#pragma unroll
        for (int n4 = 0; n4 < 16; n4++) {
            float4 v = ((const float4*)Sb)[n4];
            s[4 * n4] = v.x; s[4 * n4 + 1] = v.y; s[4 * n4 + 2] = v.z; s[4 * n4 + 3] = v.w;
        }
    } else {
#pragma unroll
        for (int n = 0; n < 64; n++) s[n] = 0.f;
    }

    for (int i = 0; i < npairs; i++) {
        int buf = i & 1;
        int t = t0 + 2 * i;
        float x0 = nx0, x1 = nx1, z0 = nz0, z1 = nz1, dt0 = ndt0, dt1 = ndt1;
        if (i + 1 < npairs) {
            *(float4*)&sBC[hl][buf ^ 1][ldoff] = gv;              // commit pair i+1
            const float* xn = xb + (size_t)(2 * (i + 1)) * CONV_DIM;
            const float* zn = zb + (size_t)(2 * (i + 1)) * D_IN_PROJ;
            nx0 = (p < HEADDIM) ? xn[h * HEADDIM + p] : 0.f;
            nx1 = (p < HEADDIM) ? xn[CONV_DIM + h * HEADDIM + p] : 0.f;
            nz0 = (p < HEADDIM) ? zn[h * HEADDIM + p] : 0.f;
            nz1 = (p < HEADDIM) ? zn[D_IN_PROJ + h * HEADDIM + p] : 0.f;
            ndt0 = dtp[(size_t)(2 * (i + 1)) * NHEADS];
            ndt1 = dtp[(size_t)(2 * (i + 1) + 1) * NHEADS];
            if (i + 2 < npairs)                                    // issue pair i+2
                gv = ((const float4*)(xb + (size_t)(2 * (i + 2) + ldtok) * CONV_DIM))[ldf4];
        }
#pragma unroll
        for (int k = 0; k < 2; k++) {
            float dtv = k ? dt1 : dt0;
            float xp  = k ? x1 : x0;
            float zv  = k ? z1 : z0;
            float dA = __expf(dtv * A);
            float u  = dtv * xp;
            const float4* B4 = (const float4*)&sBC[hl][buf][k * 128];
            const float4* C4 = (const float4*)&sBC[hl][buf][k * 128 + 64];
            float y0 = 0.f, y1 = 0.f, y2 = 0.f, y3 = 0.f;
#pragma unroll
            for (int n4 = 0; n4 < 16; n4++) {
                float4 bq = B4[n4];
                float4 cq = C4[n4];
                float t0v = fmaf(s[4 * n4 + 0], dA, u * bq.x);
                float t1v = fmaf(s[4 * n4 + 1], dA, u * bq.y);
                float t2v = fmaf(s[4 * n4 + 2], dA, u * bq.z);
                float t3v = fmaf(s[4 * n4 + 3], dA, u * bq.w);
                s[4 * n4 + 0] = t0v; s[4 * n4 + 1] = t1v;
                s[4 * n4 + 2] = t2v; s[4 * n4 + 3] = t3v;
                y0 = fmaf(t0v, cq.x, y0);
                y1 = fmaf(t1v, cq.y, y1);
                y2 = fmaf(t2v, cq.z, y2);
                y3 = fmaf(t3v, cq.w, y3);
            }
            float g0 = 0.f;
            if (p < HEADDIM) {
                float yv = fmaf(xp, Dh, (y0 + y1) + (y2 + y3));
                g0 = yv * (zv / (1.f + __expf(-zv)));
            }
            size_t row0 = (size_t)(b * SEQ + t + k) * 416;
            if (p < HEADDIM) {
                ybf[row0 + h * HEADDIM + p] = f2bf(g0 * gval);
            } else {
                int widx = h * 14 + (p - HEADDIM);
                if (widx < 16) ybf[row0 + 400 + widx] = 0;
            }
            float gs0 = g0 * g0;
#pragma unroll
            for (int o = 32; o; o >>= 1) gs0 += __shfl_xor(gs0, o, 64);
            if (p == 0) ssq[(size_t)(b * SEQ + t + k) * NHEADS + h] = gs0;
        }
    }
}

// combine per-head sums -> per-token rstd for the GEMM row-scale
__global__ __launch_bounds__(256) void rstd_kernel(
    const float* __restrict__ ssq, float* __restrict__ rstdb)
{
    int m = blockIdx.x * 256 + threadIdx.x;
    if (m >= NTOK) return;
    const float4* q = (const float4*)(ssq + (size_t)m * NHEADS);
    float4 a = q[0], bq = q[1];
    float tot = ((a.x + a.y) + (a.z + a.w)) + ((bq.x + bq.y) + (bq.z + bq.w));
    rstdb[m] = rsqrtf(tot * (1.f / D_INNER) + EPS);
}

// Pass 3 (fallback, fp32 y out, single-step)
__global__ __launch_bounds__(512) void ssd_out_kernel(
    const float* __restrict__ xBC, const float* __restrict__ dtb,
    const float* __restrict__ A_log, const float* __restrict__ Dv,
    const float* __restrict__ Sbuf, float* __restrict__ y,
    int layer, int lchunk, int nchunk)
{
    int b = blockIdx.x, c = blockIdx.y;
    int tid = threadIdx.x;
    int h = tid >> 6, p = tid & 63;
    float A = -expf(A_log[layer * NHEADS + h]);
    float Dh = Dv[layer * NHEADS + h];

    __shared__ float sh[2][544];
    int t0 = c * lchunk, tend = t0 + lchunk;

    {
        const float* base = xBC + (size_t)(b * SEQ + t0) * CONV_DIM;
        sh[0][tid] = base[tid];
        if (tid < 24) {
            int e2 = 512 + tid;
            sh[0][e2] = (e2 < 528) ? base[e2]
                                   : dtb[(size_t)(b * SEQ + t0) * NHEADS + (e2 - 528)];
        }
    }

    float s[64];
    if (p < HEADDIM) {
        const float* Sb = Sbuf + ((size_t)((b * NHEADS + h) * nchunk + c)) * (HEADDIM * 64)
                          + p * 64;
#pragma unroll
        for (int n4 = 0; n4 < 16; n4++) {
            float4 v = ((const float4*)Sb)[n4];
            s[4 * n4] = v.x; s[4 * n4 + 1] = v.y; s[4 * n4 + 2] = v.z; s[4 * n4 + 3] = v.w;
        }
    } else {
#pragma unroll
        for (int n = 0; n < 64; n++) s[n] = 0.f;
    }
    __syncthreads();

    for (int t = t0; t < tend; t++) {
        int cur = (t - t0) & 1, nxt = cur ^ 1;
        float pf0 = 0.f, pf1 = 0.f;
        if (t + 1 < tend) {
            const float* base = xBC + (size_t)(b * SEQ + t + 1) * CONV_DIM;
            pf0 = base[tid];
            if (tid < 24) {
                int e2 = 512 + tid;
                pf1 = (e2 < 528) ? base[e2]
                                 : dtb[(size_t)(b * SEQ + t + 1) * NHEADS + (e2 - 528)];
            }
        }
        float dtv = sh[cur][528 + h];
        float xp  = (p < HEADDIM) ? sh[cur][h * HEADDIM + p] : 0.f;
        float dA = __expf(dtv * A);
        float u  = dtv * xp;
        const float4* B4 = (const float4*)&sh[cur][D_INNER];
        const float4* C4 = (const float4*)&sh[cur][D_INNER + D_STATE];
        float y0 = 0.f, y1 = 0.f, y2 = 0.f, y3 = 0.f;
#pragma unroll
        for (int n4 = 0; n4 < 16; n4++) {
            float4 bq = B4[n4];
            float4 cq = C4[n4];
            float t0v = fmaf(s[4 * n4 + 0], dA, u * bq.x);
            float t1v = fmaf(s[4 * n4 + 1], dA, u * bq.y);
            float t2v = fmaf(s[4 * n4 + 2], dA, u * bq.z);
            float t3v = fmaf(s[4 * n4 + 3], dA, u * bq.w);
            s[4 * n4 + 0] = t0v; s[4 * n4 + 1] = t1v;
            s[4 * n4 + 2] = t2v; s[4 * n4 + 3] = t3v;
            y0 = fmaf(t0v, cq.x, y0);
            y1 = fmaf(t1v, cq.y, y1);
            y2 = fmaf(t2v, cq.z, y2);
            y3 = fmaf(t3v, cq.w, y3);
        }
        if (p < HEADDIM) {
            float yv = (y0 + y1) + (y2 + y3);
            y[(size_t)(b * SEQ + t) * D_INNER + h * HEADDIM + p] = fmaf(xp, Dh, yv);
        }
        if (t + 1 < tend) {
            sh[nxt][tid] = pf0;
            if (tid < 24) sh[nxt][512 + tid] = pf1;
        }
        __syncthreads();
    }
}

// ---------------------------------------------------------------------------
// fallback gate+norm
__global__ __launch_bounds__(256) void gate_norm_kernel(
    float* __restrict__ y, const float* __restrict__ zxbcdt,
    const float* __restrict__ gw, short* __restrict__ ybf, int layer)
{
    int m = blockIdx.x;
    __shared__ float buf[D_INNER];
    __shared__ float red[4];
    const float* z = zxbcdt + (size_t)m * D_IN_PROJ;
    float* yr = y + (size_t)m * D_INNER;
    const float* gwl = gw + (size_t)layer * D_INNER;
    float ss = 0.f;
    for (int k = threadIdx.x; k < D_INNER; k += 256) {
        float zv = z[k];
        float sz = zv / (1.f + expf(-zv));
        float g = yr[k] * sz;
        buf[k] = g;
        ss = fmaf(g, g, ss);
    }
    int lane = threadIdx.x & 63, w = threadIdx.x >> 6;
#pragma unroll
    for (int o = 32; o; o >>= 1) ss += __shfl_xor(ss, o, 64);
    if (lane == 0) red[w] = ss;
    __syncthreads();
    float tot = red[0] + red[1] + red[2] + red[3];
    float rstd = rsqrtf(tot * (1.f / D_INNER) + EPS);
    for (int k = threadIdx.x; k < 416; k += 256) {
        if (k < D_INNER) {
            float v = buf[k] * rstd * gwl[k];
            yr[k] = v;
            if (ybf) ybf[(size_t)m * 416 + k] = f2bf(v);
        } else if (ybf) {
            ybf[(size_t)m * 416 + k] = 0;
        }
    }
}

// ---------------------------------------------------------------------------
extern "C" void kernel_launch(void* const* d_in, const int* in_sizes, int n_in,
                              void* d_out, int out_size, void* d_ws, size_t ws_size,
                              hipStream_t stream)
{
    const float* x         = (const float*)d_in[0];
    const float* pe_conv_w = (const float*)d_in[1];
    const float* proj_in_w = (const float*)d_in[2];
    const float* gn_g      = (const float*)d_in[3];
    const float* gn_b      = (const float*)d_in[4];
    const float* spec_w    = (const float*)d_in[5];
    const float* norm_w    = (const float*)d_in[6];
    const float* in_proj_w = (const float*)d_in[7];
    const float* conv_w    = (const float*)d_in[8];
    const float* conv_b    = (const float*)d_in[9];
    const float* dt_bias   = (const float*)d_in[10];
    const float* A_log     = (const float*)d_in[11];
    const float* Dv        = (const float*)d_in[12];
    const float* gnorm_w   = (const float*)d_in[13];
    const float* out_proj_w= (const float*)d_in[14];
    const float* norm_f_w  = (const float*)d_in[15];
    const float* head_w    = (const float*)d_in[16];
    const float* head_b    = (const float*)d_in[17];
    float* out = (float*)d_out;
    float* ws  = (float*)d_ws;

    // fast gate: 28,011,424 floats = 112.05 MB (prior rounds ran fast at
    // gates up to 136.4 MB on this harness).
    const size_t needA = 28011424ull * sizeof(float);
    int fast = (ws_size >= needA) ? 1 : 0;

    int nchunk, lchunk;
    float *residual = ws, *hidden = ws + 1824000;
    float *zxbcdt, *xBC, *dtb, *Sbuf, *Pd;
    float *ubuf = nullptr, *ybuf = nullptr, *ssq = nullptr, *rstdb = nullptr;
    short *w_in_bf = nullptr, *w_out_bf = nullptr, *w_head_bf = nullptr,
          *w_spec_bf = nullptr, *csmat_bf = nullptr, *x_bf = nullptr,
          *ubuf_bf = nullptr, *ybuf_bf = nullptr, *magb_bf = nullptr;

    if (fast) {
        nchunk = 15; lchunk = 38;               // 15*38 = 570 (even lchunk)
        zxbcdt = ws + 3648000;                  // 8,536,320
        xBC    = ws + 12184320;                 // 4,815,360
        dtb    = ws + 16999680;                 // 72,960
        Sbuf   = ws + 17072640;                 // 15*128*3200 = 6,144,000
        Pd     = ws + 23216640;                 // 1,920
        short* pool = (short*)(ws + 23218560);
        w_in_bf   = pool;                       // 2,515,968
        w_out_bf  = pool + 2515968;             //   998,400
        w_head_bf = pool + 3514368;             //    44,800
        w_spec_bf = pool + 3559168;             //    25,600
        ubuf_bf   = pool + 3584768;             // 2,042,880
        ybuf_bf   = pool + 5627648;             // 3,793,920 -> 9,421,568 shorts
        ssq       = ws + 27929344;              // 72,960 (NTOK*8)
        rstdb     = ws + 28002304;              // 9,120 -> end 28,011,424
        // preamble-only temporaries in the (then-dead) Sbuf region
        csmat_bf  = (short*)(Sbuf + 4000000);   //    45,248 shorts
        x_bf      = (short*)(Sbuf + 4100000);   // 2,042,880 shorts
        magb_bf   = (short*)(Sbuf + 5200000);   // 1,167,360 shorts (fits 6.14M)
    } else {
        nchunk = 6; lchunk = 95;
        ubuf   = ws + 3648000;
        zxbcdt = ws + 5472000;
        xBC    = ws + 14008320;
        dtb    = ws + 18823680;
        ybuf   = ws + 18896640;
        Sbuf   = ws + 1824000;
        Pd     = ws + 5470000;
    }

    // preamble aliases (dead layer buffers / dead Sbuf)
    float* traw  = fast ? Sbuf : ybuf;
    float* patch = zxbcdt;
    float* csout = fast ? (Sbuf + 2000000) : (xBC + 50000);
    float* csmat = xBC;                         // fallback fp32 DFT matrix
    float* magb  = fast ? nullptr : (xBC + 2000000);
    float* stats = dtb;

    // ---- weight / input casts (fast) ----
    if (fast) {
        cast_pad_kernel<<<(12 * 936 * 224 + 255) / 256, 256, 0, stream>>>(
            in_proj_w, w_in_bf, 12 * 936, 200, 224);
        cast_pad_kernel<<<(12 * 200 * 416 + 255) / 256, 256, 0, stream>>>(
            out_proj_w, w_out_bf, 12 * 200, 400, 416);
        cast_pad_kernel<<<(200 * 224 + 255) / 256, 256, 0, stream>>>(
            head_w, w_head_bf, 200, 200, 224);
        cast_pad_kernel<<<(200 * 128 + 255) / 256, 256, 0, stream>>>(
            spec_w, w_spec_bf, 200, 101, 128);
        cast_pad_kernel<<<(9120 * 224 + 255) / 256, 256, 0, stream>>>(
            x, x_bf, 9120, 200, 224);
        dft_init_bf_kernel<<<(202 * 224 + 255) / 256, 256, 0, stream>>>(csmat_bf);
    } else {
        dft_init_kernel<<<(202 * 200 + 255) / 256, 256, 0, stream>>>(csmat);
    }

    // ---- patch embed ----
    time_conv_kernel<<<NTOK, 256, 0, stream>>>(x, proj_in_w, traw);
    gn_stats_kernel<<<80, 256, 0, stream>>>(traw, stats);
    gn_gelu_kernel<<<(NTOK * 200 + 255) / 256, 256, 0, stream>>>(traw, stats, gn_g, gn_b, patch);
    if (fast) {
        gemm_bf16<<<dim3(2, 72), 256, 0, stream>>>(x_bf, csmat_bf, nullptr, nullptr, csout,
                                                   NTOK, 202, 224, 0);
        mag_bf_kernel<<<(NTOK * 128 + 255) / 256, 256, 0, stream>>>(csout, magb_bf);
        gemm_bf16<<<dim3(2, 72), 256, 0, stream>>>(magb_bf, w_spec_bf, nullptr, nullptr, patch,
                                                   NTOK, 200, 128, 1);
    } else {
        gemm_nt<<<dim3(2, 72), 256, 0, stream>>>(x, csmat, nullptr, csout, NTOK, 202, 200, 0);
        mag_kernel<<<(NTOK * NFREQ + 255) / 256, 256, 0, stream>>>(csout, magb);
        gemm_nt<<<dim3(2, 72), 256, 0, stream>>>(magb, spec_w, nullptr, patch,
                                                 NTOK, 200, NFREQ, 1);
    }
    pe_conv3_kernel<<<dim3(16, 13, 5), 256, 0, stream>>>(patch, pe_conv_w, hidden);

    // ---- layers ----
    for (int i = 0; i < N_LAYER; i++) {
        if (fast) {
            norm_dt_kernel<<<NTOK, 256, 0, stream>>>(hidden, residual, norm_w + i * 200,
                                                     ubuf_bf, in_proj_w, dt_bias, dtb,
                                                     i, (i == 0) ? 1 : 0);
            gemm_bf16<<<dim3(8, 72), 256, 0, stream>>>(
                ubuf_bf, w_in_bf + (size_t)i * 936 * 224, nullptr, nullptr, zxbcdt,
                NTOK, D_IN_PROJ, 224, 0);
        } else {
            add_rmsnorm_kernel<<<NTOK, 64, 0, stream>>>(hidden, residual, norm_w + i * 200,
                                                        ubuf, nullptr, (i == 0) ? 1 : 0);
            dt_gemv_kernel<<<NTOK / 4, 256, 0, stream>>>(ubuf, in_proj_w, dt_bias, dtb, i);
            gemm_nt<<<dim3(8, 72), 256, 0, stream>>>(
                ubuf, in_proj_w + (size_t)i * D_IN_PROJ * 200, nullptr, zxbcdt,
                NTOK, D_IN_PROJ, 200, 0);
        }
        dtconv2_kernel<<<dim3(16, 72), 256, 0, stream>>>(zxbcdt, conv_w, conv_b, xBC, i);
        {
            dim3 g(BATCH, nchunk);
            if (fast) {
                ssd_state12_kernel<<<dim3(BATCH, nchunk, 2), 256, 0, stream>>>(
                    xBC, dtb, A_log, Sbuf, Pd, i, lchunk, nchunk);
                ssd_scan2b_kernel<<<dim3(BATCH * NHEADS, 13), 256, 0, stream>>>(Sbuf, Pd, nchunk);
                ssd_out7_kernel<<<dim3(BATCH, nchunk, 2), 256, 0, stream>>>(
                    xBC, dtb, zxbcdt, A_log, Dv, Sbuf, gnorm_w, ybuf_bf, ssq,
                    i, lchunk, nchunk);
                rstd_kernel<<<(NTOK + 255) / 256, 256, 0, stream>>>(ssq, rstdb);
                gemm_bf16<<<dim3(2, 72), 256, 0, stream>>>(
                    ybuf_bf, w_out_bf + (size_t)i * 200 * 416, nullptr, rstdb, hidden,
                    NTOK, 200, 416, 0);
            } else {
                ssd_state_kernel<<<g, 512, 0, stream>>>(xBC, dtb, A_log, Sbuf, Pd,
                                                        i, lchunk, nchunk);
                ssd_scan2b_kernel<<<dim3(BATCH * NHEADS, 13), 256, 0, stream>>>(Sbuf, Pd, nchunk);
                ssd_out_kernel<<<g, 512, 0, stream>>>(xBC, dtb, A_log, Dv, Sbuf, ybuf,
                                                      i, lchunk, nchunk);
                gate_norm_kernel<<<NTOK, 256, 0, stream>>>(ybuf, zxbcdt, gnorm_w, nullptr, i);
                gemm_nt<<<dim3(2, 72), 256, 0, stream>>>(
                    ybuf, out_proj_w + (size_t)i * 200 * D_INNER, nullptr, hidden,
                    NTOK, 200, D_INNER, 0);
            }
        }
    }

    // ---- final norm + head ----
    add_rmsnorm_kernel<<<NTOK, 64, 0, stream>>>(hidden, residual, norm_f_w,
                                                fast ? nullptr : ubuf,
                                                fast ? ubuf_bf : nullptr, 0);
    if (fast) {
        gemm_bf16<<<dim3(2, 72), 256, 0, stream>>>(ubuf_bf, w_head_bf, head_b, nullptr, out,
                                                   NTOK, 200, 224, 0);
    } else {
        gemm_nt<<<dim3(2, 72), 256, 0, stream>>>(ubuf, head_w, head_b, out,
                                                 NTOK, 200, 200, 0);
    }
}

// Round 14
// 2289.532 us; speedup vs baseline: 1.0801x; 1.0050x over previous
//
#include <hip/hip_runtime.h>
#include <hip/hip_bf16.h>
#include <math.h>

// ---------------------------------------------------------------------------
// EEGMamba forward. Round 23: pass 3 as chunked MFMA (pass 1 already MFMA in
// R22, 2426->2301). Per (b,h,chunk): CB = Ct@Bt^T (shared operands), G =
// CB * exp(lc_t-lc_s)*dt_s masked s<=t (bf16 -> LDS), Y = G@Xt^T +
// exp(lc_t)*(Ct@Sin^T), epilogue adds D*x, gates silu(z), ssq-reduces, writes
// ybf. No serial recurrence anywhere. LDS tiles stride-72 (aligned, ~2-way
// conflicts). Fragment layouts mirror verified gemm_bf16/state12.
#define D_MODEL   200
#define N_LAYER   12
#define NHEADS    8
#define HEADDIM   50
#define D_STATE   64
#define D_INNER   400
#define CONV_DIM  528
#define D_IN_PROJ 936
#define D_CONV    4
#define EPS       1e-5f

#define BATCH 16
#define CH    19
#define LLEN  30
#define SEQ   570
#define NTOK  9120
#define NFREQ 101

typedef __attribute__((ext_vector_type(8))) short s8v;
typedef __attribute__((ext_vector_type(4))) float f32x4;

__device__ __forceinline__ short f2bf(float f) {
    unsigned u = __float_as_uint(f);
    u += 0x7FFFu + ((u >> 16) & 1u);      // RNE
    return (short)(u >> 16);
}

// ---------------------------------------------------------------------------
// bf16 MFMA GEMM: C[M,N] = rowscale[m] * (A[M,Kp] @ W[N,Kp]^T) (+bias) (+C)
__global__ __launch_bounds__(256) void gemm_bf16(
    const short* __restrict__ A, const short* __restrict__ W,
    const float* __restrict__ bias, const float* __restrict__ rowscale,
    float* __restrict__ C, int M, int N, int Kp, int accum)
{
    __shared__ __align__(16) short As[128][40];
    __shared__ __align__(16) short Ws[128][40];

    int bm = blockIdx.y * 128;
    int bn = blockIdx.x * 128;
    int tid = threadIdx.x;
    int lane = tid & 63;
    int wv = tid >> 6;
    int wm = wv & 1, wn = wv >> 1;
    int lm = lane & 15, lg = lane >> 4;

    int sr = tid >> 1;
    int sh_ = (tid & 1) * 16;

    f32x4 acc[4][4];
#pragma unroll
    for (int i = 0; i < 4; i++)
#pragma unroll
        for (int j = 0; j < 4; j++) acc[i][j] = (f32x4)0.f;

    for (int k0 = 0; k0 < Kp; k0 += 32) {
        {
            s8v v0 = (s8v)0, v1 = (s8v)0;
            if (bm + sr < M) {
                const short* ga = A + (size_t)(bm + sr) * Kp + k0 + sh_;
                v0 = *(const s8v*)ga;
                v1 = *(const s8v*)(ga + 8);
            }
            *(s8v*)&As[sr][sh_] = v0;
            *(s8v*)&As[sr][sh_ + 8] = v1;
        }
        {
            s8v v0 = (s8v)0, v1 = (s8v)0;
            if (bn + sr < N) {
                const short* gw = W + (size_t)(bn + sr) * Kp + k0 + sh_;
                v0 = *(const s8v*)gw;
                v1 = *(const s8v*)(gw + 8);
            }
            *(s8v*)&Ws[sr][sh_] = v0;
            *(s8v*)&Ws[sr][sh_ + 8] = v1;
        }
        __syncthreads();

        s8v af[4], bf[4];
#pragma unroll
        for (int i = 0; i < 4; i++)
            af[i] = *(const s8v*)&As[wm * 64 + i * 16 + lm][lg * 8];
#pragma unroll
        for (int j = 0; j < 4; j++)
            bf[j] = *(const s8v*)&Ws[wn * 64 + j * 16 + lm][lg * 8];
#pragma unroll
        for (int i = 0; i < 4; i++)
#pragma unroll
            for (int j = 0; j < 4; j++)
                acc[i][j] = __builtin_amdgcn_mfma_f32_16x16x32_bf16(
                    af[i], bf[j], acc[i][j], 0, 0, 0);
        __syncthreads();
    }

#pragma unroll
    for (int j = 0; j < 4; j++) {
        int n = bn + wn * 64 + j * 16 + lm;
        if (n >= N) continue;
        float bv = bias ? bias[n] : 0.f;
#pragma unroll
        for (int i = 0; i < 4; i++) {
            int mbase = bm + wm * 64 + i * 16 + lg * 4;
#pragma unroll
            for (int r = 0; r < 4; r++) {
                int m = mbase + r;
                if (m >= M) continue;
                size_t idx = (size_t)m * N + n;
                float v = acc[i][j][r];
                if (rowscale) v *= rowscale[m];
                v += bv;
                if (accum) v += C[idx];
                C[idx] = v;
            }
        }
    }
}

// ---------------------------------------------------------------------------
// fp32 GEMM (fallback path)
__global__ __launch_bounds__(256) void gemm_nt(
    const float* __restrict__ A, const float* __restrict__ W,
    const float* __restrict__ bias, float* __restrict__ C,
    int M, int N, int K, int accum)
{
    const int BM = 128, BK = 16;
    __shared__ float As[16][BM + 4];
    __shared__ float Ws[16][BM + 4];

    int bm = blockIdx.y * BM;
    int bn = blockIdx.x * BM;
    int tid = threadIdx.x;
    int lr = tid >> 1;
    int lc = (tid & 1) * 8;
    int tx = tid & 15;
    int ty = tid >> 4;

    float acc[8][8];
#pragma unroll
    for (int i = 0; i < 8; i++)
#pragma unroll
        for (int j = 0; j < 8; j++) acc[i][j] = 0.f;

    for (int k0 = 0; k0 < K; k0 += BK) {
#pragma unroll
        for (int i = 0; i < 8; i++) {
            int gr = bm + lr, gk = k0 + lc + i;
            As[lc + i][lr] = (gr < M && gk < K) ? A[(size_t)gr * K + gk] : 0.f;
        }
#pragma unroll
        for (int i = 0; i < 8; i++) {
            int gr = bn + lr, gk = k0 + lc + i;
            Ws[lc + i][lr] = (gr < N && gk < K) ? W[(size_t)gr * K + gk] : 0.f;
        }
        __syncthreads();
#pragma unroll
        for (int kk = 0; kk < BK; kk++) {
            float a[8], bv[8];
#pragma unroll
            for (int i = 0; i < 8; i++) a[i] = As[kk][ty * 8 + i];
#pragma unroll
            for (int j = 0; j < 8; j++) bv[j] = Ws[kk][tx * 8 + j];
#pragma unroll
            for (int i = 0; i < 8; i++)
#pragma unroll
                for (int j = 0; j < 8; j++)
                    acc[i][j] = fmaf(a[i], bv[j], acc[i][j]);
        }
        __syncthreads();
    }

#pragma unroll
    for (int i = 0; i < 8; i++) {
        int gm = bm + ty * 8 + i;
        if (gm >= M) continue;
#pragma unroll
        for (int j = 0; j < 8; j++) {
            int gn = bn + tx * 8 + j;
            if (gn >= N) continue;
            float v = acc[i][j];
            if (bias) v += bias[gn];
            if (accum) v += C[(size_t)gm * N + gn];
            C[(size_t)gm * N + gn] = v;
        }
    }
}

// ---------------------------------------------------------------------------
__global__ __launch_bounds__(256) void cast_pad_kernel(
    const float* __restrict__ src, short* __restrict__ dst,
    int R, int K, int Kp)
{
    int idx = blockIdx.x * 256 + threadIdx.x;
    if (idx >= R * Kp) return;
    int r = idx / Kp, k = idx - r * Kp;
    dst[idx] = (k < K) ? f2bf(src[(size_t)r * K + k]) : (short)0;
}

// ---------------------------------------------------------------------------
__global__ __launch_bounds__(256) void time_conv_kernel(
    const float* __restrict__ x, const float* __restrict__ pw,
    float* __restrict__ traw)
{
    int br = blockIdx.x;
    __shared__ float xr[200];
    if (threadIdx.x < 200) xr[threadIdx.x] = x[(size_t)br * 200 + threadIdx.x];
    __syncthreads();
    if (threadIdx.x < 200) {
        int oc = threadIdx.x >> 3, j = threadIdx.x & 7;
        int start = j * 25 - 24;
        float acc = 0.f;
#pragma unroll
        for (int k = 0; k < 49; k++) {
            int d = start + k;
            if (d >= 0 && d < 200) acc = fmaf(xr[d], pw[oc * 49 + k], acc);
        }
        int b = br / SEQ, row = br % SEQ;
        traw[(((size_t)b * 25 + oc) * SEQ + row) * 8 + j] = acc;
    }
}

__global__ __launch_bounds__(256) void gn_stats_kernel(
    const float* __restrict__ traw, float* __restrict__ stats)
{
    int bg = blockIdx.x;
    int b = bg / 5, g = bg % 5;
    const float* base = traw + ((size_t)b * 25 + g * 5) * SEQ * 8;
    float s = 0.f, q = 0.f;
    for (int i = threadIdx.x; i < 5 * SEQ * 8; i += 256) {
        float v = base[i];
        s += v; q = fmaf(v, v, q);
    }
    __shared__ float rs[4], rq[4];
    int lane = threadIdx.x & 63, w = threadIdx.x >> 6;
#pragma unroll
    for (int o = 32; o; o >>= 1) { s += __shfl_xor(s, o, 64); q += __shfl_xor(q, o, 64); }
    if (lane == 0) { rs[w] = s; rq[w] = q; }
    __syncthreads();
    if (threadIdx.x == 0) {
        float S = rs[0] + rs[1] + rs[2] + rs[3];
        float Q = rq[0] + rq[1] + rq[2] + rq[3];
        float inv = 1.f / (5.f * SEQ * 8.f);
        float mean = S * inv;
        float var = Q * inv - mean * mean;
        stats[bg * 2] = mean;
        stats[bg * 2 + 1] = rsqrtf(var + EPS);
    }
}

__global__ __launch_bounds__(256) void gn_gelu_kernel(
    const float* __restrict__ traw, const float* __restrict__ stats,
    const float* __restrict__ gn_g, const float* __restrict__ gn_b,
    float* __restrict__ patch)
{
    int idx = blockIdx.x * 256 + threadIdx.x;
    if (idx >= NTOK * 200) return;
    int d = idx % 200;
    int row = (idx / 200) % SEQ;
    int b = idx / (200 * SEQ);
    int oc = d >> 3, j = d & 7;
    float v = traw[(((size_t)b * 25 + oc) * SEQ + row) * 8 + j];
    int g = oc / 5;
    float mean = stats[(b * 5 + g) * 2];
    float rstd = stats[(b * 5 + g) * 2 + 1];
    v = (v - mean) * rstd * gn_g[oc] + gn_b[oc];
    float ge = 0.5f * v * (1.f + erff(v * 0.70710678118654752f));
    patch[idx] = ge;
}

__global__ __launch_bounds__(256) void dft_init_kernel(float* __restrict__ CS)
{
    int idx = blockIdx.x * 256 + threadIdx.x;
    if (idx >= 202 * 200) return;
    int f = idx / 200, d = idx % 200;
    int fr = (f < NFREQ) ? f : (f - NFREQ);
    int m = (fr * d) % 200;
    float ang = -6.283185307179586f * (float)m * (1.f / 200.f);
    CS[idx] = (f < NFREQ) ? cosf(ang) : sinf(ang);
}

__global__ __launch_bounds__(256) void dft_init_bf_kernel(short* __restrict__ CS)
{
    int idx = blockIdx.x * 256 + threadIdx.x;
    if (idx >= 202 * 224) return;
    int f = idx / 224, d = idx - f * 224;
    short out = 0;
    if (d < 200) {
        int fr = (f < NFREQ) ? f : (f - NFREQ);
        int m = (fr * d) % 200;
        float ang = -6.283185307179586f * (float)m * (1.f / 200.f);
        out = f2bf((f < NFREQ) ? cosf(ang) : sinf(ang));
    }
    CS[idx] = out;
}

__global__ __launch_bounds__(256) void mag_kernel(
    const float* __restrict__ cs_out, float* __restrict__ magv)
{
    int idx = blockIdx.x * 256 + threadIdx.x;
    if (idx >= NTOK * NFREQ) return;
    int m = idx / NFREQ, f = idx % NFREQ;
    float re = cs_out[(size_t)m * 202 + f];
    float im = cs_out[(size_t)m * 202 + NFREQ + f];
    magv[idx] = sqrtf(re * re + im * im) * 0.005f;
}

__global__ __launch_bounds__(256) void mag_bf_kernel(
    const float* __restrict__ cs_out, short* __restrict__ magv)
{
    int idx = blockIdx.x * 256 + threadIdx.x;
    if (idx >= NTOK * 128) return;
    int m = idx >> 7, f = idx & 127;
    short out = 0;
    if (f < NFREQ) {
        float re = cs_out[(size_t)m * 202 + f];
        float im = cs_out[(size_t)m * 202 + NFREQ + f];
        out = f2bf(sqrtf(re * re + im * im) * 0.005f);
    }
    magv[idx] = out;
}

// ---------------------------------------------------------------------------
// depthwise 7x7 pos conv + residual. block = (b, 16-d slice, 4-c tile+halo)
__global__ __launch_bounds__(256) void pe_conv3_kernel(
    const float* __restrict__ patch, const float* __restrict__ pw,
    float* __restrict__ hidden)
{
    int b = blockIdx.x, dc = blockIdx.y, ct = blockIdx.z;
    int d0 = dc * 16, c0 = ct * 4;
    __shared__ float pl[10 * 30 * 16];
    __shared__ float wl[49 * 16];
    int tid = threadIdx.x;
    int dd = tid & 15;
    int d = d0 + dd;

    for (int i = tid; i < 10 * 30 * 16; i += 256) {
        int ddl = i & 15, r = i >> 4;
        int l = r % 30, cr = r / 30;
        int cc = c0 + cr - 3, dl = d0 + ddl;
        pl[i] = (cc >= 0 && cc < CH && dl < 200)
                    ? patch[((size_t)(b * CH + cc) * LLEN + l) * 200 + dl] : 0.f;
    }
    for (int i = tid; i < 49 * 16; i += 256) {
        int k = i >> 4, dl = d0 + (i & 15);
        wl[i] = (dl < 200) ? pw[(size_t)dl * 49 + k] : 0.f;
    }
    __syncthreads();

    float wreg[49];
#pragma unroll
    for (int k = 0; k < 49; k++) wreg[k] = wl[k * 16 + dd];

    for (int o = tid; o < 4 * 30 * 16; o += 256) {
        int r2 = o >> 4;
        int l = r2 % 30, ci = r2 / 30;
        int c = c0 + ci;
        if (c >= CH) continue;
        float acc = pl[((ci + 3) * 30 + l) * 16 + dd];
#pragma unroll
        for (int i = 0; i < 7; i++) {
#pragma unroll
            for (int j = 0; j < 7; j++) {
                int ll = l + j - 3;
                if (ll < 0 || ll >= LLEN) continue;
                acc = fmaf(pl[((ci + i) * 30 + ll) * 16 + dd], wreg[i * 7 + j], acc);
            }
        }
        if (d < 200) hidden[((size_t)(b * CH + c) * LLEN + l) * 200 + d] = acc;
    }
}

// ---------------------------------------------------------------------------
__global__ __launch_bounds__(64) void add_rmsnorm_kernel(
    const float* __restrict__ hidden, float* __restrict__ residual,
    const float* __restrict__ wn, float* __restrict__ u,
    short* __restrict__ ubf, int first)
{
    int m = blockIdx.x;
    int lane = threadIdx.x;
    const float* hr = hidden + (size_t)m * 200;
    float* rr = residual + (size_t)m * 200;
    float v[4];
    float ss = 0.f;
#pragma unroll
    for (int i = 0; i < 4; i++) {
        int k = lane + i * 64;
        float xv = 0.f;
        if (k < 200) {
            xv = hr[k] + (first ? 0.f : rr[k]);
            rr[k] = xv;
        }
        v[i] = xv;
        ss = fmaf(xv, xv, ss);
    }
#pragma unroll
    for (int o = 32; o; o >>= 1) ss += __shfl_xor(ss, o, 64);
    float rstd = rsqrtf(ss * (1.f / 200.f) + EPS);
#pragma unroll
    for (int i = 0; i < 4; i++) {
        int k = lane + i * 64;
        float val = v[i] * rstd * ((k < 200) ? wn[k] : 0.f);
        if (k < 200 && u) u[(size_t)m * 200 + k] = val;
        if (ubf) {
            if (k < 200) ubf[(size_t)m * 224 + k] = f2bf(val);
            else if (k < 224) ubf[(size_t)m * 224 + k] = 0;
        }
    }
}

// ---------------------------------------------------------------------------
// Fused: residual += hidden; u = rmsnorm*wn -> ubf; dt GEMV fp32.
__global__ __launch_bounds__(256) void norm_dt_kernel(
    const float* __restrict__ hidden, float* __restrict__ residual,
    const float* __restrict__ wn, short* __restrict__ ubf,
    const float* __restrict__ Win, const float* __restrict__ dt_bias,
    float* __restrict__ dtb, int layer, int first)
{
    int m = blockIdx.x;
    int tid = threadIdx.x;
    __shared__ float su[200];
    __shared__ float rs[4];
    float xv = 0.f;
    if (tid < 200) {
        xv = hidden[(size_t)m * 200 + tid] + (first ? 0.f : residual[(size_t)m * 200 + tid]);
        residual[(size_t)m * 200 + tid] = xv;
    }
    float ss = xv * xv;
#pragma unroll
    for (int o = 32; o; o >>= 1) ss += __shfl_xor(ss, o, 64);
    int lane = tid & 63, w = tid >> 6;
    if (lane == 0) rs[w] = ss;
    __syncthreads();
    float rstd = rsqrtf((rs[0] + rs[1] + rs[2] + rs[3]) * (1.f / 200.f) + EPS);
    if (tid < 200) {
        float val = xv * rstd * wn[tid];
        su[tid] = val;
        ubf[(size_t)m * 224 + tid] = f2bf(val);
    } else if (tid < 224) {
        ubf[(size_t)m * 224 + tid] = 0;
    }
    __syncthreads();
    int h = tid >> 5, l = tid & 31;
    const float* wr = Win + (size_t)layer * D_IN_PROJ * 200 + (size_t)(928 + h) * 200;
    float s = 0.f;
    for (int k = l; k < 200; k += 32) s = fmaf(su[k], wr[k], s);
    s += __shfl_xor(s, 16, 32);
    s += __shfl_xor(s, 8, 32);
    s += __shfl_xor(s, 4, 32);
    s += __shfl_xor(s, 2, 32);
    s += __shfl_xor(s, 1, 32);
    if (l == 0) {
        float raw = s + dt_bias[layer * NHEADS + h];
        dtb[(size_t)m * NHEADS + h] = (raw > 20.f) ? raw : log1pf(expf(raw));
    }
}

// fp32 dt GEMV (fallback)
__global__ __launch_bounds__(256) void dt_gemv_kernel(
    const float* __restrict__ u, const float* __restrict__ Win,
    const float* __restrict__ dt_bias, float* __restrict__ dtb, int layer)
{
    int tid = threadIdx.x;
    int tok = blockIdx.x * 4 + (tid >> 6);
    int head = (tid >> 3) & 7;
    int l8 = tid & 7;
    const float* ur = u + (size_t)tok * 200;
    const float* wr = Win + (size_t)layer * D_IN_PROJ * 200 + (size_t)(928 + head) * 200;
    float s = 0.f;
    for (int k = l8; k < 200; k += 8) s = fmaf(ur[k], wr[k], s);
    s += __shfl_xor(s, 1, 64);
    s += __shfl_xor(s, 2, 64);
    s += __shfl_xor(s, 4, 64);
    if (l8 == 0) {
        float raw = s + dt_bias[layer * NHEADS + head];
        dtb[(size_t)tok * NHEADS + head] = (raw > 20.f) ? raw : log1pf(expf(raw));
    }
}

// ---------------------------------------------------------------------------
// xBC = silu(causal depthwise conv4), t-tiled
__global__ __launch_bounds__(256) void dtconv2_kernel(
    const float* __restrict__ zxbcdt, const float* __restrict__ cw,
    const float* __restrict__ cb, float* __restrict__ xBC, int layer)
{
    int b = blockIdx.x, tt = blockIdx.y;
    int t0 = tt * 8;
    __shared__ float zs[11][528];
    const float* cwl = cw + (size_t)layer * CONV_DIM * 4;
    const float* cbl = cb + (size_t)layer * CONV_DIM;
    for (int i = threadIdx.x; i < 11 * 528; i += 256) {
        int r = i / 528, ch = i - r * 528;
        int t = t0 - 3 + r;
        zs[r][ch] = (t >= 0 && t < SEQ)
                        ? zxbcdt[(size_t)(b * SEQ + t) * D_IN_PROJ + D_INNER + ch] : 0.f;
    }
    __syncthreads();
    for (int o = threadIdx.x; o < 8 * 528; o += 256) {
        int tr = o / 528, ch = o - tr * 528;
        int t = t0 + tr;
        if (t >= SEQ) continue;
        float acc = cbl[ch];
#pragma unroll
        for (int k = 0; k < 4; k++)
            acc = fmaf(zs[tr + k][ch], cwl[ch * 4 + k], acc);
        xBC[(size_t)(b * SEQ + t) * CONV_DIM + ch] = acc / (1.f + __expf(-acc));
    }
}

// ---------------------------------------------------------------------------
// SSD pass 1 as ONE MFMA GEMM per (b,h,chunk) (verified R22).
__global__ __launch_bounds__(256) void ssd_state12_kernel(
    const float* __restrict__ xBC, const float* __restrict__ dtb,
    const float* __restrict__ A_log, float* __restrict__ Sbuf,
    float* __restrict__ Pd, int layer, int lchunk, int nchunk)
{
    int b = blockIdx.x, c = blockIdx.y, bz = blockIdx.z;
    int tid = threadIdx.x;
    int w = tid >> 6, lane = tid & 63;
    int h = bz * 4 + w;
    int t0 = c * lchunk;
    float A = -expf(A_log[layer * NHEADS + h]);

    __shared__ __align__(16) short Bt[64 * 64];      // [n][s], block-shared
    __shared__ __align__(16) short Xw[4][64 * 64];   // [p][s], per wave

    for (int i = tid; i < 512; i += 256) ((s8v*)Bt)[i] = (s8v)0;
#pragma unroll
    for (int ww = 0; ww < 4; ww++)
        for (int i = tid; i < 512; i += 256) ((s8v*)Xw[ww])[i] = (s8v)0;
    __syncthreads();

    float dtv = 0.f;
    if (lane < lchunk) dtv = dtb[(size_t)(b * SEQ + t0 + lane) * NHEADS + h];
    float lc = dtv * A;
#pragma unroll
    for (int o = 1; o < 64; o <<= 1) {
        float v = __shfl_up(lc, o, 64);
        if (lane >= o) lc += v;
    }
    float lcTot = __shfl(lc, lchunk - 1, 64);
    float wdec = __expf(lcTot - lc) * dtv;

    for (int idx = tid; idx < lchunk * 64; idx += 256) {
        int s = idx >> 6, n = idx & 63;
        float v = xBC[(size_t)(b * SEQ + t0 + s) * CONV_DIM + D_INNER + n];
        Bt[n * 64 + s] = f2bf(v);
    }
    for (int idx = lane; idx < lchunk * HEADDIM; idx += 64) {
        int s = idx / HEADDIM, p = idx - s * HEADDIM;
        float ws = __shfl(wdec, s, 64);
        float v = xBC[(size_t)(b * SEQ + t0 + s) * CONV_DIM + h * HEADDIM + p] * ws;
        Xw[w][p * 64 + s] = f2bf(v);
    }
    __syncthreads();

    int lm = lane & 15, lg = lane >> 4;
    f32x4 acc[4][4];
#pragma unroll
    for (int i = 0; i < 4; i++)
#pragma unroll
        for (int j = 0; j < 4; j++) acc[i][j] = (f32x4)0.f;

#pragma unroll
    for (int k0 = 0; k0 < 64; k0 += 32) {
        s8v af[4], bf[4];
#pragma unroll
        for (int i = 0; i < 4; i++)
            af[i] = *(const s8v*)&Xw[w][(i * 16 + lm) * 64 + k0 + lg * 8];
#pragma unroll
        for (int j = 0; j < 4; j++)
            bf[j] = *(const s8v*)&Bt[(j * 16 + lm) * 64 + k0 + lg * 8];
#pragma unroll
        for (int i = 0; i < 4; i++)
#pragma unroll
            for (int j = 0; j < 4; j++)
                acc[i][j] = __builtin_amdgcn_mfma_f32_16x16x32_bf16(
                    af[i], bf[j], acc[i][j], 0, 0, 0);
    }

    float* Sb = Sbuf + ((size_t)((b * NHEADS + h) * nchunk + c)) * (HEADDIM * 64);
#pragma unroll
    for (int i = 0; i < 4; i++) {
        int pbase = i * 16 + lg * 4;
#pragma unroll
        for (int r = 0; r < 4; r++) {
            int p = pbase + r;
            if (p >= HEADDIM) continue;
#pragma unroll
            for (int j = 0; j < 4; j++) {
                int n = j * 16 + lm;
                Sb[(size_t)p * 64 + n] = acc[i][j][r];
            }
        }
    }
    if (lane == 0) Pd[(b * NHEADS + h) * nchunk + c] = __expf(lcTot);
}

// single-step pass 1 (fallback)
__global__ __launch_bounds__(512) void ssd_state_kernel(
    const float* __restrict__ xBC, const float* __restrict__ dtb,
    const float* __restrict__ A_log, float* __restrict__ Sbuf,
    float* __restrict__ Pd, int layer, int lchunk, int nchunk)
{
    int b = blockIdx.x, c = blockIdx.y;
    int tid = threadIdx.x;
    int h = tid >> 6, p = tid & 63;
    float A = -expf(A_log[layer * NHEADS + h]);

    __shared__ float sh[2][544];
    int t0 = c * lchunk, tend = t0 + lchunk;

    {
        const float* base = xBC + (size_t)(b * SEQ + t0) * CONV_DIM;
        sh[0][tid] = base[tid];
        if (tid < 24) {
            int e2 = 512 + tid;
            sh[0][e2] = (e2 < 528) ? base[e2]
                                   : dtb[(size_t)(b * SEQ + t0) * NHEADS + (e2 - 528)];
        }
    }
    __syncthreads();

    float s[64];
#pragma unroll
    for (int n = 0; n < 64; n++) s[n] = 0.f;
    float pacc = 1.f;

    for (int t = t0; t < tend; t++) {
        int cur = (t - t0) & 1, nxt = cur ^ 1;
        float pf0 = 0.f, pf1 = 0.f;
        if (t + 1 < tend) {
            const float* base = xBC + (size_t)(b * SEQ + t + 1) * CONV_DIM;
            pf0 = base[tid];
            if (tid < 24) {
                int e2 = 512 + tid;
                pf1 = (e2 < 528) ? base[e2]
                                 : dtb[(size_t)(b * SEQ + t + 1) * NHEADS + (e2 - 528)];
            }
        }
        float dtv = sh[cur][528 + h];
        float xp  = (p < HEADDIM) ? sh[cur][h * HEADDIM + p] : 0.f;
        float dA = __expf(dtv * A);
        float u  = dtv * xp;
        pacc *= dA;
        const float4* B4 = (const float4*)&sh[cur][D_INNER];
#pragma unroll
        for (int n4 = 0; n4 < 16; n4++) {
            float4 bq = B4[n4];
            s[4 * n4 + 0] = fmaf(s[4 * n4 + 0], dA, u * bq.x);
            s[4 * n4 + 1] = fmaf(s[4 * n4 + 1], dA, u * bq.y);
            s[4 * n4 + 2] = fmaf(s[4 * n4 + 2], dA, u * bq.z);
            s[4 * n4 + 3] = fmaf(s[4 * n4 + 3], dA, u * bq.w);
        }
        if (t + 1 < tend) {
            sh[nxt][tid] = pf0;
            if (tid < 24) sh[nxt][512 + tid] = pf1;
        }
        __syncthreads();
    }

    if (p < HEADDIM) {
        float* Sb = Sbuf + ((size_t)((b * NHEADS + h) * nchunk + c)) * (HEADDIM * 64)
                    + p * 64;
#pragma unroll
        for (int n4 = 0; n4 < 16; n4++)
            ((float4*)Sb)[n4] = make_float4(s[4 * n4], s[4 * n4 + 1],
                                            s[4 * n4 + 2], s[4 * n4 + 3]);
    }
    if (p == 0) Pd[(b * NHEADS + h) * nchunk + c] = pacc;
}

// ---------------------------------------------------------------------------
// Pass 2, parallel over element tiles: grid (128 bh, 13), 256 thr.
__global__ __launch_bounds__(256) void ssd_scan2b_kernel(
    float* __restrict__ Sbuf, const float* __restrict__ Pd, int nchunk)
{
    int bh = blockIdx.x;
    int e = blockIdx.y * 256 + threadIdx.x;
    if (e >= HEADDIM * 64) return;
    float* base = Sbuf + (size_t)bh * nchunk * (HEADDIM * 64) + e;
    const float* pd = Pd + bh * nchunk;
    float cur = 0.f;
    for (int c = 0; c < nchunk; c++) {
        float l = base[(size_t)c * (HEADDIM * 64)];
        base[(size_t)c * (HEADDIM * 64)] = cur;
        cur = fmaf(pd[c], cur, l);
    }
}

// ---------------------------------------------------------------------------
// SSD pass 3, chunked MFMA. grid (b, chunk, 2), 256 thr = 4 waves, wave=head.
//   CB[t][s] = Ct @ Bt^T        (Ct/Bt block-shared, K=n=64)
//   G[t][s]  = CB * exp(lc_t - lc_s) * dt_s * [s<=t]   (bf16 -> per-wave LDS)
//   Y        = G @ Xt^T + exp(lc_t) * (Ct @ Sin^T)     (two K=64 GEMMs)
// Epilogue: y += D*x; g = y*silu(z); ybf = bf16(g*gw); ssq per (t,h).
// M tiles: 3 (t<48 covers lchunk<=48). LDS stride 72 shorts (aligned, ~2-way).
__global__ __launch_bounds__(256) void ssd_out13_kernel(
    const float* __restrict__ xBC, const float* __restrict__ dtb,
    const float* __restrict__ zxbcdt, const float* __restrict__ A_log,
    const float* __restrict__ Dv, const float* __restrict__ Sbuf,
    const float* __restrict__ gw, short* __restrict__ ybf,
    float* __restrict__ ssq, int layer, int lchunk, int nchunk)
{
    int b = blockIdx.x, c = blockIdx.y, bz = blockIdx.z;
    int tid = threadIdx.x;
    int w = tid >> 6, lane = tid & 63;
    int h = bz * 4 + w;
    int t0 = c * lchunk;
    float A = -expf(A_log[layer * NHEADS + h]);
    float Dh = Dv[layer * NHEADS + h];

    __shared__ __align__(16) short Ct[64 * 72];
    __shared__ __align__(16) short Bt[64 * 72];
    __shared__ __align__(16) short Gm[4][48 * 72];
    __shared__ __align__(16) short Xt[4][64 * 72];
    __shared__ __align__(16) short Sn[4][64 * 72];

    // zero pads (Gm fully overwritten later)
    for (int i = tid; i < 576; i += 256) { ((s8v*)Ct)[i] = (s8v)0; ((s8v*)Bt)[i] = (s8v)0; }
#pragma unroll
    for (int ww = 0; ww < 4; ww++)
        for (int i = tid; i < 576; i += 256) {
            ((s8v*)Xt[ww])[i] = (s8v)0; ((s8v*)Sn[ww])[i] = (s8v)0;
        }
    __syncthreads();

    // dt + inclusive log-decay prefix (per wave/head)
    float dtv = 0.f;
    if (lane < lchunk) dtv = dtb[(size_t)(b * SEQ + t0 + lane) * NHEADS + h];
    float lc = dtv * A;
#pragma unroll
    for (int o = 1; o < 64; o <<= 1) {
        float v = __shfl_up(lc, o, 64);
        if (lane >= o) lc += v;
    }

    // stage Ct/Bt (block-coop): rows s<lchunk of B and C panels
    for (int idx = tid; idx < lchunk * 64; idx += 256) {
        int s = idx >> 6, n = idx & 63;
        const float* row = xBC + (size_t)(b * SEQ + t0 + s) * CONV_DIM + D_INNER;
        Bt[s * 72 + n] = f2bf(row[n]);
        Ct[s * 72 + n] = f2bf(row[64 + n]);
    }
    // stage Xt per wave: Xt[p][s] = x[s][p]
    for (int p = 0; p < HEADDIM; p++) {
        if (lane < lchunk)
            Xt[w][p * 72 + lane] =
                f2bf(xBC[(size_t)(b * SEQ + t0 + lane) * CONV_DIM + h * HEADDIM + p]);
    }
    // stage Sin per wave: Sn[p][n] = s_in[p][n] (fp32 -> bf16, coalesced)
    {
        const float* Sb = Sbuf + ((size_t)((b * NHEADS + h) * nchunk + c)) * (HEADDIM * 64);
        for (int p = 0; p < HEADDIM; p++)
            Sn[w][p * 72 + lane] = f2bf(Sb[(size_t)p * 64 + lane]);
    }
    __syncthreads();

    int lm = lane & 15, lg = lane >> 4;

    // ---- CB = Ct @ Bt^T (M tiles i<3: t<48) ----
    f32x4 acc[3][4];
#pragma unroll
    for (int i = 0; i < 3; i++)
#pragma unroll
        for (int j = 0; j < 4; j++) acc[i][j] = (f32x4)0.f;
#pragma unroll
    for (int k0 = 0; k0 < 64; k0 += 32) {
        s8v af[3], bfv[4];
#pragma unroll
        for (int i = 0; i < 3; i++)
            af[i] = *(const s8v*)&Ct[(i * 16 + lm) * 72 + k0 + lg * 8];
#pragma unroll
        for (int j = 0; j < 4; j++)
            bfv[j] = *(const s8v*)&Bt[(j * 16 + lm) * 72 + k0 + lg * 8];
#pragma unroll
        for (int i = 0; i < 3; i++)
#pragma unroll
            for (int j = 0; j < 4; j++)
                acc[i][j] = __builtin_amdgcn_mfma_f32_16x16x32_bf16(
                    af[i], bfv[j], acc[i][j], 0, 0, 0);
    }

    // ---- scale + mask -> G (per-wave LDS; same-wave write->read, no barrier)
    float lcs4[4], dts4[4];
#pragma unroll
    for (int j = 0; j < 4; j++) {
        int s = j * 16 + lm;
        lcs4[j] = __shfl(lc, s, 64);
        dts4[j] = __shfl(dtv, s, 64);
    }
#pragma unroll
    for (int i = 0; i < 3; i++) {
#pragma unroll
        for (int r = 0; r < 4; r++) {
            int t = i * 16 + lg * 4 + r;
            float lct = __shfl(lc, t, 64);
#pragma unroll
            for (int j = 0; j < 4; j++) {
                int s = j * 16 + lm;
                float gv = (s <= t)
                    ? acc[i][j][r] * __expf(lct - lcs4[j]) * dts4[j] : 0.f;
                Gm[w][t * 72 + s] = f2bf(gv);
            }
        }
    }

    // ---- Y1 = G @ Xt^T ; Y2 = Ct @ Sn^T ----
    f32x4 acc2[3][4];
#pragma unroll
    for (int i = 0; i < 3; i++)
#pragma unroll
        for (int j = 0; j < 4; j++) { acc[i][j] = (f32x4)0.f; acc2[i][j] = (f32x4)0.f; }
#pragma unroll
    for (int k0 = 0; k0 < 64; k0 += 32) {
        s8v a1[3], b1[4], a2[3], b2[4];
#pragma unroll
        for (int i = 0; i < 3; i++) {
            a1[i] = *(const s8v*)&Gm[w][(i * 16 + lm) * 72 + k0 + lg * 8];
            a2[i] = *(const s8v*)&Ct[(i * 16 + lm) * 72 + k0 + lg * 8];
        }
#pragma unroll
        for (int j = 0; j < 4; j++) {
            b1[j] = *(const s8v*)&Xt[w][(j * 16 + lm) * 72 + k0 + lg * 8];
            b2[j] = *(const s8v*)&Sn[w][(j * 16 + lm) * 72 + k0 + lg * 8];
        }
#pragma unroll
        for (int i = 0; i < 3; i++)
#pragma unroll
            for (int j = 0; j < 4; j++) {
                acc[i][j]  = __builtin_amdgcn_mfma_f32_16x16x32_bf16(
                    a1[i], b1[j], acc[i][j], 0, 0, 0);
                acc2[i][j] = __builtin_amdgcn_mfma_f32_16x16x32_bf16(
                    a2[i], b2[j], acc2[i][j], 0, 0, 0);
            }
    }

    // ---- epilogue ----
    float gwv[4];
#pragma unroll
    for (int j = 0; j < 4; j++) {
        int p = j * 16 + lm;
        gwv[j] = (p < HEADDIM) ? gw[(size_t)layer * D_INNER + h * HEADDIM + p] : 0.f;
    }
#pragma unroll
    for (int i = 0; i < 3; i++) {
#pragma unroll
        for (int r = 0; r < 4; r++) {
            int t = i * 16 + lg * 4 + r;
            float lct = __shfl(lc, t, 64);
            float elc = __expf(lct);
            int ok = (t < lchunk);
            size_t grow = (size_t)(b * SEQ + t0 + t);
            size_t row0 = grow * 416;
            float gsum = 0.f;
#pragma unroll
            for (int j = 0; j < 4; j++) {
                int p = j * 16 + lm;
                float yv = acc[i][j][r] + elc * acc2[i][j][r];
                float g = 0.f;
                if (p < HEADDIM && ok) {
                    float xv = xBC[grow * CONV_DIM + h * HEADDIM + p];
                    float zv = zxbcdt[grow * D_IN_PROJ + h * HEADDIM + p];
                    yv += Dh * xv;
                    g = yv * (zv / (1.f + __expf(-zv)));
                    ybf[row0 + h * HEADDIM + p] = f2bf(g * gwv[j]);
                }
                gsum += g * g;
            }
            gsum += __shfl_xor(gsum, 1, 64);
            gsum += __shfl_xor(gsum, 2, 64);
            gsum += __shfl_xor(gsum, 4, 64);
            gsum += __shfl_xor(gsum, 8, 64);
            if (lm == 0 && ok) ssq[grow * NHEADS + h] = gsum;
            if (bz == 0 && w == 0 && ok) ybf[row0 + 400 + lm] = 0;
        }
    }
}

// combine per-head sums -> per-token rstd for the GEMM row-scale
__global__ __launch_bounds__(256) void rstd_kernel(
    const float* __restrict__ ssq, float* __restrict__ rstdb)
{
    int m = blockIdx.x * 256 + threadIdx.x;
    if (m >= NTOK) return;
    const float4* q = (const float4*)(ssq + (size_t)m * NHEADS);
    float4 a = q[0], bq = q[1];
    float tot = ((a.x + a.y) + (a.z + a.w)) + ((bq.x + bq.y) + (bq.z + bq.w));
    rstdb[m] = rsqrtf(tot * (1.f / D_INNER) + EPS);
}

// Pass 3 (fallback, fp32 y out, single-step)
__global__ __launch_bounds__(512) void ssd_out_kernel(
    const float* __restrict__ xBC, const float* __restrict__ dtb,
    const float* __restrict__ A_log, const float* __restrict__ Dv,
    const float* __restrict__ Sbuf, float* __restrict__ y,
    int layer, int lchunk, int nchunk)
{
    int b = blockIdx.x, c = blockIdx.y;
    int tid = threadIdx.x;
    int h = tid >> 6, p = tid & 63;
    float A = -expf(A_log[layer * NHEADS + h]);
    float Dh = Dv[layer * NHEADS + h];

    __shared__ float sh[2][544];
    int t0 = c * lchunk, tend = t0 + lchunk;

    {
        const float* base = xBC + (size_t)(b * SEQ + t0) * CONV_DIM;
        sh[0][tid] = base[tid];
        if (tid < 24) {
            int e2 = 512 + tid;
            sh[0][e2] = (e2 < 528) ? base[e2]
                                   : dtb[(size_t)(b * SEQ + t0) * NHEADS + (e2 - 528)];
        }
    }

    float s[64];
    if (p < HEADDIM) {
        const float* Sb = Sbuf + ((size_t)((b * NHEADS + h) * nchunk + c)) * (HEADDIM * 64)
                          + p * 64;
#pragma unroll
        for (int n4 = 0; n4 < 16; n4++) {
            float4 v = ((const float4*)Sb)[n4];
            s[4 * n4] = v.x; s[4 * n4 + 1] = v.y; s[4 * n4 + 2] = v.z; s[4 * n4 + 3] = v.w;
        }
    } else {
#pragma unroll
        for (int n = 0; n < 64; n++) s[n] = 0.f;
    }
    __syncthreads();

    for (int t = t0; t < tend; t++) {
        int cur = (t - t0) & 1, nxt = cur ^ 1;
        float pf0 = 0.f, pf1 = 0.f;
        if (t + 1 < tend) {
            const float* base = xBC + (size_t)(b * SEQ + t + 1) * CONV_DIM;
            pf0 = base[tid];
            if (tid < 24) {
                int e2 = 512 + tid;
                pf1 = (e2 < 528) ? base[e2]
                                 : dtb[(size_t)(b * SEQ + t + 1) * NHEADS + (e2 - 528)];
            }
        }
        float dtv = sh[cur][528 + h];
        float xp  = (p < HEADDIM) ? sh[cur][h * HEADDIM + p] : 0.f;
        float dA = __expf(dtv * A);
        float u  = dtv * xp;
        const float4* B4 = (const float4*)&sh[cur][D_INNER];
        const float4* C4 = (const float4*)&sh[cur][D_INNER + D_STATE];
        float y0 = 0.f, y1 = 0.f, y2 = 0.f, y3 = 0.f;
#pragma unroll
        for (int n4 = 0; n4 < 16; n4++) {
            float4 bq = B4[n4];
            float4 cq = C4[n4];
            float t0v = fmaf(s[4 * n4 + 0], dA, u * bq.x);
            float t1v = fmaf(s[4 * n4 + 1], dA, u * bq.y);
            float t2v = fmaf(s[4 * n4 + 2], dA, u * bq.z);
            float t3v = fmaf(s[4 * n4 + 3], dA, u * bq.w);
            s[4 * n4 + 0] = t0v; s[4 * n4 + 1] = t1v;
            s[4 * n4 + 2] = t2v; s[4 * n4 + 3] = t3v;
            y0 = fmaf(t0v, cq.x, y0);
            y1 = fmaf(t1v, cq.y, y1);
            y2 = fmaf(t2v, cq.z, y2);
            y3 = fmaf(t3v, cq.w, y3);
        }
        if (p < HEADDIM) {
            float yv = (y0 + y1) + (y2 + y3);
            y[(size_t)(b * SEQ + t) * D_INNER + h * HEADDIM + p] = fmaf(xp, Dh, yv);
        }
        if (t + 1 < tend) {
            sh[nxt][tid] = pf0;
            if (tid < 24) sh[nxt][512 + tid] = pf1;
        }
        __syncthreads();
    }
}

// ---------------------------------------------------------------------------
// fallback gate+norm
__global__ __launch_bounds__(256) void gate_norm_kernel(
    float* __restrict__ y, const float* __restrict__ zxbcdt,
    const float* __restrict__ gw, short* __restrict__ ybf, int layer)
{
    int m = blockIdx.x;
    __shared__ float buf[D_INNER];
    __shared__ float red[4];
    const float* z = zxbcdt + (size_t)m * D_IN_PROJ;
    float* yr = y + (size_t)m * D_INNER;
    const float* gwl = gw + (size_t)layer * D_INNER;
    float ss = 0.f;
    for (int k = threadIdx.x; k < D_INNER; k += 256) {
        float zv = z[k];
        float sz = zv / (1.f + expf(-zv));
        float g = yr[k] * sz;
        buf[k] = g;
        ss = fmaf(g, g, ss);
    }
    int lane = threadIdx.x & 63, w = threadIdx.x >> 6;
#pragma unroll
    for (int o = 32; o; o >>= 1) ss += __shfl_xor(ss, o, 64);
    if (lane == 0) red[w] = ss;
    __syncthreads();
    float tot = red[0] + red[1] + red[2] + red[3];
    float rstd = rsqrtf(tot * (1.f / D_INNER) + EPS);
    for (int k = threadIdx.x; k < 416; k += 256) {
        if (k < D_INNER) {
            float v = buf[k] * rstd * gwl[k];
            yr[k] = v;
            if (ybf) ybf[(size_t)m * 416 + k] = f2bf(v);
        } else if (ybf) {
            ybf[(size_t)m * 416 + k] = 0;
        }
    }
}

// ---------------------------------------------------------------------------
extern "C" void kernel_launch(void* const* d_in, const int* in_sizes, int n_in,
                              void* d_out, int out_size, void* d_ws, size_t ws_size,
                              hipStream_t stream)
{
    const float* x         = (const float*)d_in[0];
    const float* pe_conv_w = (const float*)d_in[1];
    const float* proj_in_w = (const float*)d_in[2];
    const float* gn_g      = (const float*)d_in[3];
    const float* gn_b      = (const float*)d_in[4];
    const float* spec_w    = (const float*)d_in[5];
    const float* norm_w    = (const float*)d_in[6];
    const float* in_proj_w = (const float*)d_in[7];
    const float* conv_w    = (const float*)d_in[8];
    const float* conv_b    = (const float*)d_in[9];
    const float* dt_bias   = (const float*)d_in[10];
    const float* A_log     = (const float*)d_in[11];
    const float* Dv        = (const float*)d_in[12];
    const float* gnorm_w   = (const float*)d_in[13];
    const float* out_proj_w= (const float*)d_in[14];
    const float* norm_f_w  = (const float*)d_in[15];
    const float* head_w    = (const float*)d_in[16];
    const float* head_b    = (const float*)d_in[17];
    float* out = (float*)d_out;
    float* ws  = (float*)d_ws;

    // fast gate: 28,011,424 floats = 112.05 MB (prior rounds ran fast at
    // gates up to 136.4 MB on this harness).
    const size_t needA = 28011424ull * sizeof(float);
    int fast = (ws_size >= needA) ? 1 : 0;

    int nchunk, lchunk;
    float *residual = ws, *hidden = ws + 1824000;
    float *zxbcdt, *xBC, *dtb, *Sbuf, *Pd;
    float *ubuf = nullptr, *ybuf = nullptr, *ssq = nullptr, *rstdb = nullptr;
    short *w_in_bf = nullptr, *w_out_bf = nullptr, *w_head_bf = nullptr,
          *w_spec_bf = nullptr, *csmat_bf = nullptr, *x_bf = nullptr,
          *ubuf_bf = nullptr, *ybuf_bf = nullptr, *magb_bf = nullptr;

    if (fast) {
        nchunk = 15; lchunk = 38;               // 15*38 = 570
        zxbcdt = ws + 3648000;                  // 8,536,320
        xBC    = ws + 12184320;                 // 4,815,360
        dtb    = ws + 16999680;                 // 72,960
        Sbuf   = ws + 17072640;                 // 15*128*3200 = 6,144,000
        Pd     = ws + 23216640;                 // 1,920
        short* pool = (short*)(ws + 23218560);
        w_in_bf   = pool;                       // 2,515,968
        w_out_bf  = pool + 2515968;             //   998,400
        w_head_bf = pool + 3514368;             //    44,800
        w_spec_bf = pool + 3559168;             //    25,600
        ubuf_bf   = pool + 3584768;             // 2,042,880
        ybuf_bf   = pool + 5627648;             // 3,793,920 -> 9,421,568 shorts
        ssq       = ws + 27929344;              // 72,960 (NTOK*8)
        rstdb     = ws + 28002304;              // 9,120 -> end 28,011,424
        // preamble-only temporaries in the (then-dead) Sbuf region
        csmat_bf  = (short*)(Sbuf + 4000000);   //    45,248 shorts
        x_bf      = (short*)(Sbuf + 4100000);   // 2,042,880 shorts
        magb_bf   = (short*)(Sbuf + 5200000);   // 1,167,360 shorts (fits 6.14M)
    } else {
        nchunk = 6; lchunk = 95;
        ubuf   = ws + 3648000;
        zxbcdt = ws + 5472000;
        xBC    = ws + 14008320;
        dtb    = ws + 18823680;
        ybuf   = ws + 18896640;
        Sbuf   = ws + 1824000;
        Pd     = ws + 5470000;
    }

    // preamble aliases (dead layer buffers / dead Sbuf)
    float* traw  = fast ? Sbuf : ybuf;
    float* patch = zxbcdt;
    float* csout = fast ? (Sbuf + 2000000) : (xBC + 50000);
    float* csmat = xBC;                         // fallback fp32 DFT matrix
    float* magb  = fast ? nullptr : (xBC + 2000000);
    float* stats = dtb;

    // ---- weight / input casts (fast) ----
    if (fast) {
        cast_pad_kernel<<<(12 * 936 * 224 + 255) / 256, 256, 0, stream>>>(
            in_proj_w, w_in_bf, 12 * 936, 200, 224);
        cast_pad_kernel<<<(12 * 200 * 416 + 255) / 256, 256, 0, stream>>>(
            out_proj_w, w_out_bf, 12 * 200, 400, 416);
        cast_pad_kernel<<<(200 * 224 + 255) / 256, 256, 0, stream>>>(
            head_w, w_head_bf, 200, 200, 224);
        cast_pad_kernel<<<(200 * 128 + 255) / 256, 256, 0, stream>>>(
            spec_w, w_spec_bf, 200, 101, 128);
        cast_pad_kernel<<<(9120 * 224 + 255) / 256, 256, 0, stream>>>(
            x, x_bf, 9120, 200, 224);
        dft_init_bf_kernel<<<(202 * 224 + 255) / 256, 256, 0, stream>>>(csmat_bf);
    } else {
        dft_init_kernel<<<(202 * 200 + 255) / 256, 256, 0, stream>>>(csmat);
    }

    // ---- patch embed ----
    time_conv_kernel<<<NTOK, 256, 0, stream>>>(x, proj_in_w, traw);
    gn_stats_kernel<<<80, 256, 0, stream>>>(traw, stats);
    gn_gelu_kernel<<<(NTOK * 200 + 255) / 256, 256, 0, stream>>>(traw, stats, gn_g, gn_b, patch);
    if (fast) {
        gemm_bf16<<<dim3(2, 72), 256, 0, stream>>>(x_bf, csmat_bf, nullptr, nullptr, csout,
                                                   NTOK, 202, 224, 0);
        mag_bf_kernel<<<(NTOK * 128 + 255) / 256, 256, 0, stream>>>(csout, magb_bf);
        gemm_bf16<<<dim3(2, 72), 256, 0, stream>>>(magb_bf, w_spec_bf, nullptr, nullptr, patch,
                                                   NTOK, 200, 128, 1);
    } else {
        gemm_nt<<<dim3(2, 72), 256, 0, stream>>>(x, csmat, nullptr, csout, NTOK, 202, 200, 0);
        mag_kernel<<<(NTOK * NFREQ + 255) / 256, 256, 0, stream>>>(csout, magb);
        gemm_nt<<<dim3(2, 72), 256, 0, stream>>>(magb, spec_w, nullptr, patch,
                                                 NTOK, 200, NFREQ, 1);
    }
    pe_conv3_kernel<<<dim3(16, 13, 5), 256, 0, stream>>>(patch, pe_conv_w, hidden);

    // ---- layers ----
    for (int i = 0; i < N_LAYER; i++) {
        if (fast) {
            norm_dt_kernel<<<NTOK, 256, 0, stream>>>(hidden, residual, norm_w + i * 200,
                                                     ubuf_bf, in_proj_w, dt_bias, dtb,
                                                     i, (i == 0) ? 1 : 0);
            gemm_bf16<<<dim3(8, 72), 256, 0, stream>>>(
                ubuf_bf, w_in_bf + (size_t)i * 936 * 224, nullptr, nullptr, zxbcdt,
                NTOK, D_IN_PROJ, 224, 0);
        } else {
            add_rmsnorm_kernel<<<NTOK, 64, 0, stream>>>(hidden, residual, norm_w + i * 200,
                                                        ubuf, nullptr, (i == 0) ? 1 : 0);
            dt_gemv_kernel<<<NTOK / 4, 256, 0, stream>>>(ubuf, in_proj_w, dt_bias, dtb, i);
            gemm_nt<<<dim3(8, 72), 256, 0, stream>>>(
                ubuf, in_proj_w + (size_t)i * D_IN_PROJ * 200, nullptr, zxbcdt,
                NTOK, D_IN_PROJ, 200, 0);
        }
        dtconv2_kernel<<<dim3(16, 72), 256, 0, stream>>>(zxbcdt, conv_w, conv_b, xBC, i);
        {
            dim3 g(BATCH, nchunk);
            if (fast) {
                ssd_state12_kernel<<<dim3(BATCH, nchunk, 2), 256, 0, stream>>>(
                    xBC, dtb, A_log, Sbuf, Pd, i, lchunk, nchunk);
                ssd_scan2b_kernel<<<dim3(BATCH * NHEADS, 13), 256, 0, stream>>>(Sbuf, Pd, nchunk);
                ssd_out13_kernel<<<dim3(BATCH, nchunk, 2), 256, 0, stream>>>(
                    xBC, dtb, zxbcdt, A_log, Dv, Sbuf, gnorm_w, ybuf_bf, ssq,
                    i, lchunk, nchunk);
                rstd_kernel<<<(NTOK + 255) / 256, 256, 0, stream>>>(ssq, rstdb);
                gemm_bf16<<<dim3(2, 72), 256, 0, stream>>>(
                    ybuf_bf, w_out_bf + (size_t)i * 200 * 416, nullptr, rstdb, hidden,
                    NTOK, 200, 416, 0);
            } else {
                ssd_state_kernel<<<g, 512, 0, stream>>>(xBC, dtb, A_log, Sbuf, Pd,
                                                        i, lchunk, nchunk);
                ssd_scan2b_kernel<<<dim3(BATCH * NHEADS, 13), 256, 0, stream>>>(Sbuf, Pd, nchunk);
                ssd_out_kernel<<<g, 512, 0, stream>>>(xBC, dtb, A_log, Dv, Sbuf, ybuf,
                                                      i, lchunk, nchunk);
                gate_norm_kernel<<<NTOK, 256, 0, stream>>>(ybuf, zxbcdt, gnorm_w, nullptr, i);
                gemm_nt<<<dim3(2, 72), 256, 0, stream>>>(
                    ybuf, out_proj_w + (size_t)i * 200 * D_INNER, nullptr, hidden,
                    NTOK, 200, D_INNER, 0);
            }
        }
    }

    // ---- final norm + head ----
    add_rmsnorm_kernel<<<NTOK, 64, 0, stream>>>(hidden, residual, norm_f_w,
                                                fast ? nullptr : ubuf,
                                                fast ? ubuf_bf : nullptr, 0);
    if (fast) {
        gemm_bf16<<<dim3(2, 72), 256, 0, stream>>>(ubuf_bf, w_head_bf, head_b, nullptr, out,
                                                   NTOK, 200, 224, 0);
    } else {
        gemm_nt<<<dim3(2, 72), 256, 0, stream>>>(ubuf, head_w, head_b, out,
                                                 NTOK, 200, 200, 0);
    }
}